// Round 1
// baseline (1593.636 us; speedup 1.0000x reference)
//
#include <hip/hip_runtime.h>
#include <hip/hip_bf16.h>

typedef unsigned short u16;
typedef __attribute__((ext_vector_type(8))) short short8;
typedef __attribute__((ext_vector_type(4))) float f32x4;

#define DI __device__ __forceinline__

DI u16 f2b(float f){
  unsigned u = __float_as_uint(f);
  unsigned r = 0x7fffu + ((u >> 16) & 1u);
  return (u16)((u + r) >> 16);
}

// ---------------- workspace layout (bytes) ----------------
constexpr size_t O_XBF   = 0;                    // 33554432: x bf16 [8192,2048]; later reused as X2 f32 [8192,1024]
constexpr size_t O_W0T   = O_XBF  + 33554432;    // 8388608:  W0^T bf16 [2048,2048]
constexpr size_t O_WGT   = O_W0T  + 8388608;     // 4194304:  [Wg1|Wg2]^T bf16 [1024,2048]
constexpr size_t O_W2T   = O_WGT  + 4194304;     // 4194304:  W2^T bf16 [1024,2048]
constexpr size_t O_LW0   = O_W2T  + 4194304;     // 25165824: [Wih0|Whh0] bf16 [4096,3072]
constexpr size_t O_LW1   = O_LW0  + 25165824;    // 16777216: [Wih1|Whh1] bf16 [4096,2048]
constexpr size_t O_XB    = O_LW1  + 16777216;    // 33554432: xb bf16 [8192,2048]
constexpr size_t O_H     = O_XB   + 33554432;    // 33554432: h f32 [8192,1024]
constexpr size_t O_ES    = O_H    + 33554432;    // 524288:   es f32 [8192,16]
constexpr size_t O_ED    = O_ES   + 524288;      // 524288
constexpr size_t O_SC0   = O_ED   + 524288;      // 8192
constexpr size_t O_SH0   = O_SC0  + 8192;        // 8192
constexpr size_t O_SC2   = O_SH0  + 8192;        // 4096
constexpr size_t O_SH2   = O_SC2  + 4096;        // 4096
constexpr size_t O_LB0   = O_SH2  + 4096;        // 16384
constexpr size_t O_LB1   = O_LB0  + 16384;       // 16384
constexpr size_t O_QS    = O_LB1  + 16384;       // 1048576: q_star f32 [128,2048]
constexpr size_t O_H0    = O_QS   + 1048576;     // 524288 each: h0,c0,h1,c1
constexpr size_t O_C0    = O_H0   + 524288;
constexpr size_t O_H1    = O_C0   + 524288;
constexpr size_t O_C1    = O_H1   + 524288;
constexpr size_t O_ACAT  = O_C1   + 524288;      // 786432: lstm input bf16 [128,3072]
constexpr size_t O_Z     = O_ACAT + 786432;      // 2097152: z f32 [128,4096]
constexpr size_t O_QBF   = O_Z    + 2097152;     // 524288: q_star bf16
constexpr size_t O_Y2    = O_QBF  + 524288;      // 524288: lin2 out f32 [128,1024]

// ---------------- converters ----------------
__global__ void cvt_strided(const float* __restrict__ src, u16* __restrict__ dst,
                            int rows, int cols, int sld, int dld, int doff){
  int t = blockIdx.x * 256 + threadIdx.x;
  int cq = cols >> 2;
  int tot = rows * cq;
  if(t >= tot) return;
  int r = t / cq, c4 = (t - r * cq) * 4;
  float4 v = *(const float4*)(src + (size_t)r * sld + c4);
  u16 o[4] = { f2b(v.x), f2b(v.y), f2b(v.z), f2b(v.w) };
  *(ushort4*)(dst + (size_t)r * dld + doff + c4) = *(ushort4*)o;
}

__global__ void cvt_transpose(const float* __restrict__ src, u16* __restrict__ dst,
                              int R, int C, int dld, int droff){
  __shared__ float tile[32][33];
  int c0 = blockIdx.x * 32, r0 = blockIdx.y * 32;
  int tx = threadIdx.x, ty = threadIdx.y;  // (32,8)
  for(int i = 0; i < 4; i++)
    tile[ty + 8*i][tx] = src[(size_t)(r0 + ty + 8*i) * C + c0 + tx];
  __syncthreads();
  for(int i = 0; i < 4; i++)
    dst[(size_t)(droff + c0 + ty + 8*i) * dld + r0 + tx] = f2b(tile[tx][ty + 8*i]);
}

__global__ void prep(const float* g0, const float* b0, const float* m0, const float* v0,
                     const float* g2, const float* b2, const float* m2, const float* v2,
                     const float* bih0, const float* bhh0, const float* bih1, const float* bhh1,
                     float* sc0, float* sh0, float* sc2, float* sh2, float* lb0, float* lb1){
  int t = blockIdx.x * 256 + threadIdx.x;
  if(t < 2048){ float s = g0[t] * rsqrtf(v0[t] + 0.1f); sc0[t] = s; sh0[t] = b0[t] - m0[t] * s; }
  if(t < 1024){ float s = g2[t] * rsqrtf(v2[t] + 0.1f); sc2[t] = s; sh2[t] = b2[t] - m2[t] * s; }
  if(t < 4096){ lb0[t] = bih0[t] + bhh0[t]; lb1[t] = bih1[t] + bhh1[t]; }
}

// ---------------- bf16 MFMA GEMM:  C[M,N] = A[M,K] @ Bt[N,K]^T ----------------
// MODE 0: f32 out.  MODE 1: relu+bn -> bf16 out.  MODE 2: +bias f32 out.  MODE 3: relu+bn f32 out.
template<int BN, int MODE>
__global__ __launch_bounds__(256) void gemm_bf16(
    const u16* __restrict__ A, const u16* __restrict__ Bt,
    float* __restrict__ Cf, u16* __restrict__ Cb,
    const float* __restrict__ p1, const float* __restrict__ p2,
    int M, int N, int K)
{
  constexpr int BM = 128, BK = 64;
  constexpr int NI = BN / 32;
  static_assert(BN == 128 || BN == 64, "");
  __shared__ alignas(16) u16 Al[BM * BK];
  __shared__ alignas(16) u16 Bl[BN * BK];
  int m0 = blockIdx.x * BM, n0 = blockIdx.y * BN;
  int t = threadIdx.x, w = t >> 6, l = t & 63;
  int wm = (w >> 1) * 64, wn = (w & 1) * (BN / 2);
  f32x4 acc[4][NI];
  for(int a = 0; a < 4; a++) for(int b = 0; b < NI; b++) acc[a][b] = {0.f, 0.f, 0.f, 0.f};

  const short8* Ap = (const short8*)Al;
  const short8* Bp = (const short8*)Bl;

  for(int k0 = 0; k0 < K; k0 += BK){
    // stage A (BM rows x 8 16B-units, XOR-swizzled), then B
    for(int u = t; u < BM * 8; u += 256){
      int r = u >> 3, c = u & 7;
      uint4 v = *(const uint4*)(A + (size_t)(m0 + r) * K + k0 + c * 8);
      ((uint4*)Al)[r * 8 + (c ^ (r & 7))] = v;
    }
    for(int u = t; u < BN * 8; u += 256){
      int r = u >> 3, c = u & 7;
      uint4 v = *(const uint4*)(Bt + (size_t)(n0 + r) * K + k0 + c * 8);
      ((uint4*)Bl)[r * 8 + (c ^ (r & 7))] = v;
    }
    __syncthreads();
    for(int ks = 0; ks < 2; ks++){
      int kc = ks * 4 + (l >> 4);
      short8 av[4], bv[NI];
      for(int mi = 0; mi < 4; mi++){ int r = wm + mi * 16 + (l & 15); av[mi] = Ap[r * 8 + (kc ^ (r & 7))]; }
      for(int ni = 0; ni < NI; ni++){ int r = wn + ni * 16 + (l & 15); bv[ni] = Bp[r * 8 + (kc ^ (r & 7))]; }
      for(int mi = 0; mi < 4; mi++)
        for(int ni = 0; ni < NI; ni++)
          acc[mi][ni] = __builtin_amdgcn_mfma_f32_16x16x32_bf16(av[mi], bv[ni], acc[mi][ni], 0, 0, 0);
    }
    __syncthreads();
  }

  int cr = m0 + wm + ((l >> 4) << 2);
  int cc = n0 + wn + (l & 15);
  for(int mi = 0; mi < 4; mi++)
    for(int ni = 0; ni < NI; ni++)
      for(int r = 0; r < 4; r++){
        int row = cr + mi * 16 + r, col = cc + ni * 16;
        float v = acc[mi][ni][r];
        if(MODE == 0) Cf[(size_t)row * N + col] = v;
        else if(MODE == 1){ v = fmaxf(v, 0.f) * p1[col] + p2[col]; Cb[(size_t)row * N + col] = f2b(v); }
        else if(MODE == 2){ Cf[(size_t)row * N + col] = v + p1[col]; }
        else { v = fmaxf(v, 0.f) * p1[col] + p2[col]; Cf[(size_t)row * N + col] = v; }
      }
}

// ---------------- GAT attention scores es/ed ----------------
__global__ __launch_bounds__(256) void gat_scores(const float* __restrict__ h,
    const float* __restrict__ as1, const float* __restrict__ ad1,
    const float* __restrict__ as2, const float* __restrict__ ad2,
    float* __restrict__ es, float* __restrict__ ed){
  __shared__ float aS[16][64], aD[16][64];
  int t = threadIdx.x;
  for(int i = t; i < 1024; i += 256){
    int cc = i >> 6, d = i & 63;
    aS[cc][d] = (cc < 8) ? as1[i] : as2[i - 512];
    aD[cc][d] = (cc < 8) ? ad1[i] : ad2[i - 512];
  }
  __syncthreads();
  int w = t >> 6, l = t & 63;
  int node = blockIdx.x * 4 + w;
  const float* hr = h + (size_t)node * 1024;
  for(int cc = 0; cc < 16; cc++){
    float v = hr[cc * 64 + l];
    float ps = v * aS[cc][l], pd = v * aD[cc][l];
    for(int o = 32; o; o >>= 1){ ps += __shfl_down(ps, o); pd += __shfl_down(pd, o); }
    if(l == 0){ es[node * 16 + cc] = ps; ed[node * 16 + cc] = pd; }
  }
}

// ---------------- GAT: adjacency + softmax + aggregate, per (graph, conv) ----------------
__global__ __launch_bounds__(256) void gat_attn(const float* __restrict__ pos,
    const float* __restrict__ es, const float* __restrict__ ed,
    const float* __restrict__ h, const float* __restrict__ b1, const float* __restrict__ b2,
    float* __restrict__ x2){
  int b = blockIdx.x >> 1, c = blockIdx.x & 1;
  __shared__ float px[64], py[64];
  __shared__ unsigned long long adj[64];
  __shared__ float esl[64][9], edl[64][9];
  __shared__ float alphaL[64][65];
  __shared__ float hst[64][64];
  int t = threadIdx.x, w = t >> 6, l = t & 63;
  if(t < 64){ px[t] = pos[(b * 64 + t) * 2]; py[t] = pos[(b * 64 + t) * 2 + 1]; }
  __syncthreads();
  if(w == 0){
    float xi = px[l], yi = py[l];
    unsigned long long m = 0;
    for(int j = 0; j < 64; j++){
      float dx = xi - px[j], dy = yi - py[j];
      float dx2 = dx * dx;
      float dy2 = dy * dy;
      float d2 = dx2 + dy2;
      if(d2 <= 16.0f) m |= (1ull << j);
    }
    adj[l] = m;
  }
  for(int i = t; i < 512; i += 256){
    int n = i >> 3, hh = i & 7;
    esl[n][hh] = es[(b * 64 + n) * 16 + c * 8 + hh];
    edl[n][hh] = ed[(b * 64 + n) * 16 + c * 8 + hh];
  }
  __syncthreads();
  const float* bias = c ? b2 : b1;
  for(int hh = 0; hh < 8; hh++){
    // stage h slice [j][d] for this (conv, head)
    for(int i = t; i < 1024; i += 256){
      int j = i >> 4, d4 = (i & 15) * 4;
      float4 v = *(const float4*)(h + (size_t)(b * 64 + j) * 1024 + c * 512 + hh * 64 + d4);
      *(float4*)&hst[j][d4] = v;
    }
    // scores + per-row softmax (wave-parallel: lane = j, wave handles row i)
    for(int it = 0; it < 16; it++){
      int i = it * 4 + w;
      bool on = (adj[i] >> l) & 1;
      float e = edl[i][hh] + esl[l][hh];
      e = e > 0.f ? e : 0.2f * e;
      float ei = on ? e : -1e30f;
      float mx = ei;
      for(int o = 32; o; o >>= 1) mx = fmaxf(mx, __shfl_xor(mx, o));
      float p = on ? __expf(e - mx) : 0.f;
      float s = p;
      for(int o = 32; o; o >>= 1) s += __shfl_xor(s, o);
      alphaL[i][l] = p / s;
    }
    __syncthreads();
    // aggregate out[i][d] = sum_j alpha[i][j] * h[j][d]
    for(int it = 0; it < 4; it++){
      int i = it * 16 + (t >> 4), dq = t & 15;
      float ax = 0.f, ay = 0.f, az = 0.f, aw = 0.f;
      for(int j = 0; j < 64; j++){
        float al = alphaL[i][j];
        float4 hv = *(float4*)&hst[j][dq * 4];
        ax += al * hv.x; ay += al * hv.y; az += al * hv.z; aw += al * hv.w;
      }
      int col = c * 512 + hh * 64 + dq * 4;
      float4 bv = *(const float4*)(bias + hh * 64 + dq * 4);
      float4 o;
      o.x = fmaxf(ax + bv.x, 0.f); o.y = fmaxf(ay + bv.y, 0.f);
      o.z = fmaxf(az + bv.z, 0.f); o.w = fmaxf(aw + bv.w, 0.f);
      *(float4*)(x2 + (size_t)(b * 64 + i) * 1024 + col) = o;
    }
    __syncthreads();
  }
}

// ---------------- LSTM pointwise gates ----------------
__global__ void lstm_gate(const float* __restrict__ z, float* __restrict__ h, float* __restrict__ c){
  int t = blockIdx.x * 256 + threadIdx.x;  // 128*1024
  int b = t >> 10, j = t & 1023;
  const float* zr = z + (size_t)b * 4096;
  float zi = zr[j], zf = zr[1024 + j], zg = zr[2048 + j], zo = zr[3072 + j];
  float ci = c[t];
  float si = 1.f / (1.f + __expf(-zi));
  float sf = 1.f / (1.f + __expf(-zf));
  float so = 1.f / (1.f + __expf(-zo));
  float g = tanhf(zg);
  float cn = sf * ci + si * g;
  c[t] = cn;
  h[t] = so * tanhf(cn);
}

// ---------------- Set2Set attention: e = x2.h1, softmax over nodes, r; q_star=[h1|r] ----------------
__global__ __launch_bounds__(256) void s2s_attn(const float* __restrict__ x2,
    const float* __restrict__ h1, float* __restrict__ qstar){
  int b = blockIdx.x;
  __shared__ float hl[1024];
  __shared__ float el[64], al[64];
  int t = threadIdx.x, w = t >> 6, l = t & 63;
  for(int i = t; i < 1024; i += 256) hl[i] = h1[(size_t)b * 1024 + i];
  __syncthreads();
  for(int it = 0; it < 16; it++){
    int n = it * 4 + w;
    const float* xr = x2 + (size_t)(b * 64 + n) * 1024;
    float s = 0.f;
    for(int d = l; d < 1024; d += 64) s += xr[d] * hl[d];
    for(int o = 32; o; o >>= 1) s += __shfl_xor(s, o);
    if(l == 0) el[n] = s;
  }
  __syncthreads();
  if(w == 0){
    float v = el[l];
    float mx = v;
    for(int o = 32; o; o >>= 1) mx = fmaxf(mx, __shfl_xor(mx, o));
    float p = __expf(v - mx);
    float s = p;
    for(int o = 32; o; o >>= 1) s += __shfl_xor(s, o);
    al[l] = p / s;
  }
  __syncthreads();
  for(int d = t; d < 1024; d += 256){
    float r = 0.f;
    for(int j = 0; j < 64; j++) r += al[j] * x2[(size_t)(b * 64 + j) * 1024 + d];
    qstar[(size_t)b * 2048 + 1024 + d] = r;
    qstar[(size_t)b * 2048 + d] = hl[d];
  }
}

// ---------------- final tiny GEMM: out = y2 @ W3 + b3 ----------------
__global__ __launch_bounds__(256) void lin3(const float* __restrict__ y2, const float* __restrict__ W3,
                                            const float* __restrict__ b3, float* __restrict__ out){
  int b = blockIdx.x;
  __shared__ float yl[1024];
  int t = threadIdx.x, w = t >> 6, l = t & 63;
  for(int i = t; i < 1024; i += 256) yl[i] = y2[(size_t)b * 1024 + i];
  __syncthreads();
  for(int n = w; n < 10; n += 4){
    float s = 0.f;
    for(int d = l; d < 1024; d += 64) s += yl[d] * W3[d * 10 + n];
    for(int o = 32; o; o >>= 1) s += __shfl_xor(s, o);
    if(l == 0) out[b * 10 + n] = s + b3[n];
  }
}

extern "C" void kernel_launch(void* const* d_in, const int* in_sizes, int n_in,
                              void* d_out, int out_size, void* d_ws, size_t ws_size,
                              hipStream_t stream){
  const float* x    = (const float*)d_in[0];
  const float* pos  = (const float*)d_in[1];
  const float* W0   = (const float*)d_in[3];
  const float* bn0g = (const float*)d_in[4];
  const float* bn0b = (const float*)d_in[5];
  const float* bn0m = (const float*)d_in[6];
  const float* bn0v = (const float*)d_in[7];
  const float* Wg1  = (const float*)d_in[8];
  const float* as1  = (const float*)d_in[9];
  const float* ad1  = (const float*)d_in[10];
  const float* b1   = (const float*)d_in[11];
  const float* Wg2  = (const float*)d_in[12];
  const float* as2  = (const float*)d_in[13];
  const float* ad2  = (const float*)d_in[14];
  const float* b2   = (const float*)d_in[15];
  const float* Wih0 = (const float*)d_in[16];
  const float* Whh0 = (const float*)d_in[17];
  const float* bih0 = (const float*)d_in[18];
  const float* bhh0 = (const float*)d_in[19];
  const float* Wih1 = (const float*)d_in[20];
  const float* Whh1 = (const float*)d_in[21];
  const float* bih1 = (const float*)d_in[22];
  const float* bhh1 = (const float*)d_in[23];
  const float* W2   = (const float*)d_in[24];
  const float* bn2g = (const float*)d_in[25];
  const float* bn2b = (const float*)d_in[26];
  const float* bn2m = (const float*)d_in[27];
  const float* bn2v = (const float*)d_in[28];
  const float* W3   = (const float*)d_in[29];
  const float* b3   = (const float*)d_in[30];

  char* ws = (char*)d_ws;
  u16*   xbf  = (u16*)(ws + O_XBF);
  float* x2   = (float*)(ws + O_XBF);   // alias: x_bf16 dead after GEMM1
  u16*   w0t  = (u16*)(ws + O_W0T);
  u16*   wgt  = (u16*)(ws + O_WGT);
  u16*   w2t  = (u16*)(ws + O_W2T);
  u16*   lw0  = (u16*)(ws + O_LW0);
  u16*   lw1  = (u16*)(ws + O_LW1);
  u16*   xb   = (u16*)(ws + O_XB);
  float* h    = (float*)(ws + O_H);
  float* es   = (float*)(ws + O_ES);
  float* ed   = (float*)(ws + O_ED);
  float* sc0  = (float*)(ws + O_SC0);
  float* sh0  = (float*)(ws + O_SH0);
  float* sc2  = (float*)(ws + O_SC2);
  float* sh2  = (float*)(ws + O_SH2);
  float* lb0  = (float*)(ws + O_LB0);
  float* lb1  = (float*)(ws + O_LB1);
  float* qs   = (float*)(ws + O_QS);
  float* h0b  = (float*)(ws + O_H0);
  float* c0b  = (float*)(ws + O_C0);
  float* h1b  = (float*)(ws + O_H1);
  float* c1b  = (float*)(ws + O_C1);
  u16*   acat = (u16*)(ws + O_ACAT);
  float* z    = (float*)(ws + O_Z);
  u16*   qbf  = (u16*)(ws + O_QBF);
  float* y2   = (float*)(ws + O_Y2);

  auto cvtN = [](int rows, int cols){ return (rows * (cols >> 2) + 255) / 256; };

  // --- prep + weight conversions ---
  prep<<<16, 256, 0, stream>>>(bn0g, bn0b, bn0m, bn0v, bn2g, bn2b, bn2m, bn2v,
                               bih0, bhh0, bih1, bhh1, sc0, sh0, sc2, sh2, lb0, lb1);
  cvt_strided<<<cvtN(8192, 2048), 256, 0, stream>>>(x, xbf, 8192, 2048, 2048, 2048, 0);
  cvt_transpose<<<dim3(64, 64), dim3(32, 8), 0, stream>>>(W0, w0t, 2048, 2048, 2048, 0);
  cvt_transpose<<<dim3(16, 64), dim3(32, 8), 0, stream>>>(Wg1, wgt, 2048, 512, 2048, 0);
  cvt_transpose<<<dim3(16, 64), dim3(32, 8), 0, stream>>>(Wg2, wgt, 2048, 512, 2048, 512);
  cvt_transpose<<<dim3(32, 64), dim3(32, 8), 0, stream>>>(W2, w2t, 2048, 1024, 2048, 0);
  cvt_strided<<<cvtN(4096, 2048), 256, 0, stream>>>(Wih0, lw0, 4096, 2048, 2048, 3072, 0);
  cvt_strided<<<cvtN(4096, 1024), 256, 0, stream>>>(Whh0, lw0, 4096, 1024, 1024, 3072, 2048);
  cvt_strided<<<cvtN(4096, 1024), 256, 0, stream>>>(Wih1, lw1, 4096, 1024, 1024, 2048, 0);
  cvt_strided<<<cvtN(4096, 1024), 256, 0, stream>>>(Whh1, lw1, 4096, 1024, 1024, 2048, 1024);

  // --- GEMM1: xb = bf16(bn0(relu(x @ W0))) ---
  gemm_bf16<128, 1><<<dim3(64, 16), 256, 0, stream>>>(xbf, w0t, nullptr, xb, sc0, sh0, 8192, 2048, 2048);
  // --- fused GAT h: h = xb @ [Wg1|Wg2] (f32 out) ---
  gemm_bf16<128, 0><<<dim3(64, 8), 256, 0, stream>>>(xb, wgt, h, nullptr, nullptr, nullptr, 8192, 1024, 2048);
  // --- GAT attention ---
  gat_scores<<<2048, 256, 0, stream>>>(h, as1, ad1, as2, ad2, es, ed);
  gat_attn<<<256, 256, 0, stream>>>(pos, es, ed, h, b1, b2, x2);

  // --- Set2Set ---
  hipMemsetAsync(ws + O_QS, 0, 1048576 + 4 * 524288, stream);  // q_star,h0,c0,h1,c1 = 0
  for(int step = 0; step < 2; step++){
    cvt_strided<<<cvtN(128, 2048), 256, 0, stream>>>(qs, acat, 128, 2048, 2048, 3072, 0);
    cvt_strided<<<cvtN(128, 1024), 256, 0, stream>>>(h0b, acat, 128, 1024, 1024, 3072, 2048);
    gemm_bf16<64, 2><<<dim3(1, 64), 256, 0, stream>>>(acat, lw0, z, nullptr, lb0, nullptr, 128, 4096, 3072);
    lstm_gate<<<512, 256, 0, stream>>>(z, h0b, c0b);
    cvt_strided<<<cvtN(128, 1024), 256, 0, stream>>>(h0b, acat, 128, 1024, 1024, 2048, 0);
    cvt_strided<<<cvtN(128, 1024), 256, 0, stream>>>(h1b, acat, 128, 1024, 1024, 2048, 1024);
    gemm_bf16<64, 2><<<dim3(1, 64), 256, 0, stream>>>(acat, lw1, z, nullptr, lb1, nullptr, 128, 4096, 2048);
    lstm_gate<<<512, 256, 0, stream>>>(z, h1b, c1b);
    s2s_attn<<<128, 256, 0, stream>>>(x2, h1b, qs);
  }

  // --- lin2 + bn2 + relu, then lin3 ---
  cvt_strided<<<cvtN(128, 2048), 256, 0, stream>>>(qs, qbf, 128, 2048, 2048, 2048, 0);
  gemm_bf16<64, 3><<<dim3(1, 16), 256, 0, stream>>>(qbf, w2t, y2, nullptr, sc2, sh2, 128, 1024, 2048);
  lin3<<<128, 256, 0, stream>>>(y2, W3, b3, (float*)d_out);
}

// Round 2
// 577.499 us; speedup vs baseline: 2.7595x; 2.7595x over previous
//
#include <hip/hip_runtime.h>
#include <hip/hip_bf16.h>

typedef unsigned short u16;
typedef __attribute__((ext_vector_type(8))) short short8;
typedef __attribute__((ext_vector_type(4))) float f32x4;
typedef unsigned long long u64;

#define DI __device__ __forceinline__

DI u16 f2b(float f){
  unsigned u = __float_as_uint(f);
  unsigned r = 0x7fffu + ((u >> 16) & 1u);
  return (u16)((u + r) >> 16);
}

DI void gl_lds16(const void* g, void* l){
  __builtin_amdgcn_global_load_lds((const __attribute__((address_space(1))) void*)g,
                                   (__attribute__((address_space(3))) void*)l, 16, 0, 0);
}

// ---------------- workspace layout (bytes) ----------------
constexpr size_t O_XBF = 0;                    // 33554432: x bf16 [8192,2048]; later x2 f32 [8192,1024]
constexpr size_t O_W0T = O_XBF + 33554432;     // 8388608:  W0^T bf16 [2048,2048]
constexpr size_t O_WGT = O_W0T + 8388608;      // 4194304:  [Wg1|Wg2]^T bf16 [1024,2048]
constexpr size_t O_W2T = O_WGT + 4194304;      // 4194304:  W2^T bf16 [1024,2048]
constexpr size_t O_LW0 = O_W2T + 4194304;      // 25165824: [Wih0|Whh0] bf16 [4096,3072]
constexpr size_t O_LW1 = O_LW0 + 25165824;     // 16777216: [Wih1|Whh1] bf16 [4096,2048]
constexpr size_t O_XB  = O_LW1 + 16777216;     // 33554432: xb bf16 [8192,2048]
constexpr size_t O_H   = O_XB  + 33554432;     // 33554432: h f32 [8192,1024]; Set2Set scratch after GAT
constexpr size_t O_ES  = O_H   + 33554432;     // 524288
constexpr size_t O_ED  = O_ES  + 524288;       // 524288
constexpr size_t O_ADJ = O_ED  + 524288;       // 65536: adjacency masks [128][64] u64
constexpr size_t O_SC0 = O_ADJ + 65536;        // 8192
constexpr size_t O_SH0 = O_SC0 + 8192;         // 8192
constexpr size_t O_SC2 = O_SH0 + 8192;         // 4096
constexpr size_t O_SH2 = O_SC2 + 4096;         // 4096
constexpr size_t O_LB0 = O_SH2 + 4096;         // 16384
constexpr size_t O_LB1 = O_LB0 + 16384;        // 16384
// Set2Set scratch inside O_H (h is dead after gat_attn2):
constexpr size_t S_AC0 = 0;                    // 786432: acat0 bf16 [128][3072] = [q_star(2048) | h0(1024)]
constexpr size_t S_AC1 = S_AC0 + 786432;       // 524288: acat1 bf16 [128][2048] = [h0 | h1]
constexpr size_t S_C0  = S_AC1 + 524288;       // 524288
constexpr size_t S_C1  = S_C0  + 524288;       // 524288
constexpr size_t S_ZERO_BYTES = S_C1 + 524288; // zero AC0,AC1,C0,C1 each call
constexpr size_t S_H1F = S_C1  + 524288;       // 524288: h1 f32
constexpr size_t S_ZP  = S_H1F + 524288;       // 8388608: split-K partials (4x[128*4096] or 8x[128*1024])

// ---------------- converters ----------------
__global__ void cvt_strided(const float* __restrict__ src, u16* __restrict__ dst,
                            int rows, int cols, int sld, int dld, int doff){
  int t = blockIdx.x * 256 + threadIdx.x;
  int cq = cols >> 2;
  int tot = rows * cq;
  if(t >= tot) return;
  int r = t / cq, c4 = (t - r * cq) * 4;
  float4 v = *(const float4*)(src + (size_t)r * sld + c4);
  u16 o[4] = { f2b(v.x), f2b(v.y), f2b(v.z), f2b(v.w) };
  *(ushort4*)(dst + (size_t)r * dld + doff + c4) = *(ushort4*)o;
}

__global__ void cvt_transpose(const float* __restrict__ src, u16* __restrict__ dst,
                              int R, int C, int dld, int droff){
  __shared__ float tile[32][33];
  int c0 = blockIdx.x * 32, r0 = blockIdx.y * 32;
  int tx = threadIdx.x, ty = threadIdx.y;  // (32,8)
  for(int i = 0; i < 4; i++)
    tile[ty + 8*i][tx] = src[(size_t)(r0 + ty + 8*i) * C + c0 + tx];
  __syncthreads();
  for(int i = 0; i < 4; i++)
    dst[(size_t)(droff + c0 + ty + 8*i) * dld + r0 + tx] = f2b(tile[tx][ty + 8*i]);
}

__global__ void prep(const float* g0, const float* b0, const float* m0, const float* v0,
                     const float* g2, const float* b2, const float* m2, const float* v2,
                     const float* bih0, const float* bhh0, const float* bih1, const float* bhh1,
                     float* sc0, float* sh0, float* sc2, float* sh2, float* lb0, float* lb1){
  int t = blockIdx.x * 256 + threadIdx.x;
  if(t < 2048){ float s = g0[t] * rsqrtf(v0[t] + 0.1f); sc0[t] = s; sh0[t] = b0[t] - m0[t] * s; }
  if(t < 1024){ float s = g2[t] * rsqrtf(v2[t] + 0.1f); sc2[t] = s; sh2[t] = b2[t] - m2[t] * s; }
  if(t < 4096){ lb0[t] = bih0[t] + bhh0[t]; lb1[t] = bih1[t] + bhh1[t]; }
}

__global__ void adj_kernel(const float* __restrict__ pos, u64* __restrict__ adjm){
  int b = blockIdx.x, l = threadIdx.x;  // 64 threads
  __shared__ float px[64], py[64];
  float2 p = ((const float2*)pos)[b * 64 + l];
  px[l] = p.x; py[l] = p.y;
  __syncthreads();
  float xi = px[l], yi = py[l];
  u64 m = 0;
  for(int j = 0; j < 64; j++){
    float dx = xi - px[j], dy = yi - py[j];
    if(dx * dx + dy * dy <= 16.0f) m |= (1ull << j);
  }
  adjm[b * 64 + l] = m;
}

// ---------------- bf16 MFMA GEMM (m97 structure: linear LDS + gload_lds16 + swizzled read) ----------------
// C[M,N] = A[M,K] @ Bt[N,K]^T.  MODE 0: f32 out. MODE 1: relu+bn -> bf16 out.
template<int MODE>
__global__ __launch_bounds__(256) void gemm_bf16(
    const u16* __restrict__ A, const u16* __restrict__ Bt,
    float* __restrict__ Cf, u16* __restrict__ Cb,
    const float* __restrict__ p1, const float* __restrict__ p2,
    int M, int N, int K)
{
  constexpr int BM = 128, BN = 128, BK = 64;
  __shared__ alignas(16) u16 Al[BM * BK];
  __shared__ alignas(16) u16 Bl[BN * BK];
  int m0 = blockIdx.x * BM, n0 = blockIdx.y * BN;
  int t = threadIdx.x, w = t >> 6, l = t & 63;
  int wm = (w >> 1) * 64, wn = (w & 1) * 64;
  f32x4 acc[4][4];
  for(int a = 0; a < 4; a++) for(int b = 0; b < 4; b++) acc[a][b] = {0.f, 0.f, 0.f, 0.f};

  const short8* Ap = (const short8*)Al;
  const short8* Bp = (const short8*)Bl;

  for(int k0 = 0; k0 < K; k0 += BK){
    // linear LDS dest + inverse-swizzled global source (rule 21)
    #pragma unroll
    for(int u = t; u < BM * 8; u += 256){
      int r = u >> 3, c = u & 7;
      gl_lds16(A + (size_t)(m0 + r) * K + k0 + ((c ^ (r & 7)) << 3), Al + u * 8);
    }
    #pragma unroll
    for(int u = t; u < BN * 8; u += 256){
      int r = u >> 3, c = u & 7;
      gl_lds16(Bt + (size_t)(n0 + r) * K + k0 + ((c ^ (r & 7)) << 3), Bl + u * 8);
    }
    __syncthreads();
    #pragma unroll
    for(int ks = 0; ks < 2; ks++){
      int kc = ks * 4 + (l >> 4);
      short8 av[4], bv[4];
      #pragma unroll
      for(int mi = 0; mi < 4; mi++){ int r = wm + mi * 16 + (l & 15); av[mi] = Ap[r * 8 + (kc ^ (r & 7))]; }
      #pragma unroll
      for(int ni = 0; ni < 4; ni++){ int r = wn + ni * 16 + (l & 15); bv[ni] = Bp[r * 8 + (kc ^ (r & 7))]; }
      #pragma unroll
      for(int mi = 0; mi < 4; mi++)
        #pragma unroll
        for(int ni = 0; ni < 4; ni++)
          acc[mi][ni] = __builtin_amdgcn_mfma_f32_16x16x32_bf16(av[mi], bv[ni], acc[mi][ni], 0, 0, 0);
    }
    __syncthreads();
  }

  int cr = m0 + wm + ((l >> 4) << 2);
  int cc = n0 + wn + (l & 15);
  for(int mi = 0; mi < 4; mi++)
    for(int ni = 0; ni < 4; ni++)
      for(int r = 0; r < 4; r++){
        int row = cr + mi * 16 + r, col = cc + ni * 16;
        float v = acc[mi][ni][r];
        if(MODE == 0) Cf[(size_t)row * N + col] = v;
        else { v = fmaxf(v, 0.f) * p1[col] + p2[col]; Cb[(size_t)row * N + col] = f2b(v); }
      }
}

// ---------------- split-K skinny GEMM: M=128=BM, BN=64; partial s -> Cf + s*128*N ----------------
__global__ __launch_bounds__(256) void gemm_sk(
    const u16* __restrict__ A, const u16* __restrict__ Bt, float* __restrict__ Cf,
    int N, int lda, int ldb, int kPer)
{
  constexpr int BM = 128, BN = 64, BK = 64;
  __shared__ alignas(16) u16 Al[BM * BK];
  __shared__ alignas(16) u16 Bl[BN * BK];
  int n0 = blockIdx.x * BN;
  int kb = blockIdx.y * kPer;
  float* C = Cf + (size_t)blockIdx.y * 128 * N;
  int t = threadIdx.x, w = t >> 6, l = t & 63;
  int wm = (w >> 1) * 64, wn = (w & 1) * 32;
  f32x4 acc[4][2];
  for(int a = 0; a < 4; a++) for(int b = 0; b < 2; b++) acc[a][b] = {0.f, 0.f, 0.f, 0.f};

  const short8* Ap = (const short8*)Al;
  const short8* Bp = (const short8*)Bl;

  for(int k0 = kb; k0 < kb + kPer; k0 += BK){
    #pragma unroll
    for(int u = t; u < BM * 8; u += 256){
      int r = u >> 3, c = u & 7;
      gl_lds16(A + (size_t)r * lda + k0 + ((c ^ (r & 7)) << 3), Al + u * 8);
    }
    #pragma unroll
    for(int u = t; u < BN * 8; u += 256){
      int r = u >> 3, c = u & 7;
      gl_lds16(Bt + (size_t)(n0 + r) * ldb + k0 + ((c ^ (r & 7)) << 3), Bl + u * 8);
    }
    __syncthreads();
    #pragma unroll
    for(int ks = 0; ks < 2; ks++){
      int kc = ks * 4 + (l >> 4);
      short8 av[4], bv[2];
      #pragma unroll
      for(int mi = 0; mi < 4; mi++){ int r = wm + mi * 16 + (l & 15); av[mi] = Ap[r * 8 + (kc ^ (r & 7))]; }
      #pragma unroll
      for(int ni = 0; ni < 2; ni++){ int r = wn + ni * 16 + (l & 15); bv[ni] = Bp[r * 8 + (kc ^ (r & 7))]; }
      #pragma unroll
      for(int mi = 0; mi < 4; mi++)
        #pragma unroll
        for(int ni = 0; ni < 2; ni++)
          acc[mi][ni] = __builtin_amdgcn_mfma_f32_16x16x32_bf16(av[mi], bv[ni], acc[mi][ni], 0, 0, 0);
    }
    __syncthreads();
  }

  int cr = wm + ((l >> 4) << 2);
  int cc = n0 + wn + (l & 15);
  for(int mi = 0; mi < 4; mi++)
    for(int ni = 0; ni < 2; ni++)
      for(int r = 0; r < 4; r++)
        C[(size_t)(cr + mi * 16 + r) * N + cc + ni * 16] = acc[mi][ni][r];
}

// ---------------- GAT attention scores es/ed ----------------
__global__ __launch_bounds__(256) void gat_scores(const float* __restrict__ h,
    const float* __restrict__ as1, const float* __restrict__ ad1,
    const float* __restrict__ as2, const float* __restrict__ ad2,
    float* __restrict__ es, float* __restrict__ ed){
  __shared__ float aS[16][64], aD[16][64];
  int t = threadIdx.x;
  for(int i = t; i < 1024; i += 256){
    int cc = i >> 6, d = i & 63;
    aS[cc][d] = (cc < 8) ? as1[i] : as2[i - 512];
    aD[cc][d] = (cc < 8) ? ad1[i] : ad2[i - 512];
  }
  __syncthreads();
  int w = t >> 6, l = t & 63;
  int node = blockIdx.x * 4 + w;
  const float* hr = h + (size_t)node * 1024;
  for(int cc = 0; cc < 16; cc++){
    float v = hr[cc * 64 + l];
    float ps = v * aS[cc][l], pd = v * aD[cc][l];
    for(int o = 32; o; o >>= 1){ ps += __shfl_down(ps, o); pd += __shfl_down(pd, o); }
    if(l == 0){ es[node * 16 + cc] = ps; ed[node * 16 + cc] = pd; }
  }
}

// ---------------- GAT attention+aggregate: one block per (graph, conv, head) ----------------
__global__ __launch_bounds__(256) void gat_attn2(const u64* __restrict__ adjm,
    const float* __restrict__ es, const float* __restrict__ ed,
    const float* __restrict__ h, const float* __restrict__ b1, const float* __restrict__ b2,
    float* __restrict__ x2){
  int b = blockIdx.x;
  int cv = blockIdx.y >> 3, hh = blockIdx.y & 7;
  __shared__ float hst[64][64];
  __shared__ float alphaL[64][65];
  __shared__ float esl[64], edl[64];
  __shared__ u64 adjs[64];
  int t = threadIdx.x, w = t >> 6, l = t & 63;
  {
    int j = t >> 2, d0 = (t & 3) * 16;
    const float* hr = h + (size_t)(b * 64 + j) * 1024 + cv * 512 + hh * 64 + d0;
    *(float4*)&hst[j][d0]      = *(const float4*)hr;
    *(float4*)&hst[j][d0 + 4]  = *(const float4*)(hr + 4);
    *(float4*)&hst[j][d0 + 8]  = *(const float4*)(hr + 8);
    *(float4*)&hst[j][d0 + 12] = *(const float4*)(hr + 12);
  }
  if(t < 64){
    esl[t] = es[(b * 64 + t) * 16 + cv * 8 + hh];
    edl[t] = ed[(b * 64 + t) * 16 + cv * 8 + hh];
    adjs[t] = adjm[b * 64 + t];
  }
  __syncthreads();
  // softmax rows: wave w handles rows {w, w+4, ...}; lane = neighbor j
  for(int it = 0; it < 16; it++){
    int i = it * 4 + w;
    bool on = (adjs[i] >> l) & 1;
    float e = edl[i] + esl[l];
    e = e > 0.f ? e : 0.2f * e;
    float mx = on ? e : -1e30f;
    for(int o = 32; o; o >>= 1) mx = fmaxf(mx, __shfl_xor(mx, o));
    float p = on ? __expf(e - mx) : 0.f;
    float s = p;
    for(int o = 32; o; o >>= 1) s += __shfl_xor(s, o);
    alphaL[i][l] = p / s;
  }
  __syncthreads();
  // aggregate: thread -> row i = t>>2, col block q = t&3 (16 cols)
  int i = t >> 2, q = t & 3;
  float acc[16];
  #pragma unroll
  for(int k = 0; k < 16; k++) acc[k] = 0.f;
  for(int j = 0; j < 64; j++){
    float al = alphaL[i][j];
    const float* hr = &hst[j][q * 16];
    #pragma unroll
    for(int k = 0; k < 16; k++) acc[k] += al * hr[k];
  }
  const float* bias = (cv ? b2 : b1) + hh * 64 + q * 16;
  float* op = x2 + (size_t)(b * 64 + i) * 1024 + cv * 512 + hh * 64 + q * 16;
  #pragma unroll
  for(int k = 0; k < 16; k++) op[k] = fmaxf(acc[k] + bias[k], 0.f);
}

// ---------------- LSTM gates (sum split-K partials + bias, write bf16 into next GEMM inputs) ----------------
__global__ void lstm_gate0(const float* __restrict__ zp, const float* __restrict__ lb,
                           float* __restrict__ c, u16* __restrict__ ac0, u16* __restrict__ ac1){
  int t = blockIdx.x * 256 + threadIdx.x;  // 128*1024
  int b = t >> 10, j = t & 1023;
  size_t base = (size_t)b * 4096;
  float zi = 0, zf = 0, zg = 0, zo = 0;
  for(int s = 0; s < 4; s++){
    const float* zr = zp + (size_t)s * 524288 + base;
    zi += zr[j]; zf += zr[1024 + j]; zg += zr[2048 + j]; zo += zr[3072 + j];
  }
  zi += lb[j]; zf += lb[1024 + j]; zg += lb[2048 + j]; zo += lb[3072 + j];
  float ci = c[t];
  float si = 1.f / (1.f + __expf(-zi)), sf = 1.f / (1.f + __expf(-zf)), so = 1.f / (1.f + __expf(-zo));
  float cn = sf * ci + si * tanhf(zg);
  c[t] = cn;
  u16 hb = f2b(so * tanhf(cn));
  ac0[(size_t)b * 3072 + 2048 + j] = hb;
  ac1[(size_t)b * 2048 + j] = hb;
}

__global__ void lstm_gate1(const float* __restrict__ zp, const float* __restrict__ lb,
                           float* __restrict__ c, float* __restrict__ h1f, u16* __restrict__ ac1){
  int t = blockIdx.x * 256 + threadIdx.x;
  int b = t >> 10, j = t & 1023;
  size_t base = (size_t)b * 4096;
  float zi = 0, zf = 0, zg = 0, zo = 0;
  for(int s = 0; s < 4; s++){
    const float* zr = zp + (size_t)s * 524288 + base;
    zi += zr[j]; zf += zr[1024 + j]; zg += zr[2048 + j]; zo += zr[3072 + j];
  }
  zi += lb[j]; zf += lb[1024 + j]; zg += lb[2048 + j]; zo += lb[3072 + j];
  float ci = c[t];
  float si = 1.f / (1.f + __expf(-zi)), sf = 1.f / (1.f + __expf(-zf)), so = 1.f / (1.f + __expf(-zo));
  float cn = sf * ci + si * tanhf(zg);
  c[t] = cn;
  float hn = so * tanhf(cn);
  h1f[t] = hn;
  ac1[(size_t)b * 2048 + 1024 + j] = f2b(hn);
}

// ---------------- Set2Set attention: q_star=[h1|r] written as bf16 into acat0 ----------------
__global__ __launch_bounds__(256) void s2s_attn(const float* __restrict__ x2,
    const float* __restrict__ h1, u16* __restrict__ ac0){
  int b = blockIdx.x;
  __shared__ float hl[1024];
  __shared__ float el[64], al[64];
  int t = threadIdx.x, w = t >> 6, l = t & 63;
  for(int i = t; i < 1024; i += 256) hl[i] = h1[(size_t)b * 1024 + i];
  __syncthreads();
  for(int it = 0; it < 16; it++){
    int n = it * 4 + w;
    const float* xr = x2 + (size_t)(b * 64 + n) * 1024;
    float s = 0.f;
    for(int d = l; d < 1024; d += 64) s += xr[d] * hl[d];
    for(int o = 32; o; o >>= 1) s += __shfl_xor(s, o);
    if(l == 0) el[n] = s;
  }
  __syncthreads();
  if(w == 0){
    float v = el[l];
    float mx = v;
    for(int o = 32; o; o >>= 1) mx = fmaxf(mx, __shfl_xor(mx, o));
    float p = __expf(v - mx);
    float s = p;
    for(int o = 32; o; o >>= 1) s += __shfl_xor(s, o);
    al[l] = p / s;
  }
  __syncthreads();
  for(int d = t; d < 1024; d += 256){
    float r = 0.f;
    for(int j = 0; j < 64; j++) r += al[j] * x2[(size_t)(b * 64 + j) * 1024 + d];
    ac0[(size_t)b * 3072 + 1024 + d] = f2b(r);
    ac0[(size_t)b * 3072 + d] = f2b(hl[d]);
  }
}

// ---------------- lin2 combine (8 split partials) + bn + relu + lin3 ----------------
__global__ __launch_bounds__(256) void lin3(const float* __restrict__ zp2,
    const float* __restrict__ sc2, const float* __restrict__ sh2,
    const float* __restrict__ W3, const float* __restrict__ b3, float* __restrict__ out){
  int b = blockIdx.x;
  __shared__ float yl[1024];
  int t = threadIdx.x, w = t >> 6, l = t & 63;
  for(int d = t; d < 1024; d += 256){
    float v = 0.f;
    for(int s = 0; s < 8; s++) v += zp2[(size_t)s * 131072 + b * 1024 + d];
    yl[d] = fmaxf(v, 0.f) * sc2[d] + sh2[d];
  }
  __syncthreads();
  for(int n = w; n < 10; n += 4){
    float s = 0.f;
    for(int d = l; d < 1024; d += 64) s += yl[d] * W3[d * 10 + n];
    for(int o = 32; o; o >>= 1) s += __shfl_xor(s, o);
    if(l == 0) out[b * 10 + n] = s + b3[n];
  }
}

extern "C" void kernel_launch(void* const* d_in, const int* in_sizes, int n_in,
                              void* d_out, int out_size, void* d_ws, size_t ws_size,
                              hipStream_t stream){
  const float* x    = (const float*)d_in[0];
  const float* pos  = (const float*)d_in[1];
  const float* W0   = (const float*)d_in[3];
  const float* bn0g = (const float*)d_in[4];
  const float* bn0b = (const float*)d_in[5];
  const float* bn0m = (const float*)d_in[6];
  const float* bn0v = (const float*)d_in[7];
  const float* Wg1  = (const float*)d_in[8];
  const float* as1  = (const float*)d_in[9];
  const float* ad1  = (const float*)d_in[10];
  const float* b1   = (const float*)d_in[11];
  const float* Wg2  = (const float*)d_in[12];
  const float* as2  = (const float*)d_in[13];
  const float* ad2  = (const float*)d_in[14];
  const float* b2   = (const float*)d_in[15];
  const float* Wih0 = (const float*)d_in[16];
  const float* Whh0 = (const float*)d_in[17];
  const float* bih0 = (const float*)d_in[18];
  const float* bhh0 = (const float*)d_in[19];
  const float* Wih1 = (const float*)d_in[20];
  const float* Whh1 = (const float*)d_in[21];
  const float* bih1 = (const float*)d_in[22];
  const float* bhh1 = (const float*)d_in[23];
  const float* W2   = (const float*)d_in[24];
  const float* bn2g = (const float*)d_in[25];
  const float* bn2b = (const float*)d_in[26];
  const float* bn2m = (const float*)d_in[27];
  const float* bn2v = (const float*)d_in[28];
  const float* W3   = (const float*)d_in[29];
  const float* b3   = (const float*)d_in[30];

  char* ws = (char*)d_ws;
  u16*   xbf  = (u16*)(ws + O_XBF);
  float* x2   = (float*)(ws + O_XBF);   // alias: x bf16 dead after GEMM1
  u16*   w0t  = (u16*)(ws + O_W0T);
  u16*   wgt  = (u16*)(ws + O_WGT);
  u16*   w2t  = (u16*)(ws + O_W2T);
  u16*   lw0  = (u16*)(ws + O_LW0);
  u16*   lw1  = (u16*)(ws + O_LW1);
  u16*   xb   = (u16*)(ws + O_XB);
  float* h    = (float*)(ws + O_H);
  float* es   = (float*)(ws + O_ES);
  float* ed   = (float*)(ws + O_ED);
  u64*   adjm = (u64*)(ws + O_ADJ);
  float* sc0  = (float*)(ws + O_SC0);
  float* sh0  = (float*)(ws + O_SH0);
  float* sc2  = (float*)(ws + O_SC2);
  float* sh2  = (float*)(ws + O_SH2);
  float* lb0  = (float*)(ws + O_LB0);
  float* lb1  = (float*)(ws + O_LB1);
  // Set2Set scratch lives in the (dead) h region
  char*  s2sb = ws + O_H;
  u16*   ac0  = (u16*)(s2sb + S_AC0);
  u16*   ac1  = (u16*)(s2sb + S_AC1);
  float* c0b  = (float*)(s2sb + S_C0);
  float* c1b  = (float*)(s2sb + S_C1);
  float* h1f  = (float*)(s2sb + S_H1F);
  float* zp   = (float*)(s2sb + S_ZP);

  auto cvtN = [](int rows, int cols){ return (rows * (cols >> 2) + 255) / 256; };

  // --- prep + adjacency + weight conversions ---
  prep<<<16, 256, 0, stream>>>(bn0g, bn0b, bn0m, bn0v, bn2g, bn2b, bn2m, bn2v,
                               bih0, bhh0, bih1, bhh1, sc0, sh0, sc2, sh2, lb0, lb1);
  adj_kernel<<<128, 64, 0, stream>>>(pos, adjm);
  cvt_strided<<<cvtN(8192, 2048), 256, 0, stream>>>(x, xbf, 8192, 2048, 2048, 2048, 0);
  cvt_transpose<<<dim3(64, 64), dim3(32, 8), 0, stream>>>(W0, w0t, 2048, 2048, 2048, 0);
  cvt_transpose<<<dim3(16, 64), dim3(32, 8), 0, stream>>>(Wg1, wgt, 2048, 512, 2048, 0);
  cvt_transpose<<<dim3(16, 64), dim3(32, 8), 0, stream>>>(Wg2, wgt, 2048, 512, 2048, 512);
  cvt_transpose<<<dim3(32, 64), dim3(32, 8), 0, stream>>>(W2, w2t, 2048, 1024, 2048, 0);
  cvt_strided<<<cvtN(4096, 2048), 256, 0, stream>>>(Wih0, lw0, 4096, 2048, 2048, 3072, 0);
  cvt_strided<<<cvtN(4096, 1024), 256, 0, stream>>>(Whh0, lw0, 4096, 1024, 1024, 3072, 2048);
  cvt_strided<<<cvtN(4096, 1024), 256, 0, stream>>>(Wih1, lw1, 4096, 1024, 1024, 2048, 0);
  cvt_strided<<<cvtN(4096, 1024), 256, 0, stream>>>(Whh1, lw1, 4096, 1024, 1024, 2048, 1024);

  // --- GEMM1: xb = bf16(bn0(relu(x @ W0))) ; GAT h = xb @ [Wg1|Wg2] ---
  gemm_bf16<1><<<dim3(64, 16), 256, 0, stream>>>(xbf, w0t, nullptr, xb, sc0, sh0, 8192, 2048, 2048);
  gemm_bf16<0><<<dim3(64, 8), 256, 0, stream>>>(xb, wgt, h, nullptr, nullptr, nullptr, 8192, 1024, 2048);
  // --- GAT attention ---
  gat_scores<<<2048, 256, 0, stream>>>(h, as1, ad1, as2, ad2, es, ed);
  gat_attn2<<<dim3(128, 16), 256, 0, stream>>>(adjm, es, ed, h, b1, b2, x2);

  // --- Set2Set (scratch now occupies the dead h region) ---
  hipMemsetAsync(s2sb, 0, S_ZERO_BYTES, stream);  // acat0, acat1, c0, c1 = 0
  for(int step = 0; step < 2; step++){
    gemm_sk<<<dim3(64, 4), 256, 0, stream>>>(ac0, lw0, zp, 4096, 3072, 3072, 768);
    lstm_gate0<<<512, 256, 0, stream>>>(zp, lb0, c0b, ac0, ac1);
    gemm_sk<<<dim3(64, 4), 256, 0, stream>>>(ac1, lw1, zp, 4096, 2048, 2048, 512);
    lstm_gate1<<<512, 256, 0, stream>>>(zp, lb1, c1b, h1f, ac1);
    s2s_attn<<<128, 256, 0, stream>>>(x2, h1f, ac0);
  }

  // --- lin2 (split-K 8) + lin3 ---
  gemm_sk<<<dim3(16, 8), 256, 0, stream>>>(ac0, w2t, zp, 1024, 3072, 2048, 256);
  lin3<<<128, 256, 0, stream>>>(zp, sc2, sh2, W3, b3, (float*)d_out);
}

// Round 3
// 377.790 us; speedup vs baseline: 4.2183x; 1.5286x over previous
//
#include <hip/hip_runtime.h>
#include <hip/hip_bf16.h>

typedef unsigned short u16;
typedef __attribute__((ext_vector_type(8))) short short8;
typedef __attribute__((ext_vector_type(4))) float f32x4;
typedef unsigned long long u64;

#define DI __device__ __forceinline__

DI u16 f2b(float f){
  unsigned u = __float_as_uint(f);
  unsigned r = 0x7fffu + ((u >> 16) & 1u);
  return (u16)((u + r) >> 16);
}

DI void gl_lds16(const void* g, void* l){
  __builtin_amdgcn_global_load_lds((const __attribute__((address_space(1))) void*)g,
                                   (__attribute__((address_space(3))) void*)l, 16, 0, 0);
}

// ---------------- workspace layout (bytes) ----------------
constexpr size_t O_XBF = 0;                    // 33554432: x bf16 [8192,2048]; later x2 f32 [8192,1024]
constexpr size_t O_W0T = O_XBF + 33554432;     // 8388608:  W0^T bf16 [2048,2048]
constexpr size_t O_WGT = O_W0T + 8388608;      // 4194304:  [Wg1|Wg2]^T bf16 [1024,2048]
constexpr size_t O_W2T = O_WGT + 4194304;      // 4194304:  W2^T bf16 [1024,2048]
constexpr size_t O_LW0 = O_W2T + 4194304;      // 25165824: [Wih0|Whh0] bf16 [4096,3072]
constexpr size_t O_LW1 = O_LW0 + 25165824;     // 16777216: [Wih1|Whh1] bf16 [4096,2048]
constexpr size_t O_XB  = O_LW1 + 16777216;     // 33554432: xb bf16 [8192,2048]
constexpr size_t O_H   = O_XB  + 33554432;     // 33554432: h f32 [8192,1024]; Set2Set scratch after GAT
constexpr size_t O_ES  = O_H   + 33554432;     // 524288
constexpr size_t O_ED  = O_ES  + 524288;       // 524288
constexpr size_t O_ADJ = O_ED  + 524288;       // 65536: adjacency masks [128][64] u64
constexpr size_t O_SC0 = O_ADJ + 65536;        // 8192
constexpr size_t O_SH0 = O_SC0 + 8192;         // 8192
constexpr size_t O_SC2 = O_SH0 + 8192;         // 4096
constexpr size_t O_SH2 = O_SC2 + 4096;         // 4096
constexpr size_t O_LB0 = O_SH2 + 4096;         // 16384
constexpr size_t O_LB1 = O_LB0 + 16384;        // 16384
// Set2Set scratch inside O_H (h is dead after gat_attn2):
constexpr size_t S_AC0 = 0;                    // 786432: acat0 bf16 [128][3072] = [h1(1024) | r(1024) | h0(1024)]... layout: [q_star(2048) | h0(1024)]
constexpr size_t S_AC1 = S_AC0 + 786432;       // 524288: acat1 bf16 [128][2048] = [h0 | h1]
constexpr size_t S_C0  = S_AC1 + 524288;       // 524288
constexpr size_t S_C1  = S_C0  + 524288;       // 524288
constexpr size_t S_ZERO_BYTES = S_C1 + 524288; // zero AC0,AC1,C0,C1 each call
constexpr size_t S_H1F = S_C1  + 524288;       // 524288: h1 f32
constexpr size_t S_ZP  = S_H1F + 524288;       // 8388608: split-K partials
constexpr size_t S_E   = S_ZP  + 8388608;      // 32768: s2s scores e[8192]

// ---------------- converters ----------------
__global__ void cvt_strided(const float* __restrict__ src, u16* __restrict__ dst,
                            int rows, int cols, int sld, int dld, int doff){
  int t = blockIdx.x * 256 + threadIdx.x;
  int cq = cols >> 2;
  int tot = rows * cq;
  if(t >= tot) return;
  int r = t / cq, c4 = (t - r * cq) * 4;
  float4 v = *(const float4*)(src + (size_t)r * sld + c4);
  u16 o[4] = { f2b(v.x), f2b(v.y), f2b(v.z), f2b(v.w) };
  *(ushort4*)(dst + (size_t)r * dld + doff + c4) = *(ushort4*)o;
}

__global__ void cvt_transpose(const float* __restrict__ src, u16* __restrict__ dst,
                              int R, int C, int dld, int droff){
  __shared__ float tile[32][33];
  int c0 = blockIdx.x * 32, r0 = blockIdx.y * 32;
  int tx = threadIdx.x, ty = threadIdx.y;  // (32,8)
  for(int i = 0; i < 4; i++)
    tile[ty + 8*i][tx] = src[(size_t)(r0 + ty + 8*i) * C + c0 + tx];
  __syncthreads();
  for(int i = 0; i < 4; i++)
    dst[(size_t)(droff + c0 + ty + 8*i) * dld + r0 + tx] = f2b(tile[tx][ty + 8*i]);
}

__global__ void prep(const float* g0, const float* b0, const float* m0, const float* v0,
                     const float* g2, const float* b2, const float* m2, const float* v2,
                     const float* bih0, const float* bhh0, const float* bih1, const float* bhh1,
                     float* sc0, float* sh0, float* sc2, float* sh2, float* lb0, float* lb1){
  int t = blockIdx.x * 256 + threadIdx.x;
  if(t < 2048){ float s = g0[t] * rsqrtf(v0[t] + 0.1f); sc0[t] = s; sh0[t] = b0[t] - m0[t] * s; }
  if(t < 1024){ float s = g2[t] * rsqrtf(v2[t] + 0.1f); sc2[t] = s; sh2[t] = b2[t] - m2[t] * s; }
  if(t < 4096){ lb0[t] = bih0[t] + bhh0[t]; lb1[t] = bih1[t] + bhh1[t]; }
}

__global__ void adj_kernel(const float* __restrict__ pos, u64* __restrict__ adjm){
  int b = blockIdx.x, l = threadIdx.x;  // 64 threads
  __shared__ float px[64], py[64];
  float2 p = ((const float2*)pos)[b * 64 + l];
  px[l] = p.x; py[l] = p.y;
  __syncthreads();
  float xi = px[l], yi = py[l];
  u64 m = 0;
  for(int j = 0; j < 64; j++){
    float dx = xi - px[j], dy = yi - py[j];
    if(dx * dx + dy * dy <= 16.0f) m |= (1ull << j);
  }
  adjm[b * 64 + l] = m;
}

// ---------------- bf16 MFMA GEMM (m97 structure) ----------------
template<int MODE>
__global__ __launch_bounds__(256) void gemm_bf16(
    const u16* __restrict__ A, const u16* __restrict__ Bt,
    float* __restrict__ Cf, u16* __restrict__ Cb,
    const float* __restrict__ p1, const float* __restrict__ p2,
    int M, int N, int K)
{
  constexpr int BM = 128, BN = 128, BK = 64;
  __shared__ alignas(16) u16 Al[BM * BK];
  __shared__ alignas(16) u16 Bl[BN * BK];
  int m0 = blockIdx.x * BM, n0 = blockIdx.y * BN;
  int t = threadIdx.x, w = t >> 6, l = t & 63;
  int wm = (w >> 1) * 64, wn = (w & 1) * 64;
  f32x4 acc[4][4];
  for(int a = 0; a < 4; a++) for(int b = 0; b < 4; b++) acc[a][b] = {0.f, 0.f, 0.f, 0.f};

  const short8* Ap = (const short8*)Al;
  const short8* Bp = (const short8*)Bl;

  for(int k0 = 0; k0 < K; k0 += BK){
    #pragma unroll
    for(int u = t; u < BM * 8; u += 256){
      int r = u >> 3, c = u & 7;
      gl_lds16(A + (size_t)(m0 + r) * K + k0 + ((c ^ (r & 7)) << 3), Al + u * 8);
    }
    #pragma unroll
    for(int u = t; u < BN * 8; u += 256){
      int r = u >> 3, c = u & 7;
      gl_lds16(Bt + (size_t)(n0 + r) * K + k0 + ((c ^ (r & 7)) << 3), Bl + u * 8);
    }
    __syncthreads();
    #pragma unroll
    for(int ks = 0; ks < 2; ks++){
      int kc = ks * 4 + (l >> 4);
      short8 av[4], bv[4];
      #pragma unroll
      for(int mi = 0; mi < 4; mi++){ int r = wm + mi * 16 + (l & 15); av[mi] = Ap[r * 8 + (kc ^ (r & 7))]; }
      #pragma unroll
      for(int ni = 0; ni < 4; ni++){ int r = wn + ni * 16 + (l & 15); bv[ni] = Bp[r * 8 + (kc ^ (r & 7))]; }
      #pragma unroll
      for(int mi = 0; mi < 4; mi++)
        #pragma unroll
        for(int ni = 0; ni < 4; ni++)
          acc[mi][ni] = __builtin_amdgcn_mfma_f32_16x16x32_bf16(av[mi], bv[ni], acc[mi][ni], 0, 0, 0);
    }
    __syncthreads();
  }

  int cr = m0 + wm + ((l >> 4) << 2);
  int cc = n0 + wn + (l & 15);
  for(int mi = 0; mi < 4; mi++)
    for(int ni = 0; ni < 4; ni++)
      for(int r = 0; r < 4; r++){
        int row = cr + mi * 16 + r, col = cc + ni * 16;
        float v = acc[mi][ni][r];
        if(MODE == 0) Cf[(size_t)row * N + col] = v;
        else { v = fmaxf(v, 0.f) * p1[col] + p2[col]; Cb[(size_t)row * N + col] = f2b(v); }
      }
}

// ---------------- split-K skinny GEMM: M=128=BM, BN=64; partial s -> Cf + s*128*N ----------------
__global__ __launch_bounds__(256) void gemm_sk(
    const u16* __restrict__ A, const u16* __restrict__ Bt, float* __restrict__ Cf,
    int N, int lda, int ldb, int kPer)
{
  constexpr int BM = 128, BN = 64, BK = 64;
  __shared__ alignas(16) u16 Al[BM * BK];
  __shared__ alignas(16) u16 Bl[BN * BK];
  int n0 = blockIdx.x * BN;
  int kb = blockIdx.y * kPer;
  float* C = Cf + (size_t)blockIdx.y * 128 * N;
  int t = threadIdx.x, w = t >> 6, l = t & 63;
  int wm = (w >> 1) * 64, wn = (w & 1) * 32;
  f32x4 acc[4][2];
  for(int a = 0; a < 4; a++) for(int b = 0; b < 2; b++) acc[a][b] = {0.f, 0.f, 0.f, 0.f};

  const short8* Ap = (const short8*)Al;
  const short8* Bp = (const short8*)Bl;

  for(int k0 = kb; k0 < kb + kPer; k0 += BK){
    #pragma unroll
    for(int u = t; u < BM * 8; u += 256){
      int r = u >> 3, c = u & 7;
      gl_lds16(A + (size_t)r * lda + k0 + ((c ^ (r & 7)) << 3), Al + u * 8);
    }
    #pragma unroll
    for(int u = t; u < BN * 8; u += 256){
      int r = u >> 3, c = u & 7;
      gl_lds16(Bt + (size_t)(n0 + r) * ldb + k0 + ((c ^ (r & 7)) << 3), Bl + u * 8);
    }
    __syncthreads();
    #pragma unroll
    for(int ks = 0; ks < 2; ks++){
      int kc = ks * 4 + (l >> 4);
      short8 av[4], bv[2];
      #pragma unroll
      for(int mi = 0; mi < 4; mi++){ int r = wm + mi * 16 + (l & 15); av[mi] = Ap[r * 8 + (kc ^ (r & 7))]; }
      #pragma unroll
      for(int ni = 0; ni < 2; ni++){ int r = wn + ni * 16 + (l & 15); bv[ni] = Bp[r * 8 + (kc ^ (r & 7))]; }
      #pragma unroll
      for(int mi = 0; mi < 4; mi++)
        #pragma unroll
        for(int ni = 0; ni < 2; ni++)
          acc[mi][ni] = __builtin_amdgcn_mfma_f32_16x16x32_bf16(av[mi], bv[ni], acc[mi][ni], 0, 0, 0);
    }
    __syncthreads();
  }

  int cr = wm + ((l >> 4) << 2);
  int cc = n0 + wn + (l & 15);
  for(int mi = 0; mi < 4; mi++)
    for(int ni = 0; ni < 2; ni++)
      for(int r = 0; r < 4; r++)
        C[(size_t)(cr + mi * 16 + r) * N + cc + ni * 16] = acc[mi][ni][r];
}

// ---------------- GAT attention scores es/ed ----------------
__global__ __launch_bounds__(256) void gat_scores(const float* __restrict__ h,
    const float* __restrict__ as1, const float* __restrict__ ad1,
    const float* __restrict__ as2, const float* __restrict__ ad2,
    float* __restrict__ es, float* __restrict__ ed){
  __shared__ float aS[16][64], aD[16][64];
  int t = threadIdx.x;
  for(int i = t; i < 1024; i += 256){
    int cc = i >> 6, d = i & 63;
    aS[cc][d] = (cc < 8) ? as1[i] : as2[i - 512];
    aD[cc][d] = (cc < 8) ? ad1[i] : ad2[i - 512];
  }
  __syncthreads();
  int w = t >> 6, l = t & 63;
  int node = blockIdx.x * 4 + w;
  const float* hr = h + (size_t)node * 1024;
  for(int cc = 0; cc < 16; cc++){
    float v = hr[cc * 64 + l];
    float ps = v * aS[cc][l], pd = v * aD[cc][l];
    for(int o = 32; o; o >>= 1){ ps += __shfl_down(ps, o); pd += __shfl_down(pd, o); }
    if(l == 0){ es[node * 16 + cc] = ps; ed[node * 16 + cc] = pd; }
  }
}

// ---------------- GAT attention+aggregate: one block per (graph, conv, head) ----------------
__global__ __launch_bounds__(256) void gat_attn2(const u64* __restrict__ adjm,
    const float* __restrict__ es, const float* __restrict__ ed,
    const float* __restrict__ h, const float* __restrict__ b1, const float* __restrict__ b2,
    float* __restrict__ x2){
  int b = blockIdx.x;
  int cv = blockIdx.y >> 3, hh = blockIdx.y & 7;
  __shared__ float hst[64][64];
  __shared__ float alphaL[64][65];
  __shared__ float esl[64], edl[64];
  __shared__ u64 adjs[64];
  int t = threadIdx.x, w = t >> 6, l = t & 63;
  {
    int j = t >> 2, d0 = (t & 3) * 16;
    const float* hr = h + (size_t)(b * 64 + j) * 1024 + cv * 512 + hh * 64 + d0;
    *(float4*)&hst[j][d0]      = *(const float4*)hr;
    *(float4*)&hst[j][d0 + 4]  = *(const float4*)(hr + 4);
    *(float4*)&hst[j][d0 + 8]  = *(const float4*)(hr + 8);
    *(float4*)&hst[j][d0 + 12] = *(const float4*)(hr + 12);
  }
  if(t < 64){
    esl[t] = es[(b * 64 + t) * 16 + cv * 8 + hh];
    edl[t] = ed[(b * 64 + t) * 16 + cv * 8 + hh];
    adjs[t] = adjm[b * 64 + t];
  }
  __syncthreads();
  for(int it = 0; it < 16; it++){
    int i = it * 4 + w;
    bool on = (adjs[i] >> l) & 1;
    float e = edl[i] + esl[l];
    e = e > 0.f ? e : 0.2f * e;
    float mx = on ? e : -1e30f;
    for(int o = 32; o; o >>= 1) mx = fmaxf(mx, __shfl_xor(mx, o));
    float p = on ? __expf(e - mx) : 0.f;
    float s = p;
    for(int o = 32; o; o >>= 1) s += __shfl_xor(s, o);
    alphaL[i][l] = p / s;
  }
  __syncthreads();
  int i = t >> 2, q = t & 3;
  float acc[16];
  #pragma unroll
  for(int k = 0; k < 16; k++) acc[k] = 0.f;
  for(int j = 0; j < 64; j++){
    float al = alphaL[i][j];
    const float* hr = &hst[j][q * 16];
    #pragma unroll
    for(int k = 0; k < 16; k++) acc[k] += al * hr[k];
  }
  const float* bias = (cv ? b2 : b1) + hh * 64 + q * 16;
  float* op = x2 + (size_t)(b * 64 + i) * 1024 + cv * 512 + hh * 64 + q * 16;
  #pragma unroll
  for(int k = 0; k < 16; k++) op[k] = fmaxf(acc[k] + bias[k], 0.f);
}

// ---------------- LSTM gates ----------------
__global__ void lstm_gate0(const float* __restrict__ zp, const float* __restrict__ lb,
                           float* __restrict__ c, u16* __restrict__ ac0, u16* __restrict__ ac1){
  int t = blockIdx.x * 256 + threadIdx.x;  // 128*1024
  int b = t >> 10, j = t & 1023;
  size_t base = (size_t)b * 4096;
  float zi = 0, zf = 0, zg = 0, zo = 0;
  for(int s = 0; s < 4; s++){
    const float* zr = zp + (size_t)s * 524288 + base;
    zi += zr[j]; zf += zr[1024 + j]; zg += zr[2048 + j]; zo += zr[3072 + j];
  }
  zi += lb[j]; zf += lb[1024 + j]; zg += lb[2048 + j]; zo += lb[3072 + j];
  float ci = c[t];
  float si = 1.f / (1.f + __expf(-zi)), sf = 1.f / (1.f + __expf(-zf)), so = 1.f / (1.f + __expf(-zo));
  float cn = sf * ci + si * tanhf(zg);
  c[t] = cn;
  u16 hb = f2b(so * tanhf(cn));
  ac0[(size_t)b * 3072 + 2048 + j] = hb;
  ac1[(size_t)b * 2048 + j] = hb;
}

// writes h1 f32, h1 bf16 into ac1 (lstm input) and ac0 (q_star first half)
__global__ void lstm_gate1(const float* __restrict__ zp, const float* __restrict__ lb,
                           float* __restrict__ c, float* __restrict__ h1f,
                           u16* __restrict__ ac1, u16* __restrict__ ac0){
  int t = blockIdx.x * 256 + threadIdx.x;
  int b = t >> 10, j = t & 1023;
  size_t base = (size_t)b * 4096;
  float zi = 0, zf = 0, zg = 0, zo = 0;
  for(int s = 0; s < 4; s++){
    const float* zr = zp + (size_t)s * 524288 + base;
    zi += zr[j]; zf += zr[1024 + j]; zg += zr[2048 + j]; zo += zr[3072 + j];
  }
  zi += lb[j]; zf += lb[1024 + j]; zg += lb[2048 + j]; zo += lb[3072 + j];
  float ci = c[t];
  float si = 1.f / (1.f + __expf(-zi)), sf = 1.f / (1.f + __expf(-zf)), so = 1.f / (1.f + __expf(-zo));
  float cn = sf * ci + si * tanhf(zg);
  c[t] = cn;
  float hn = so * tanhf(cn);
  h1f[t] = hn;
  u16 hb = f2b(hn);
  ac1[(size_t)b * 2048 + 1024 + j] = hb;
  ac0[(size_t)b * 3072 + j] = hb;
}

// ---------------- Set2Set attention, wide: e[node] = dot(x2[node], h1[graph]) ----------------
__global__ __launch_bounds__(256) void s2s_e(const float* __restrict__ x2,
    const float* __restrict__ h1, float* __restrict__ e){
  int t = threadIdx.x, w = t >> 6, l = t & 63;
  int node = blockIdx.x * 4 + w;
  int b = node >> 6;
  const float4* xr = (const float4*)(x2 + (size_t)node * 1024);
  const float4* hr = (const float4*)(h1 + (size_t)b * 1024);
  float s = 0.f;
  #pragma unroll
  for(int k = 0; k < 4; k++){
    float4 a = xr[l + 64 * k], c = hr[l + 64 * k];
    s += a.x * c.x + a.y * c.y + a.z * c.z + a.w * c.w;
  }
  for(int o = 32; o; o >>= 1) s += __shfl_xor(s, o);
  if(l == 0) e[node] = s;
}

// softmax(e) per graph (recomputed per block, wave 0) + r = sum_j a_j x2[j, slice]
__global__ __launch_bounds__(256) void s2s_r(const float* __restrict__ x2,
    const float* __restrict__ e, u16* __restrict__ ac0){
  int b = blockIdx.x, sl = blockIdx.y;
  __shared__ float al[64];
  int t = threadIdx.x;
  if(t < 64){
    float v = e[b * 64 + t];
    float mx = v;
    for(int o = 32; o; o >>= 1) mx = fmaxf(mx, __shfl_xor(mx, o));
    float p = __expf(v - mx);
    float ss = p;
    for(int o = 32; o; o >>= 1) ss += __shfl_xor(ss, o);
    al[t] = p / ss;
  }
  __syncthreads();
  int d = sl * 256 + t;
  const float* xp = x2 + (size_t)b * 64 * 1024 + d;
  float r = 0.f;
  #pragma unroll 8
  for(int j = 0; j < 64; j++) r += al[j] * xp[j * 1024];
  ac0[(size_t)b * 3072 + 1024 + d] = f2b(r);
}

// ---------------- lin2 combine (8 split partials) + bn + relu + lin3 ----------------
__global__ __launch_bounds__(256) void lin3(const float* __restrict__ zp2,
    const float* __restrict__ sc2, const float* __restrict__ sh2,
    const float* __restrict__ W3, const float* __restrict__ b3, float* __restrict__ out){
  int b = blockIdx.x;
  __shared__ float yl[1024];
  int t = threadIdx.x, w = t >> 6, l = t & 63;
  for(int d = t; d < 1024; d += 256){
    float v = 0.f;
    for(int s = 0; s < 8; s++) v += zp2[(size_t)s * 131072 + b * 1024 + d];
    yl[d] = fmaxf(v, 0.f) * sc2[d] + sh2[d];
  }
  __syncthreads();
  for(int n = w; n < 10; n += 4){
    float s = 0.f;
    for(int d = l; d < 1024; d += 64) s += yl[d] * W3[d * 10 + n];
    for(int o = 32; o; o >>= 1) s += __shfl_xor(s, o);
    if(l == 0) out[b * 10 + n] = s + b3[n];
  }
}

extern "C" void kernel_launch(void* const* d_in, const int* in_sizes, int n_in,
                              void* d_out, int out_size, void* d_ws, size_t ws_size,
                              hipStream_t stream){
  const float* x    = (const float*)d_in[0];
  const float* pos  = (const float*)d_in[1];
  const float* W0   = (const float*)d_in[3];
  const float* bn0g = (const float*)d_in[4];
  const float* bn0b = (const float*)d_in[5];
  const float* bn0m = (const float*)d_in[6];
  const float* bn0v = (const float*)d_in[7];
  const float* Wg1  = (const float*)d_in[8];
  const float* as1  = (const float*)d_in[9];
  const float* ad1  = (const float*)d_in[10];
  const float* b1   = (const float*)d_in[11];
  const float* Wg2  = (const float*)d_in[12];
  const float* as2  = (const float*)d_in[13];
  const float* ad2  = (const float*)d_in[14];
  const float* b2   = (const float*)d_in[15];
  const float* Wih0 = (const float*)d_in[16];
  const float* Whh0 = (const float*)d_in[17];
  const float* bih0 = (const float*)d_in[18];
  const float* bhh0 = (const float*)d_in[19];
  const float* Wih1 = (const float*)d_in[20];
  const float* Whh1 = (const float*)d_in[21];
  const float* bih1 = (const float*)d_in[22];
  const float* bhh1 = (const float*)d_in[23];
  const float* W2   = (const float*)d_in[24];
  const float* bn2g = (const float*)d_in[25];
  const float* bn2b = (const float*)d_in[26];
  const float* bn2m = (const float*)d_in[27];
  const float* bn2v = (const float*)d_in[28];
  const float* W3   = (const float*)d_in[29];
  const float* b3   = (const float*)d_in[30];

  char* ws = (char*)d_ws;
  u16*   xbf  = (u16*)(ws + O_XBF);
  float* x2   = (float*)(ws + O_XBF);   // alias: x bf16 dead after GEMM1
  u16*   w0t  = (u16*)(ws + O_W0T);
  u16*   wgt  = (u16*)(ws + O_WGT);
  u16*   w2t  = (u16*)(ws + O_W2T);
  u16*   lw0  = (u16*)(ws + O_LW0);
  u16*   lw1  = (u16*)(ws + O_LW1);
  u16*   xb   = (u16*)(ws + O_XB);
  float* h    = (float*)(ws + O_H);
  float* es   = (float*)(ws + O_ES);
  float* ed   = (float*)(ws + O_ED);
  u64*   adjm = (u64*)(ws + O_ADJ);
  float* sc0  = (float*)(ws + O_SC0);
  float* sh0  = (float*)(ws + O_SH0);
  float* sc2  = (float*)(ws + O_SC2);
  float* sh2  = (float*)(ws + O_SH2);
  float* lb0  = (float*)(ws + O_LB0);
  float* lb1  = (float*)(ws + O_LB1);
  char*  s2sb = ws + O_H;
  u16*   ac0  = (u16*)(s2sb + S_AC0);
  u16*   ac1  = (u16*)(s2sb + S_AC1);
  float* c0b  = (float*)(s2sb + S_C0);
  float* c1b  = (float*)(s2sb + S_C1);
  float* h1f  = (float*)(s2sb + S_H1F);
  float* zp   = (float*)(s2sb + S_ZP);
  float* ebuf = (float*)(s2sb + S_E);

  auto cvtN = [](int rows, int cols){ return (rows * (cols >> 2) + 255) / 256; };

  // --- prep + adjacency + weight conversions ---
  prep<<<16, 256, 0, stream>>>(bn0g, bn0b, bn0m, bn0v, bn2g, bn2b, bn2m, bn2v,
                               bih0, bhh0, bih1, bhh1, sc0, sh0, sc2, sh2, lb0, lb1);
  adj_kernel<<<128, 64, 0, stream>>>(pos, adjm);
  cvt_strided<<<cvtN(8192, 2048), 256, 0, stream>>>(x, xbf, 8192, 2048, 2048, 2048, 0);
  cvt_transpose<<<dim3(64, 64), dim3(32, 8), 0, stream>>>(W0, w0t, 2048, 2048, 2048, 0);
  cvt_transpose<<<dim3(16, 64), dim3(32, 8), 0, stream>>>(Wg1, wgt, 2048, 512, 2048, 0);
  cvt_transpose<<<dim3(16, 64), dim3(32, 8), 0, stream>>>(Wg2, wgt, 2048, 512, 2048, 512);
  cvt_transpose<<<dim3(32, 64), dim3(32, 8), 0, stream>>>(W2, w2t, 2048, 1024, 2048, 0);
  cvt_strided<<<cvtN(4096, 2048), 256, 0, stream>>>(Wih0, lw0, 4096, 2048, 2048, 3072, 0);
  cvt_strided<<<cvtN(4096, 1024), 256, 0, stream>>>(Whh0, lw0, 4096, 1024, 1024, 3072, 2048);
  cvt_strided<<<cvtN(4096, 1024), 256, 0, stream>>>(Wih1, lw1, 4096, 1024, 1024, 2048, 0);
  cvt_strided<<<cvtN(4096, 1024), 256, 0, stream>>>(Whh1, lw1, 4096, 1024, 1024, 2048, 1024);

  // --- GEMM1 + GAT h ---
  gemm_bf16<1><<<dim3(64, 16), 256, 0, stream>>>(xbf, w0t, nullptr, xb, sc0, sh0, 8192, 2048, 2048);
  gemm_bf16<0><<<dim3(64, 8), 256, 0, stream>>>(xb, wgt, h, nullptr, nullptr, nullptr, 8192, 1024, 2048);
  // --- GAT attention ---
  gat_scores<<<2048, 256, 0, stream>>>(h, as1, ad1, as2, ad2, es, ed);
  gat_attn2<<<dim3(128, 16), 256, 0, stream>>>(adjm, es, ed, h, b1, b2, x2);

  // --- Set2Set ---
  hipMemsetAsync(s2sb, 0, S_ZERO_BYTES, stream);  // acat0, acat1, c0, c1 = 0
  for(int step = 0; step < 2; step++){
    gemm_sk<<<dim3(64, 4), 256, 0, stream>>>(ac0, lw0, zp, 4096, 3072, 3072, 768);
    lstm_gate0<<<512, 256, 0, stream>>>(zp, lb0, c0b, ac0, ac1);
    gemm_sk<<<dim3(64, 4), 256, 0, stream>>>(ac1, lw1, zp, 4096, 2048, 2048, 512);
    lstm_gate1<<<512, 256, 0, stream>>>(zp, lb1, c1b, h1f, ac1, ac0);
    s2s_e<<<2048, 256, 0, stream>>>(x2, h1f, ebuf);
    s2s_r<<<dim3(128, 4), 256, 0, stream>>>(x2, ebuf, ac0);
  }

  // --- lin2 (split-K 8) + lin3 ---
  gemm_sk<<<dim3(16, 8), 256, 0, stream>>>(ac0, w2t, zp, 1024, 3072, 2048, 256);
  lin3<<<128, 256, 0, stream>>>(zp, sc2, sh2, W3, b3, (float*)d_out);
}

// Round 6
// 375.029 us; speedup vs baseline: 4.2494x; 1.0074x over previous
//
#include <hip/hip_runtime.h>
#include <hip/hip_bf16.h>

typedef unsigned short u16;
typedef __attribute__((ext_vector_type(8))) short short8;
typedef __attribute__((ext_vector_type(4))) float f32x4;
typedef unsigned long long u64;

#define DI __device__ __forceinline__

DI u16 f2b(float f){
  unsigned u = __float_as_uint(f);
  unsigned r = 0x7fffu + ((u >> 16) & 1u);
  return (u16)((u + r) >> 16);
}
DI float b2f(u16 u){ return __uint_as_float((unsigned)u << 16); }

DI void gl_lds16(const void* g, void* l){
  __builtin_amdgcn_global_load_lds((const __attribute__((address_space(1))) void*)g,
                                   (__attribute__((address_space(3))) void*)l, 16, 0, 0);
}

// ---------------- workspace layout (bytes) — identical to R3 ----------------
constexpr size_t O_XBF = 0;                    // 33554432: x bf16 [8192,2048]; later x2 f32 [8192,1024]
constexpr size_t O_W0T = O_XBF + 33554432;     // 8388608:  W0^T bf16 [2048,2048]
constexpr size_t O_WGT = O_W0T + 8388608;      // 4194304:  [Wg1|Wg2]^T bf16 [1024,2048]
constexpr size_t O_W2T = O_WGT + 4194304;      // 4194304:  W2^T bf16 [1024,2048]
constexpr size_t O_LW0 = O_W2T + 4194304;      // 25165824: [Wih0|Whh0] bf16 [4096,3072]
constexpr size_t O_LW1 = O_LW0 + 25165824;     // 16777216: [Wih1|Whh1] bf16 [4096,2048]
constexpr size_t O_XB  = O_LW1 + 16777216;     // 33554432: xb bf16 [8192,2048]
constexpr size_t O_H   = O_XB  + 33554432;     // 33554432 region: h bf16 [8192,1024] (16MB used); Set2Set scratch after GAT
constexpr size_t O_ES  = O_H   + 33554432;     // 524288
constexpr size_t O_ED  = O_ES  + 524288;       // 524288
constexpr size_t O_ADJ = O_ED  + 524288;       // 65536: adjacency masks [128][64] u64
constexpr size_t O_SC0 = O_ADJ + 65536;
constexpr size_t O_SH0 = O_SC0 + 8192;
constexpr size_t O_SC2 = O_SH0 + 8192;
constexpr size_t O_SH2 = O_SC2 + 4096;
constexpr size_t O_LB0 = O_SH2 + 4096;
constexpr size_t O_LB1 = O_LB0 + 16384;
// Set2Set scratch inside O_H (h is dead after gat_attn2):
constexpr size_t S_AC0 = 0;                    // 786432: acat0 bf16 [128][3072] = [q_star(2048) | h0(1024)]
constexpr size_t S_AC1 = S_AC0 + 786432;       // 524288: acat1 bf16 [128][2048] = [h0 | h1]
constexpr size_t S_C0  = S_AC1 + 524288;       // 524288
constexpr size_t S_C1  = S_C0  + 524288;       // 524288
constexpr size_t S_ZERO_BYTES = S_C1 + 524288; // zero AC0,AC1,C0,C1 each call
constexpr size_t S_H1F = S_C1  + 524288;       // 524288: h1 f32
constexpr size_t S_ZP  = S_H1F + 524288;       // 8388608: split-K partials
constexpr size_t S_E   = S_ZP  + 8388608;      // 32768: s2s scores e[8192]

// ---------------- converters (R3 verbatim) ----------------
__global__ void cvt_strided(const float* __restrict__ src, u16* __restrict__ dst,
                            int rows, int cols, int sld, int dld, int doff){
  int t = blockIdx.x * 256 + threadIdx.x;
  int cq = cols >> 2;
  int tot = rows * cq;
  if(t >= tot) return;
  int r = t / cq, c4 = (t - r * cq) * 4;
  float4 v = *(const float4*)(src + (size_t)r * sld + c4);
  u16 o[4] = { f2b(v.x), f2b(v.y), f2b(v.z), f2b(v.w) };
  *(ushort4*)(dst + (size_t)r * dld + doff + c4) = *(ushort4*)o;
}

__global__ void cvt_transpose(const float* __restrict__ src, u16* __restrict__ dst,
                              int R, int C, int dld, int droff){
  __shared__ float tile[32][33];
  int c0 = blockIdx.x * 32, r0 = blockIdx.y * 32;
  int tx = threadIdx.x, ty = threadIdx.y;  // (32,8)
  for(int i = 0; i < 4; i++)
    tile[ty + 8*i][tx] = src[(size_t)(r0 + ty + 8*i) * C + c0 + tx];
  __syncthreads();
  for(int i = 0; i < 4; i++)
    dst[(size_t)(droff + c0 + ty + 8*i) * dld + r0 + tx] = f2b(tile[tx][ty + 8*i]);
}

__global__ void prep(const float* g0, const float* b0, const float* m0, const float* v0,
                     const float* g2, const float* b2, const float* m2, const float* v2,
                     const float* bih0, const float* bhh0, const float* bih1, const float* bhh1,
                     float* sc0, float* sh0, float* sc2, float* sh2, float* lb0, float* lb1){
  int t = blockIdx.x * 256 + threadIdx.x;
  if(t < 2048){ float s = g0[t] * rsqrtf(v0[t] + 0.1f); sc0[t] = s; sh0[t] = b0[t] - m0[t] * s; }
  if(t < 1024){ float s = g2[t] * rsqrtf(v2[t] + 0.1f); sc2[t] = s; sh2[t] = b2[t] - m2[t] * s; }
  if(t < 4096){ lb0[t] = bih0[t] + bhh0[t]; lb1[t] = bih1[t] + bhh1[t]; }
}

__global__ void adj_kernel(const float* __restrict__ pos, u64* __restrict__ adjm){
  int b = blockIdx.x, l = threadIdx.x;  // 64 threads
  __shared__ float px[64], py[64];
  float2 p = ((const float2*)pos)[b * 64 + l];
  px[l] = p.x; py[l] = p.y;
  __syncthreads();
  float xi = px[l], yi = py[l];
  u64 m = 0;
  for(int j = 0; j < 64; j++){
    float dx = xi - px[j], dy = yi - py[j];
    if(dx * dx + dy * dy <= 16.0f) m |= (1ull << j);
  }
  adjm[b * 64 + l] = m;
}

// ---------------- bf16 MFMA GEMM (m97 structure, R3 + MODE 3) ----------------
// MODE 1: relu+bn -> bf16 Cb.  MODE 3: plain bf16 Cb.
template<int MODE>
__global__ __launch_bounds__(256) void gemm_bf16(
    const u16* __restrict__ A, const u16* __restrict__ Bt,
    float* __restrict__ Cf, u16* __restrict__ Cb,
    const float* __restrict__ p1, const float* __restrict__ p2,
    int M, int N, int K)
{
  constexpr int BM = 128, BN = 128, BK = 64;
  __shared__ alignas(16) u16 Al[BM * BK];
  __shared__ alignas(16) u16 Bl[BN * BK];
  int m0 = blockIdx.x * BM, n0 = blockIdx.y * BN;
  int t = threadIdx.x, w = t >> 6, l = t & 63;
  int wm = (w >> 1) * 64, wn = (w & 1) * 64;
  f32x4 acc[4][4];
  for(int a = 0; a < 4; a++) for(int b = 0; b < 4; b++) acc[a][b] = {0.f, 0.f, 0.f, 0.f};

  const short8* Ap = (const short8*)Al;
  const short8* Bp = (const short8*)Bl;

  for(int k0 = 0; k0 < K; k0 += BK){
    #pragma unroll
    for(int u = t; u < BM * 8; u += 256){
      int r = u >> 3, c = u & 7;
      gl_lds16(A + (size_t)(m0 + r) * K + k0 + ((c ^ (r & 7)) << 3), Al + u * 8);
    }
    #pragma unroll
    for(int u = t; u < BN * 8; u += 256){
      int r = u >> 3, c = u & 7;
      gl_lds16(Bt + (size_t)(n0 + r) * K + k0 + ((c ^ (r & 7)) << 3), Bl + u * 8);
    }
    __syncthreads();
    #pragma unroll
    for(int ks = 0; ks < 2; ks++){
      int kc = ks * 4 + (l >> 4);
      short8 av[4], bv[4];
      #pragma unroll
      for(int mi = 0; mi < 4; mi++){ int r = wm + mi * 16 + (l & 15); av[mi] = Ap[r * 8 + (kc ^ (r & 7))]; }
      #pragma unroll
      for(int ni = 0; ni < 4; ni++){ int r = wn + ni * 16 + (l & 15); bv[ni] = Bp[r * 8 + (kc ^ (r & 7))]; }
      #pragma unroll
      for(int mi = 0; mi < 4; mi++)
        #pragma unroll
        for(int ni = 0; ni < 4; ni++)
          acc[mi][ni] = __builtin_amdgcn_mfma_f32_16x16x32_bf16(av[mi], bv[ni], acc[mi][ni], 0, 0, 0);
    }
    __syncthreads();
  }

  int cr = m0 + wm + ((l >> 4) << 2);
  int cc = n0 + wn + (l & 15);
  for(int mi = 0; mi < 4; mi++)
    for(int ni = 0; ni < 4; ni++)
      for(int r = 0; r < 4; r++){
        int row = cr + mi * 16 + r, col = cc + ni * 16;
        float v = acc[mi][ni][r];
        if(MODE == 1){ v = fmaxf(v, 0.f) * p1[col] + p2[col]; Cb[(size_t)row * N + col] = f2b(v); }
        else if(MODE == 3){ Cb[(size_t)row * N + col] = f2b(v); }
        else { Cf[(size_t)row * N + col] = v; }
      }
}

// ---------------- split-K skinny GEMM (R3 verbatim) ----------------
__global__ __launch_bounds__(256) void gemm_sk(
    const u16* __restrict__ A, const u16* __restrict__ Bt, float* __restrict__ Cf,
    int N, int lda, int ldb, int kPer)
{
  constexpr int BM = 128, BN = 64, BK = 64;
  __shared__ alignas(16) u16 Al[BM * BK];
  __shared__ alignas(16) u16 Bl[BN * BK];
  int n0 = blockIdx.x * BN;
  int kb = blockIdx.y * kPer;
  float* C = Cf + (size_t)blockIdx.y * 128 * N;
  int t = threadIdx.x, w = t >> 6, l = t & 63;
  int wm = (w >> 1) * 64, wn = (w & 1) * 32;
  f32x4 acc[4][2];
  for(int a = 0; a < 4; a++) for(int b = 0; b < 2; b++) acc[a][b] = {0.f, 0.f, 0.f, 0.f};

  const short8* Ap = (const short8*)Al;
  const short8* Bp = (const short8*)Bl;

  for(int k0 = kb; k0 < kb + kPer; k0 += BK){
    #pragma unroll
    for(int u = t; u < BM * 8; u += 256){
      int r = u >> 3, c = u & 7;
      gl_lds16(A + (size_t)r * lda + k0 + ((c ^ (r & 7)) << 3), Al + u * 8);
    }
    #pragma unroll
    for(int u = t; u < BN * 8; u += 256){
      int r = u >> 3, c = u & 7;
      gl_lds16(Bt + (size_t)(n0 + r) * ldb + k0 + ((c ^ (r & 7)) << 3), Bl + u * 8);
    }
    __syncthreads();
    #pragma unroll
    for(int ks = 0; ks < 2; ks++){
      int kc = ks * 4 + (l >> 4);
      short8 av[4], bv[2];
      #pragma unroll
      for(int mi = 0; mi < 4; mi++){ int r = wm + mi * 16 + (l & 15); av[mi] = Ap[r * 8 + (kc ^ (r & 7))]; }
      #pragma unroll
      for(int ni = 0; ni < 2; ni++){ int r = wn + ni * 16 + (l & 15); bv[ni] = Bp[r * 8 + (kc ^ (r & 7))]; }
      #pragma unroll
      for(int mi = 0; mi < 4; mi++)
        #pragma unroll
        for(int ni = 0; ni < 2; ni++)
          acc[mi][ni] = __builtin_amdgcn_mfma_f32_16x16x32_bf16(av[mi], bv[ni], acc[mi][ni], 0, 0, 0);
    }
    __syncthreads();
  }

  int cr = wm + ((l >> 4) << 2);
  int cc = n0 + wn + (l & 15);
  for(int mi = 0; mi < 4; mi++)
    for(int ni = 0; ni < 2; ni++)
      for(int r = 0; r < 4; r++)
        C[(size_t)(cr + mi * 16 + r) * N + cc + ni * 16] = acc[mi][ni][r];
}

// ---------------- GAT attention scores es/ed (R3, h now bf16 via scalar loads) ----------------
__global__ __launch_bounds__(256) void gat_scores(const u16* __restrict__ h,
    const float* __restrict__ as1, const float* __restrict__ ad1,
    const float* __restrict__ as2, const float* __restrict__ ad2,
    float* __restrict__ es, float* __restrict__ ed){
  __shared__ float aS[16][64], aD[16][64];
  int t = threadIdx.x;
  for(int i = t; i < 1024; i += 256){
    int cc = i >> 6, d = i & 63;
    aS[cc][d] = (cc < 8) ? as1[i] : as2[i - 512];
    aD[cc][d] = (cc < 8) ? ad1[i] : ad2[i - 512];
  }
  __syncthreads();
  int w = t >> 6, l = t & 63;
  int node = blockIdx.x * 4 + w;
  const u16* hr = h + (size_t)node * 1024;
  for(int cc = 0; cc < 16; cc++){
    float v = b2f(hr[cc * 64 + l]);
    float ps = v * aS[cc][l], pd = v * aD[cc][l];
    for(int o = 32; o; o >>= 1){ ps += __shfl_down(ps, o); pd += __shfl_down(pd, o); }
    if(l == 0){ es[node * 16 + cc] = ps; ed[node * 16 + cc] = pd; }
  }
}

// ---------------- GAT attention+aggregate (R3, staging now scalar bf16 loads) ----------------
__global__ __launch_bounds__(256) void gat_attn2(const u64* __restrict__ adjm,
    const float* __restrict__ es, const float* __restrict__ ed,
    const u16* __restrict__ h, const float* __restrict__ b1, const float* __restrict__ b2,
    float* __restrict__ x2){
  int b = blockIdx.x;
  int cv = blockIdx.y >> 3, hh = blockIdx.y & 7;
  __shared__ float hst[64][64];
  __shared__ float alphaL[64][65];
  __shared__ float esl[64], edl[64];
  __shared__ u64 adjs[64];
  int t = threadIdx.x, w = t >> 6, l = t & 63;
  {
    int j = t >> 2, d0 = (t & 3) * 16;
    const u16* hr = h + (size_t)(b * 64 + j) * 1024 + cv * 512 + hh * 64 + d0;
    #pragma unroll
    for(int k = 0; k < 16; k++) hst[j][d0 + k] = b2f(hr[k]);
  }
  if(t < 64){
    esl[t] = es[(b * 64 + t) * 16 + cv * 8 + hh];
    edl[t] = ed[(b * 64 + t) * 16 + cv * 8 + hh];
    adjs[t] = adjm[b * 64 + t];
  }
  __syncthreads();
  for(int it = 0; it < 16; it++){
    int i = it * 4 + w;
    bool on = (adjs[i] >> l) & 1;
    float e = edl[i] + esl[l];
    e = e > 0.f ? e : 0.2f * e;
    float mx = on ? e : -1e30f;
    for(int o = 32; o; o >>= 1) mx = fmaxf(mx, __shfl_xor(mx, o));
    float p = on ? __expf(e - mx) : 0.f;
    float s = p;
    for(int o = 32; o; o >>= 1) s += __shfl_xor(s, o);
    alphaL[i][l] = p / s;
  }
  __syncthreads();
  int i = t >> 2, q = t & 3;
  float acc[16];
  #pragma unroll
  for(int k = 0; k < 16; k++) acc[k] = 0.f;
  for(int j = 0; j < 64; j++){
    float al = alphaL[i][j];
    const float* hr = &hst[j][q * 16];
    #pragma unroll
    for(int k = 0; k < 16; k++) acc[k] += al * hr[k];
  }
  const float* bias = (cv ? b2 : b1) + hh * 64 + q * 16;
  float* op = x2 + (size_t)(b * 64 + i) * 1024 + cv * 512 + hh * 64 + q * 16;
  #pragma unroll
  for(int k = 0; k < 16; k += 4){
    float4 o;
    o.x = fmaxf(acc[k] + bias[k], 0.f);
    o.y = fmaxf(acc[k+1] + bias[k+1], 0.f);
    o.z = fmaxf(acc[k+2] + bias[k+2], 0.f);
    o.w = fmaxf(acc[k+3] + bias[k+3], 0.f);
    *(float4*)(op + k) = o;
  }
}

// ---------------- LSTM gates (R3 verbatim) ----------------
__global__ void lstm_gate0(const float* __restrict__ zp, const float* __restrict__ lb,
                           float* __restrict__ c, u16* __restrict__ ac0, u16* __restrict__ ac1){
  int t = blockIdx.x * 256 + threadIdx.x;  // 128*1024
  int b = t >> 10, j = t & 1023;
  size_t base = (size_t)b * 4096;
  float zi = 0, zf = 0, zg = 0, zo = 0;
  for(int s = 0; s < 4; s++){
    const float* zr = zp + (size_t)s * 524288 + base;
    zi += zr[j]; zf += zr[1024 + j]; zg += zr[2048 + j]; zo += zr[3072 + j];
  }
  zi += lb[j]; zf += lb[1024 + j]; zg += lb[2048 + j]; zo += lb[3072 + j];
  float ci = c[t];
  float si = 1.f / (1.f + __expf(-zi)), sf = 1.f / (1.f + __expf(-zf)), so = 1.f / (1.f + __expf(-zo));
  float cn = sf * ci + si * tanhf(zg);
  c[t] = cn;
  u16 hb = f2b(so * tanhf(cn));
  ac0[(size_t)b * 3072 + 2048 + j] = hb;
  ac1[(size_t)b * 2048 + j] = hb;
}

__global__ void lstm_gate1(const float* __restrict__ zp, const float* __restrict__ lb,
                           float* __restrict__ c, float* __restrict__ h1f,
                           u16* __restrict__ ac1, u16* __restrict__ ac0){
  int t = blockIdx.x * 256 + threadIdx.x;
  int b = t >> 10, j = t & 1023;
  size_t base = (size_t)b * 4096;
  float zi = 0, zf = 0, zg = 0, zo = 0;
  for(int s = 0; s < 4; s++){
    const float* zr = zp + (size_t)s * 524288 + base;
    zi += zr[j]; zf += zr[1024 + j]; zg += zr[2048 + j]; zo += zr[3072 + j];
  }
  zi += lb[j]; zf += lb[1024 + j]; zg += lb[2048 + j]; zo += lb[3072 + j];
  float ci = c[t];
  float si = 1.f / (1.f + __expf(-zi)), sf = 1.f / (1.f + __expf(-zf)), so = 1.f / (1.f + __expf(-zo));
  float cn = sf * ci + si * tanhf(zg);
  c[t] = cn;
  float hn = so * tanhf(cn);
  h1f[t] = hn;
  u16 hb = f2b(hn);
  ac1[(size_t)b * 2048 + 1024 + j] = hb;
  ac0[(size_t)b * 3072 + j] = hb;
}

// ---------------- Set2Set attention (R3 verbatim, f32 x2) ----------------
__global__ __launch_bounds__(256) void s2s_e(const float* __restrict__ x2,
    const float* __restrict__ h1, float* __restrict__ e){
  int t = threadIdx.x, w = t >> 6, l = t & 63;
  int node = blockIdx.x * 4 + w;
  int b = node >> 6;
  const float4* xr = (const float4*)(x2 + (size_t)node * 1024);
  const float4* hr = (const float4*)(h1 + (size_t)b * 1024);
  float s = 0.f;
  #pragma unroll
  for(int k = 0; k < 4; k++){
    float4 a = xr[l + 64 * k], c = hr[l + 64 * k];
    s += a.x * c.x + a.y * c.y + a.z * c.z + a.w * c.w;
  }
  for(int o = 32; o; o >>= 1) s += __shfl_xor(s, o);
  if(l == 0) e[node] = s;
}

__global__ __launch_bounds__(256) void s2s_r(const float* __restrict__ x2,
    const float* __restrict__ e, u16* __restrict__ ac0){
  int b = blockIdx.x, sl = blockIdx.y;
  __shared__ float al[64];
  int t = threadIdx.x;
  if(t < 64){
    float v = e[b * 64 + t];
    float mx = v;
    for(int o = 32; o; o >>= 1) mx = fmaxf(mx, __shfl_xor(mx, o));
    float p = __expf(v - mx);
    float ss = p;
    for(int o = 32; o; o >>= 1) ss += __shfl_xor(ss, o);
    al[t] = p / ss;
  }
  __syncthreads();
  int d = sl * 256 + t;
  const float* xp = x2 + (size_t)b * 64 * 1024 + d;
  float r = 0.f;
  #pragma unroll 8
  for(int j = 0; j < 64; j++) r += al[j] * xp[j * 1024];
  ac0[(size_t)b * 3072 + 1024 + d] = f2b(r);
}

// ---------------- lin2 combine + bn + relu + lin3 (R3 verbatim) ----------------
__global__ __launch_bounds__(256) void lin3(const float* __restrict__ zp2,
    const float* __restrict__ sc2, const float* __restrict__ sh2,
    const float* __restrict__ W3, const float* __restrict__ b3, float* __restrict__ out){
  int b = blockIdx.x;
  __shared__ float yl[1024];
  int t = threadIdx.x, w = t >> 6, l = t & 63;
  for(int d = t; d < 1024; d += 256){
    float v = 0.f;
    for(int s = 0; s < 8; s++) v += zp2[(size_t)s * 131072 + b * 1024 + d];
    yl[d] = fmaxf(v, 0.f) * sc2[d] + sh2[d];
  }
  __syncthreads();
  for(int n = w; n < 10; n += 4){
    float s = 0.f;
    for(int d = l; d < 1024; d += 64) s += yl[d] * W3[d * 10 + n];
    for(int o = 32; o; o >>= 1) s += __shfl_xor(s, o);
    if(l == 0) out[b * 10 + n] = s + b3[n];
  }
}

extern "C" void kernel_launch(void* const* d_in, const int* in_sizes, int n_in,
                              void* d_out, int out_size, void* d_ws, size_t ws_size,
                              hipStream_t stream){
  const float* x    = (const float*)d_in[0];
  const float* pos  = (const float*)d_in[1];
  const float* W0   = (const float*)d_in[3];
  const float* bn0g = (const float*)d_in[4];
  const float* bn0b = (const float*)d_in[5];
  const float* bn0m = (const float*)d_in[6];
  const float* bn0v = (const float*)d_in[7];
  const float* Wg1  = (const float*)d_in[8];
  const float* as1  = (const float*)d_in[9];
  const float* ad1  = (const float*)d_in[10];
  const float* b1   = (const float*)d_in[11];
  const float* Wg2  = (const float*)d_in[12];
  const float* as2  = (const float*)d_in[13];
  const float* ad2  = (const float*)d_in[14];
  const float* b2   = (const float*)d_in[15];
  const float* Wih0 = (const float*)d_in[16];
  const float* Whh0 = (const float*)d_in[17];
  const float* bih0 = (const float*)d_in[18];
  const float* bhh0 = (const float*)d_in[19];
  const float* Wih1 = (const float*)d_in[20];
  const float* Whh1 = (const float*)d_in[21];
  const float* bih1 = (const float*)d_in[22];
  const float* bhh1 = (const float*)d_in[23];
  const float* W2   = (const float*)d_in[24];
  const float* bn2g = (const float*)d_in[25];
  const float* bn2b = (const float*)d_in[26];
  const float* bn2m = (const float*)d_in[27];
  const float* bn2v = (const float*)d_in[28];
  const float* W3   = (const float*)d_in[29];
  const float* b3   = (const float*)d_in[30];

  char* ws = (char*)d_ws;
  u16*   xbf  = (u16*)(ws + O_XBF);
  float* x2   = (float*)(ws + O_XBF);   // alias: x bf16 dead after GEMM1
  u16*   w0t  = (u16*)(ws + O_W0T);
  u16*   wgt  = (u16*)(ws + O_WGT);
  u16*   w2t  = (u16*)(ws + O_W2T);
  u16*   lw0  = (u16*)(ws + O_LW0);
  u16*   lw1  = (u16*)(ws + O_LW1);
  u16*   xb   = (u16*)(ws + O_XB);
  u16*   hb   = (u16*)(ws + O_H);      // h bf16 (first 16MB of O_H region)
  float* es   = (float*)(ws + O_ES);
  float* ed   = (float*)(ws + O_ED);
  u64*   adjm = (u64*)(ws + O_ADJ);
  float* sc0  = (float*)(ws + O_SC0);
  float* sh0  = (float*)(ws + O_SH0);
  float* sc2  = (float*)(ws + O_SC2);
  float* sh2  = (float*)(ws + O_SH2);
  float* lb0  = (float*)(ws + O_LB0);
  float* lb1  = (float*)(ws + O_LB1);
  char*  s2sb = ws + O_H;               // s2s scratch overlays h after GAT
  u16*   ac0  = (u16*)(s2sb + S_AC0);
  u16*   ac1  = (u16*)(s2sb + S_AC1);
  float* c0b  = (float*)(s2sb + S_C0);
  float* c1b  = (float*)(s2sb + S_C1);
  float* h1f  = (float*)(s2sb + S_H1F);
  float* zp   = (float*)(s2sb + S_ZP);
  float* ebuf = (float*)(s2sb + S_E);

  auto cvtN = [](int rows, int cols){ return (rows * (cols >> 2) + 255) / 256; };

  // --- prep + adjacency + weight conversions (R3 verbatim) ---
  prep<<<16, 256, 0, stream>>>(bn0g, bn0b, bn0m, bn0v, bn2g, bn2b, bn2m, bn2v,
                               bih0, bhh0, bih1, bhh1, sc0, sh0, sc2, sh2, lb0, lb1);
  adj_kernel<<<128, 64, 0, stream>>>(pos, adjm);
  cvt_strided<<<cvtN(8192, 2048), 256, 0, stream>>>(x, xbf, 8192, 2048, 2048, 2048, 0);
  cvt_transpose<<<dim3(64, 64), dim3(32, 8), 0, stream>>>(W0, w0t, 2048, 2048, 2048, 0);
  cvt_transpose<<<dim3(16, 64), dim3(32, 8), 0, stream>>>(Wg1, wgt, 2048, 512, 2048, 0);
  cvt_transpose<<<dim3(16, 64), dim3(32, 8), 0, stream>>>(Wg2, wgt, 2048, 512, 2048, 512);
  cvt_transpose<<<dim3(32, 64), dim3(32, 8), 0, stream>>>(W2, w2t, 2048, 1024, 2048, 0);
  cvt_strided<<<cvtN(4096, 2048), 256, 0, stream>>>(Wih0, lw0, 4096, 2048, 2048, 3072, 0);
  cvt_strided<<<cvtN(4096, 1024), 256, 0, stream>>>(Whh0, lw0, 4096, 1024, 1024, 3072, 2048);
  cvt_strided<<<cvtN(4096, 1024), 256, 0, stream>>>(Wih1, lw1, 4096, 1024, 1024, 2048, 0);
  cvt_strided<<<cvtN(4096, 1024), 256, 0, stream>>>(Whh1, lw1, 4096, 1024, 1024, 2048, 1024);

  // --- GEMM1: xb = bf16(bn0(relu(x @ W0))) ; GAT h = xb @ [Wg1|Wg2] (bf16 out) ---
  gemm_bf16<1><<<dim3(64, 16), 256, 0, stream>>>(xbf, w0t, nullptr, xb, sc0, sh0, 8192, 2048, 2048);
  gemm_bf16<3><<<dim3(64, 8), 256, 0, stream>>>(xb, wgt, nullptr, hb, nullptr, nullptr, 8192, 1024, 2048);
  // --- GAT attention ---
  gat_scores<<<2048, 256, 0, stream>>>(hb, as1, ad1, as2, ad2, es, ed);
  gat_attn2<<<dim3(128, 16), 256, 0, stream>>>(adjm, es, ed, hb, b1, b2, x2);

  // --- Set2Set (scratch overlays dead h region) ---
  hipMemsetAsync(s2sb, 0, S_ZERO_BYTES, stream);  // acat0, acat1, c0, c1 = 0
  for(int step = 0; step < 2; step++){
    gemm_sk<<<dim3(64, 4), 256, 0, stream>>>(ac0, lw0, zp, 4096, 3072, 3072, 768);
    lstm_gate0<<<512, 256, 0, stream>>>(zp, lb0, c0b, ac0, ac1);
    gemm_sk<<<dim3(64, 4), 256, 0, stream>>>(ac1, lw1, zp, 4096, 2048, 2048, 512);
    lstm_gate1<<<512, 256, 0, stream>>>(zp, lb1, c1b, h1f, ac1, ac0);
    s2s_e<<<2048, 256, 0, stream>>>(x2, h1f, ebuf);
    s2s_r<<<dim3(128, 4), 256, 0, stream>>>(x2, ebuf, ac0);
  }

  // --- lin2 (split-K 8) + lin3 ---
  gemm_sk<<<dim3(16, 8), 256, 0, stream>>>(ac0, w2t, zp, 1024, 3072, 2048, 256);
  lin3<<<128, 256, 0, stream>>>(zp, sc2, sh2, W3, b3, (float*)d_out);
}

// Round 7
// 364.626 us; speedup vs baseline: 4.3706x; 1.0285x over previous
//
#include <hip/hip_runtime.h>
#include <hip/hip_bf16.h>

typedef unsigned short u16;
typedef __attribute__((ext_vector_type(8))) short short8;
typedef __attribute__((ext_vector_type(4))) float f32x4;
typedef unsigned long long u64;

#define DI __device__ __forceinline__

DI u16 f2b(float f){
  unsigned u = __float_as_uint(f);
  unsigned r = 0x7fffu + ((u >> 16) & 1u);
  return (u16)((u + r) >> 16);
}
DI float b2f(u16 u){ return __uint_as_float((unsigned)u << 16); }

DI void gl_lds16(const void* g, void* l){
  __builtin_amdgcn_global_load_lds((const __attribute__((address_space(1))) void*)g,
                                   (__attribute__((address_space(3))) void*)l, 16, 0, 0);
}

// ---------------- workspace layout (bytes) ----------------
constexpr size_t O_XBF = 0;                    // 33554432: x bf16 [8192,2048]; later x2 f32 [8192,1024]
constexpr size_t O_W0T = O_XBF + 33554432;     // 8388608:  W0^T bf16 [2048,2048]
constexpr size_t O_WGT = O_W0T + 8388608;      // 4194304:  [Wg1|Wg2]^T bf16 [1024,2048]
constexpr size_t O_W2T = O_WGT + 4194304;      // 4194304:  W2^T bf16 [1024,2048]
constexpr size_t O_LW0 = O_W2T + 4194304;      // 25165824: [Wih0|Whh0] bf16 [4096,3072]
constexpr size_t O_LW1 = O_LW0 + 25165824;     // 16777216: [Wih1|Whh1] bf16 [4096,2048]
constexpr size_t O_XB  = O_LW1 + 16777216;     // 33554432: xb bf16 [8192,2048]
constexpr size_t O_H   = O_XB  + 33554432;     // region: h bf16 [8192,1024] (16MB); Set2Set scratch after GAT
constexpr size_t O_ES  = O_H   + 33554432;     // 524288
constexpr size_t O_ED  = O_ES  + 524288;       // 524288
constexpr size_t O_ADJ = O_ED  + 524288;       // 65536
constexpr size_t O_SC0 = O_ADJ + 65536;
constexpr size_t O_SH0 = O_SC0 + 8192;
constexpr size_t O_SC2 = O_SH0 + 8192;
constexpr size_t O_SH2 = O_SC2 + 4096;
constexpr size_t O_LB0 = O_SH2 + 4096;
constexpr size_t O_LB1 = O_LB0 + 16384;
// Set2Set scratch inside O_H (h is dead after gat_attn2):
constexpr size_t S_AC0 = 0;                    // 786432: acat0 bf16 [128][3072] = [q_star(2048) | h0(1024)]
constexpr size_t S_AC1 = S_AC0 + 786432;       // 524288: acat1 bf16 [128][2048] = [h0 | h1]
constexpr size_t S_C0  = S_AC1 + 524288;       // 524288
constexpr size_t S_C1  = S_C0  + 524288;       // 524288
constexpr size_t S_ZERO_BYTES = S_C1 + 524288;
constexpr size_t S_H1F = S_C1  + 524288;       // 524288: h1 f32
constexpr size_t S_ZP  = S_H1F + 524288;       // 16777216: split-K partials (8 x [128*4096] f32)
constexpr size_t S_E   = S_ZP  + 16777216;     // 32768: s2s scores e[8192]

// ---------------- fused big converters (5 strided f32->bf16 copies) ----------------
__global__ __launch_bounds__(256) void cvt_big(
    const float* __restrict__ x, const float* __restrict__ Wih0, const float* __restrict__ Whh0,
    const float* __restrict__ Wih1, const float* __restrict__ Whh1,
    u16* __restrict__ xbf, u16* __restrict__ lw0, u16* __restrict__ lw1){
  int bx = blockIdx.x;
  int idx, cq, dld, doff;
  const float* src; u16* dst;
  if(bx < 16384){      src = x;    dst = xbf; idx = bx * 256 + threadIdx.x;            cq = 512; dld = 2048; doff = 0; }
  else if(bx < 24576){ src = Wih0; dst = lw0; idx = (bx - 16384) * 256 + threadIdx.x;  cq = 512; dld = 3072; doff = 0; }
  else if(bx < 28672){ src = Whh0; dst = lw0; idx = (bx - 24576) * 256 + threadIdx.x;  cq = 256; dld = 3072; doff = 2048; }
  else if(bx < 32768){ src = Wih1; dst = lw1; idx = (bx - 28672) * 256 + threadIdx.x;  cq = 256; dld = 2048; doff = 0; }
  else {               src = Whh1; dst = lw1; idx = (bx - 32768) * 256 + threadIdx.x;  cq = 256; dld = 2048; doff = 1024; }
  int r = idx / cq, c4 = (idx - r * cq) << 2;
  float4 v = *(const float4*)(src + (size_t)r * (cq << 2) + c4);
  u16 o[4] = { f2b(v.x), f2b(v.y), f2b(v.z), f2b(v.w) };
  *(ushort4*)(dst + (size_t)r * dld + doff + c4) = *(ushort4*)o;
}

// ---------------- fused f32->bf16 transposes: W0, Wg1, Wg2, W2 ----------------
__global__ void cvt_tr(const float* __restrict__ W0, const float* __restrict__ Wg1,
                       const float* __restrict__ Wg2, const float* __restrict__ W2,
                       u16* __restrict__ w0t, u16* __restrict__ wgt, u16* __restrict__ w2t){
  __shared__ float tile[32][33];
  int bx = blockIdx.x;
  const float* src; u16* dst; int C, droff;
  if(bx < 64){      src = W0;  dst = w0t; C = 2048; droff = 0; }
  else if(bx < 80){ src = Wg1; dst = wgt; C = 512;  droff = 0;   bx -= 64; }
  else if(bx < 96){ src = Wg2; dst = wgt; C = 512;  droff = 512; bx -= 80; }
  else {            src = W2;  dst = w2t; C = 1024; droff = 0;   bx -= 96; }
  int c0 = bx * 32, r0 = blockIdx.y * 32;
  int tx = threadIdx.x, ty = threadIdx.y;  // (32,8)
  for(int i = 0; i < 4; i++)
    tile[ty + 8*i][tx] = src[(size_t)(r0 + ty + 8*i) * C + c0 + tx];
  __syncthreads();
  for(int i = 0; i < 4; i++)
    dst[(size_t)(droff + c0 + ty + 8*i) * 2048 + r0 + tx] = f2b(tile[tx][ty + 8*i]);
}

__global__ void prep(const float* g0, const float* b0, const float* m0, const float* v0,
                     const float* g2, const float* b2, const float* m2, const float* v2,
                     const float* bih0, const float* bhh0, const float* bih1, const float* bhh1,
                     float* sc0, float* sh0, float* sc2, float* sh2, float* lb0, float* lb1){
  int t = blockIdx.x * 256 + threadIdx.x;
  if(t < 2048){ float s = g0[t] * rsqrtf(v0[t] + 0.1f); sc0[t] = s; sh0[t] = b0[t] - m0[t] * s; }
  if(t < 1024){ float s = g2[t] * rsqrtf(v2[t] + 0.1f); sc2[t] = s; sh2[t] = b2[t] - m2[t] * s; }
  if(t < 4096){ lb0[t] = bih0[t] + bhh0[t]; lb1[t] = bih1[t] + bhh1[t]; }
}

__global__ void adj_kernel(const float* __restrict__ pos, u64* __restrict__ adjm){
  int b = blockIdx.x, l = threadIdx.x;  // 64 threads
  __shared__ float px[64], py[64];
  float2 p = ((const float2*)pos)[b * 64 + l];
  px[l] = p.x; py[l] = p.y;
  __syncthreads();
  float xi = px[l], yi = py[l];
  u64 m = 0;
  for(int j = 0; j < 64; j++){
    float dx = xi - px[j], dy = yi - py[j];
    if(dx * dx + dy * dy <= 16.0f) m |= (1ull << j);
  }
  adjm[b * 64 + l] = m;
}

// ---------------- bf16 MFMA GEMM (m97 structure) ----------------
// MODE 1: relu+bn -> bf16 Cb.  MODE 3: plain bf16 Cb.
template<int MODE>
__global__ __launch_bounds__(256) void gemm_bf16(
    const u16* __restrict__ A, const u16* __restrict__ Bt,
    float* __restrict__ Cf, u16* __restrict__ Cb,
    const float* __restrict__ p1, const float* __restrict__ p2,
    int M, int N, int K)
{
  constexpr int BM = 128, BN = 128, BK = 64;
  __shared__ alignas(16) u16 Al[BM * BK];
  __shared__ alignas(16) u16 Bl[BN * BK];
  int m0 = blockIdx.x * BM, n0 = blockIdx.y * BN;
  int t = threadIdx.x, w = t >> 6, l = t & 63;
  int wm = (w >> 1) * 64, wn = (w & 1) * 64;
  f32x4 acc[4][4];
  for(int a = 0; a < 4; a++) for(int b = 0; b < 4; b++) acc[a][b] = {0.f, 0.f, 0.f, 0.f};

  const short8* Ap = (const short8*)Al;
  const short8* Bp = (const short8*)Bl;

  for(int k0 = 0; k0 < K; k0 += BK){
    #pragma unroll
    for(int u = t; u < BM * 8; u += 256){
      int r = u >> 3, c = u & 7;
      gl_lds16(A + (size_t)(m0 + r) * K + k0 + ((c ^ (r & 7)) << 3), Al + u * 8);
    }
    #pragma unroll
    for(int u = t; u < BN * 8; u += 256){
      int r = u >> 3, c = u & 7;
      gl_lds16(Bt + (size_t)(n0 + r) * K + k0 + ((c ^ (r & 7)) << 3), Bl + u * 8);
    }
    __syncthreads();
    #pragma unroll
    for(int ks = 0; ks < 2; ks++){
      int kc = ks * 4 + (l >> 4);
      short8 av[4], bv[4];
      #pragma unroll
      for(int mi = 0; mi < 4; mi++){ int r = wm + mi * 16 + (l & 15); av[mi] = Ap[r * 8 + (kc ^ (r & 7))]; }
      #pragma unroll
      for(int ni = 0; ni < 4; ni++){ int r = wn + ni * 16 + (l & 15); bv[ni] = Bp[r * 8 + (kc ^ (r & 7))]; }
      #pragma unroll
      for(int mi = 0; mi < 4; mi++)
        #pragma unroll
        for(int ni = 0; ni < 4; ni++)
          acc[mi][ni] = __builtin_amdgcn_mfma_f32_16x16x32_bf16(av[mi], bv[ni], acc[mi][ni], 0, 0, 0);
    }
    __syncthreads();
  }

  int cr = m0 + wm + ((l >> 4) << 2);
  int cc = n0 + wn + (l & 15);
  for(int mi = 0; mi < 4; mi++)
    for(int ni = 0; ni < 4; ni++)
      for(int r = 0; r < 4; r++){
        int row = cr + mi * 16 + r, col = cc + ni * 16;
        float v = acc[mi][ni][r];
        if(MODE == 1){ v = fmaxf(v, 0.f) * p1[col] + p2[col]; Cb[(size_t)row * N + col] = f2b(v); }
        else if(MODE == 3){ Cb[(size_t)row * N + col] = f2b(v); }
        else { Cf[(size_t)row * N + col] = v; }
      }
}

// ---------------- split-K skinny GEMM: M=128=BM, BN=64; partial s -> Cf + s*128*N ----------------
__global__ __launch_bounds__(256) void gemm_sk(
    const u16* __restrict__ A, const u16* __restrict__ Bt, float* __restrict__ Cf,
    int N, int lda, int ldb, int kPer)
{
  constexpr int BM = 128, BN = 64, BK = 64;
  __shared__ alignas(16) u16 Al[BM * BK];
  __shared__ alignas(16) u16 Bl[BN * BK];
  int n0 = blockIdx.x * BN;
  int kb = blockIdx.y * kPer;
  float* C = Cf + (size_t)blockIdx.y * 128 * N;
  int t = threadIdx.x, w = t >> 6, l = t & 63;
  int wm = (w >> 1) * 64, wn = (w & 1) * 32;
  f32x4 acc[4][2];
  for(int a = 0; a < 4; a++) for(int b = 0; b < 2; b++) acc[a][b] = {0.f, 0.f, 0.f, 0.f};

  const short8* Ap = (const short8*)Al;
  const short8* Bp = (const short8*)Bl;

  for(int k0 = kb; k0 < kb + kPer; k0 += BK){
    #pragma unroll
    for(int u = t; u < BM * 8; u += 256){
      int r = u >> 3, c = u & 7;
      gl_lds16(A + (size_t)r * lda + k0 + ((c ^ (r & 7)) << 3), Al + u * 8);
    }
    #pragma unroll
    for(int u = t; u < BN * 8; u += 256){
      int r = u >> 3, c = u & 7;
      gl_lds16(Bt + (size_t)(n0 + r) * ldb + k0 + ((c ^ (r & 7)) << 3), Bl + u * 8);
    }
    __syncthreads();
    #pragma unroll
    for(int ks = 0; ks < 2; ks++){
      int kc = ks * 4 + (l >> 4);
      short8 av[4], bv[2];
      #pragma unroll
      for(int mi = 0; mi < 4; mi++){ int r = wm + mi * 16 + (l & 15); av[mi] = Ap[r * 8 + (kc ^ (r & 7))]; }
      #pragma unroll
      for(int ni = 0; ni < 2; ni++){ int r = wn + ni * 16 + (l & 15); bv[ni] = Bp[r * 8 + (kc ^ (r & 7))]; }
      #pragma unroll
      for(int mi = 0; mi < 4; mi++)
        #pragma unroll
        for(int ni = 0; ni < 2; ni++)
          acc[mi][ni] = __builtin_amdgcn_mfma_f32_16x16x32_bf16(av[mi], bv[ni], acc[mi][ni], 0, 0, 0);
    }
    __syncthreads();
  }

  int cr = wm + ((l >> 4) << 2);
  int cc = n0 + wn + (l & 15);
  for(int mi = 0; mi < 4; mi++)
    for(int ni = 0; ni < 2; ni++)
      for(int r = 0; r < 4; r++)
        C[(size_t)(cr + mi * 16 + r) * N + cc + ni * 16] = acc[mi][ni][r];
}

// ---------------- GAT attention scores es/ed (bf16 h, scalar loads) ----------------
__global__ __launch_bounds__(256) void gat_scores(const u16* __restrict__ h,
    const float* __restrict__ as1, const float* __restrict__ ad1,
    const float* __restrict__ as2, const float* __restrict__ ad2,
    float* __restrict__ es, float* __restrict__ ed){
  __shared__ float aS[16][64], aD[16][64];
  int t = threadIdx.x;
  for(int i = t; i < 1024; i += 256){
    int cc = i >> 6, d = i & 63;
    aS[cc][d] = (cc < 8) ? as1[i] : as2[i - 512];
    aD[cc][d] = (cc < 8) ? ad1[i] : ad2[i - 512];
  }
  __syncthreads();
  int w = t >> 6, l = t & 63;
  int node = blockIdx.x * 4 + w;
  const u16* hr = h + (size_t)node * 1024;
  for(int cc = 0; cc < 16; cc++){
    float v = b2f(hr[cc * 64 + l]);
    float ps = v * aS[cc][l], pd = v * aD[cc][l];
    for(int o = 32; o; o >>= 1){ ps += __shfl_down(ps, o); pd += __shfl_down(pd, o); }
    if(l == 0){ es[node * 16 + cc] = ps; ed[node * 16 + cc] = pd; }
  }
}

// ---------------- GAT attention+aggregate ----------------
__global__ __launch_bounds__(256) void gat_attn2(const u64* __restrict__ adjm,
    const float* __restrict__ es, const float* __restrict__ ed,
    const u16* __restrict__ h, const float* __restrict__ b1, const float* __restrict__ b2,
    float* __restrict__ x2){
  int b = blockIdx.x;
  int cv = blockIdx.y >> 3, hh = blockIdx.y & 7;
  __shared__ float hst[64][64];
  __shared__ float alphaL[64][65];
  __shared__ float esl[64], edl[64];
  __shared__ u64 adjs[64];
  int t = threadIdx.x, w = t >> 6, l = t & 63;
  {
    int j = t >> 2, d0 = (t & 3) * 16;
    const u16* hr = h + (size_t)(b * 64 + j) * 1024 + cv * 512 + hh * 64 + d0;
    #pragma unroll
    for(int k = 0; k < 16; k++) hst[j][d0 + k] = b2f(hr[k]);
  }
  if(t < 64){
    esl[t] = es[(b * 64 + t) * 16 + cv * 8 + hh];
    edl[t] = ed[(b * 64 + t) * 16 + cv * 8 + hh];
    adjs[t] = adjm[b * 64 + t];
  }
  __syncthreads();
  for(int it = 0; it < 16; it++){
    int i = it * 4 + w;
    bool on = (adjs[i] >> l) & 1;
    float e = edl[i] + esl[l];
    e = e > 0.f ? e : 0.2f * e;
    float mx = on ? e : -1e30f;
    for(int o = 32; o; o >>= 1) mx = fmaxf(mx, __shfl_xor(mx, o));
    float p = on ? __expf(e - mx) : 0.f;
    float s = p;
    for(int o = 32; o; o >>= 1) s += __shfl_xor(s, o);
    alphaL[i][l] = p / s;
  }
  __syncthreads();
  int i = t >> 2, q = t & 3;
  float acc[16];
  #pragma unroll
  for(int k = 0; k < 16; k++) acc[k] = 0.f;
  for(int j = 0; j < 64; j++){
    float al = alphaL[i][j];
    const float* hr = &hst[j][q * 16];
    #pragma unroll
    for(int k = 0; k < 16; k++) acc[k] += al * hr[k];
  }
  const float* bias = (cv ? b2 : b1) + hh * 64 + q * 16;
  float* op = x2 + (size_t)(b * 64 + i) * 1024 + cv * 512 + hh * 64 + q * 16;
  #pragma unroll
  for(int k = 0; k < 16; k += 4){
    float4 o;
    o.x = fmaxf(acc[k] + bias[k], 0.f);
    o.y = fmaxf(acc[k+1] + bias[k+1], 0.f);
    o.z = fmaxf(acc[k+2] + bias[k+2], 0.f);
    o.w = fmaxf(acc[k+3] + bias[k+3], 0.f);
    *(float4*)(op + k) = o;
  }
}

// ---------------- LSTM gates (sum ns split-K partials) ----------------
__global__ void lstm_gate0(const float* __restrict__ zp, const float* __restrict__ lb,
                           float* __restrict__ c, u16* __restrict__ ac0, u16* __restrict__ ac1,
                           int ns){
  int t = blockIdx.x * 256 + threadIdx.x;  // 128*1024
  int b = t >> 10, j = t & 1023;
  size_t base = (size_t)b * 4096;
  float zi = 0, zf = 0, zg = 0, zo = 0;
  for(int s = 0; s < ns; s++){
    const float* zr = zp + (size_t)s * 524288 + base;
    zi += zr[j]; zf += zr[1024 + j]; zg += zr[2048 + j]; zo += zr[3072 + j];
  }
  zi += lb[j]; zf += lb[1024 + j]; zg += lb[2048 + j]; zo += lb[3072 + j];
  float ci = c[t];
  float si = 1.f / (1.f + __expf(-zi)), sf = 1.f / (1.f + __expf(-zf)), so = 1.f / (1.f + __expf(-zo));
  float cn = sf * ci + si * tanhf(zg);
  c[t] = cn;
  u16 hb = f2b(so * tanhf(cn));
  ac0[(size_t)b * 3072 + 2048 + j] = hb;
  ac1[(size_t)b * 2048 + j] = hb;
}

__global__ void lstm_gate1(const float* __restrict__ zp, const float* __restrict__ lb,
                           float* __restrict__ c, float* __restrict__ h1f,
                           u16* __restrict__ ac1, u16* __restrict__ ac0, int ns){
  int t = blockIdx.x * 256 + threadIdx.x;
  int b = t >> 10, j = t & 1023;
  size_t base = (size_t)b * 4096;
  float zi = 0, zf = 0, zg = 0, zo = 0;
  for(int s = 0; s < ns; s++){
    const float* zr = zp + (size_t)s * 524288 + base;
    zi += zr[j]; zf += zr[1024 + j]; zg += zr[2048 + j]; zo += zr[3072 + j];
  }
  zi += lb[j]; zf += lb[1024 + j]; zg += lb[2048 + j]; zo += lb[3072 + j];
  float ci = c[t];
  float si = 1.f / (1.f + __expf(-zi)), sf = 1.f / (1.f + __expf(-zf)), so = 1.f / (1.f + __expf(-zo));
  float cn = sf * ci + si * tanhf(zg);
  c[t] = cn;
  float hn = so * tanhf(cn);
  h1f[t] = hn;
  u16 hb = f2b(hn);
  ac1[(size_t)b * 2048 + 1024 + j] = hb;
  ac0[(size_t)b * 3072 + j] = hb;
}

// ---------------- Set2Set attention (f32 x2) ----------------
__global__ __launch_bounds__(256) void s2s_e(const float* __restrict__ x2,
    const float* __restrict__ h1, float* __restrict__ e){
  int t = threadIdx.x, w = t >> 6, l = t & 63;
  int node = blockIdx.x * 4 + w;
  int b = node >> 6;
  const float4* xr = (const float4*)(x2 + (size_t)node * 1024);
  const float4* hr = (const float4*)(h1 + (size_t)b * 1024);
  float s = 0.f;
  #pragma unroll
  for(int k = 0; k < 4; k++){
    float4 a = xr[l + 64 * k], c = hr[l + 64 * k];
    s += a.x * c.x + a.y * c.y + a.z * c.z + a.w * c.w;
  }
  for(int o = 32; o; o >>= 1) s += __shfl_xor(s, o);
  if(l == 0) e[node] = s;
}

__global__ __launch_bounds__(256) void s2s_r(const float* __restrict__ x2,
    const float* __restrict__ e, u16* __restrict__ ac0){
  int b = blockIdx.x, sl = blockIdx.y;
  __shared__ float al[64];
  int t = threadIdx.x;
  if(t < 64){
    float v = e[b * 64 + t];
    float mx = v;
    for(int o = 32; o; o >>= 1) mx = fmaxf(mx, __shfl_xor(mx, o));
    float p = __expf(v - mx);
    float ss = p;
    for(int o = 32; o; o >>= 1) ss += __shfl_xor(ss, o);
    al[t] = p / ss;
  }
  __syncthreads();
  int d = sl * 256 + t;
  const float* xp = x2 + (size_t)b * 64 * 1024 + d;
  float r = 0.f;
  #pragma unroll 8
  for(int j = 0; j < 64; j++) r += al[j] * xp[j * 1024];
  ac0[(size_t)b * 3072 + 1024 + d] = f2b(r);
}

// ---------------- lin2 combine (8 split partials) + bn + relu + lin3 ----------------
__global__ __launch_bounds__(256) void lin3(const float* __restrict__ zp2,
    const float* __restrict__ sc2, const float* __restrict__ sh2,
    const float* __restrict__ W3, const float* __restrict__ b3, float* __restrict__ out){
  int b = blockIdx.x;
  __shared__ float yl[1024];
  int t = threadIdx.x, w = t >> 6, l = t & 63;
  for(int d = t; d < 1024; d += 256){
    float v = 0.f;
    for(int s = 0; s < 8; s++) v += zp2[(size_t)s * 131072 + b * 1024 + d];
    yl[d] = fmaxf(v, 0.f) * sc2[d] + sh2[d];
  }
  __syncthreads();
  for(int n = w; n < 10; n += 4){
    float s = 0.f;
    for(int d = l; d < 1024; d += 64) s += yl[d] * W3[d * 10 + n];
    for(int o = 32; o; o >>= 1) s += __shfl_xor(s, o);
    if(l == 0) out[b * 10 + n] = s + b3[n];
  }
}

extern "C" void kernel_launch(void* const* d_in, const int* in_sizes, int n_in,
                              void* d_out, int out_size, void* d_ws, size_t ws_size,
                              hipStream_t stream){
  const float* x    = (const float*)d_in[0];
  const float* pos  = (const float*)d_in[1];
  const float* W0   = (const float*)d_in[3];
  const float* bn0g = (const float*)d_in[4];
  const float* bn0b = (const float*)d_in[5];
  const float* bn0m = (const float*)d_in[6];
  const float* bn0v = (const float*)d_in[7];
  const float* Wg1  = (const float*)d_in[8];
  const float* as1  = (const float*)d_in[9];
  const float* ad1  = (const float*)d_in[10];
  const float* b1   = (const float*)d_in[11];
  const float* Wg2  = (const float*)d_in[12];
  const float* as2  = (const float*)d_in[13];
  const float* ad2  = (const float*)d_in[14];
  const float* b2   = (const float*)d_in[15];
  const float* Wih0 = (const float*)d_in[16];
  const float* Whh0 = (const float*)d_in[17];
  const float* bih0 = (const float*)d_in[18];
  const float* bhh0 = (const float*)d_in[19];
  const float* Wih1 = (const float*)d_in[20];
  const float* Whh1 = (const float*)d_in[21];
  const float* bih1 = (const float*)d_in[22];
  const float* bhh1 = (const float*)d_in[23];
  const float* W2   = (const float*)d_in[24];
  const float* bn2g = (const float*)d_in[25];
  const float* bn2b = (const float*)d_in[26];
  const float* bn2m = (const float*)d_in[27];
  const float* bn2v = (const float*)d_in[28];
  const float* W3   = (const float*)d_in[29];
  const float* b3   = (const float*)d_in[30];

  char* ws = (char*)d_ws;
  u16*   xbf  = (u16*)(ws + O_XBF);
  float* x2   = (float*)(ws + O_XBF);   // alias: x bf16 dead after GEMM1
  u16*   w0t  = (u16*)(ws + O_W0T);
  u16*   wgt  = (u16*)(ws + O_WGT);
  u16*   w2t  = (u16*)(ws + O_W2T);
  u16*   lw0  = (u16*)(ws + O_LW0);
  u16*   lw1  = (u16*)(ws + O_LW1);
  u16*   xb   = (u16*)(ws + O_XB);
  u16*   hb   = (u16*)(ws + O_H);      // h bf16 (first 16MB of O_H region)
  float* es   = (float*)(ws + O_ES);
  float* ed   = (float*)(ws + O_ED);
  u64*   adjm = (u64*)(ws + O_ADJ);
  float* sc0  = (float*)(ws + O_SC0);
  float* sh0  = (float*)(ws + O_SH0);
  float* sc2  = (float*)(ws + O_SC2);
  float* sh2  = (float*)(ws + O_SH2);
  float* lb0  = (float*)(ws + O_LB0);
  float* lb1  = (float*)(ws + O_LB1);
  char*  s2sb = ws + O_H;               // s2s scratch overlays h after GAT
  u16*   ac0  = (u16*)(s2sb + S_AC0);
  u16*   ac1  = (u16*)(s2sb + S_AC1);
  float* c0b  = (float*)(s2sb + S_C0);
  float* c1b  = (float*)(s2sb + S_C1);
  float* h1f  = (float*)(s2sb + S_H1F);
  float* zp   = (float*)(s2sb + S_ZP);
  float* ebuf = (float*)(s2sb + S_E);

  // --- prep + adjacency + fused weight conversions ---
  prep<<<16, 256, 0, stream>>>(bn0g, bn0b, bn0m, bn0v, bn2g, bn2b, bn2m, bn2v,
                               bih0, bhh0, bih1, bhh1, sc0, sh0, sc2, sh2, lb0, lb1);
  adj_kernel<<<128, 64, 0, stream>>>(pos, adjm);
  cvt_big<<<36864, 256, 0, stream>>>(x, Wih0, Whh0, Wih1, Whh1, xbf, lw0, lw1);
  cvt_tr<<<dim3(128, 64), dim3(32, 8), 0, stream>>>(W0, Wg1, Wg2, W2, w0t, wgt, w2t);

  // --- GEMM1: xb = bf16(bn0(relu(x @ W0))) ; GAT h = xb @ [Wg1|Wg2] (bf16 out) ---
  gemm_bf16<1><<<dim3(64, 16), 256, 0, stream>>>(xbf, w0t, nullptr, xb, sc0, sh0, 8192, 2048, 2048);
  gemm_bf16<3><<<dim3(64, 8), 256, 0, stream>>>(xb, wgt, nullptr, hb, nullptr, nullptr, 8192, 1024, 2048);
  // --- GAT attention ---
  gat_scores<<<2048, 256, 0, stream>>>(hb, as1, ad1, as2, ad2, es, ed);
  gat_attn2<<<dim3(128, 16), 256, 0, stream>>>(adjm, es, ed, hb, b1, b2, x2);

  // --- Set2Set (scratch overlays dead h region) ---
  hipMemsetAsync(s2sb, 0, S_ZERO_BYTES, stream);  // acat0, acat1, c0, c1 = 0
  for(int step = 0; step < 2; step++){
    gemm_sk<<<dim3(64, 8), 256, 0, stream>>>(ac0, lw0, zp, 4096, 3072, 3072, 384);
    lstm_gate0<<<512, 256, 0, stream>>>(zp, lb0, c0b, ac0, ac1, 8);
    gemm_sk<<<dim3(64, 8), 256, 0, stream>>>(ac1, lw1, zp, 4096, 2048, 2048, 256);
    lstm_gate1<<<512, 256, 0, stream>>>(zp, lb1, c1b, h1f, ac1, ac0, 8);
    s2s_e<<<2048, 256, 0, stream>>>(x2, h1f, ebuf);
    s2s_r<<<dim3(128, 4), 256, 0, stream>>>(x2, ebuf, ac0);
  }

  // --- lin2 (split-K 8) + lin3 ---
  gemm_sk<<<dim3(16, 8), 256, 0, stream>>>(ac0, w2t, zp, 1024, 3072, 2048, 256);
  lin3<<<128, 256, 0, stream>>>(zp, sc2, sh2, W3, b3, (float*)d_out);
}

// Round 8
// 340.372 us; speedup vs baseline: 4.6820x; 1.0713x over previous
//
#include <hip/hip_runtime.h>
#include <hip/hip_bf16.h>

typedef unsigned short u16;
typedef __attribute__((ext_vector_type(8))) short short8;
typedef __attribute__((ext_vector_type(4))) float f32x4;
typedef unsigned long long u64;

#define DI __device__ __forceinline__

DI u16 f2b(float f){
  unsigned u = __float_as_uint(f);
  unsigned r = 0x7fffu + ((u >> 16) & 1u);
  return (u16)((u + r) >> 16);
}
DI float b2f(u16 u){ return __uint_as_float((unsigned)u << 16); }

DI void gl_lds16(const void* g, void* l){
  __builtin_amdgcn_global_load_lds((const __attribute__((address_space(1))) void*)g,
                                   (__attribute__((address_space(3))) void*)l, 16, 0, 0);
}

// ---------------- workspace layout (bytes) ----------------
constexpr size_t O_XBF = 0;                    // 33554432: x bf16 [8192,2048]; later x2 f32 [8192,1024]
constexpr size_t O_W0T = O_XBF + 33554432;     // 8388608:  W0^T bf16 [2048,2048]
constexpr size_t O_WGT = O_W0T + 8388608;      // 4194304:  [Wg1|Wg2]^T bf16 [1024,2048]
constexpr size_t O_W2T = O_WGT + 4194304;      // 4194304:  W2^T bf16 [1024,2048]
constexpr size_t O_LW0 = O_W2T + 4194304;      // 25165824: [Wih0|Whh0] bf16 [4096,3072]
constexpr size_t O_LW1 = O_LW0 + 25165824;     // 16777216: [Wih1|Whh1] bf16 [4096,2048]
constexpr size_t O_XB  = O_LW1 + 16777216;     // 33554432: xb bf16 [8192,2048]
constexpr size_t O_H   = O_XB  + 33554432;     // region: h bf16 [8192,1024] (16MB); Set2Set scratch after GAT
constexpr size_t O_ES  = O_H   + 33554432;     // 524288
constexpr size_t O_ED  = O_ES  + 524288;       // 524288
constexpr size_t O_ADJ = O_ED  + 524288;       // 65536
constexpr size_t O_SC0 = O_ADJ + 65536;
constexpr size_t O_SH0 = O_SC0 + 8192;
constexpr size_t O_SC2 = O_SH0 + 8192;
constexpr size_t O_SH2 = O_SC2 + 4096;
constexpr size_t O_LB0 = O_SH2 + 4096;
constexpr size_t O_LB1 = O_LB0 + 16384;
// Set2Set scratch inside O_H (h is dead after gat_attn2):
constexpr size_t S_AC0 = 0;                    // 786432: acat0 bf16 [128][3072] = [q_star(2048) | h0(1024)]
constexpr size_t S_AC1 = S_AC0 + 786432;       // 524288: acat1 bf16 [128][2048] = [h0 | h1]
constexpr size_t S_C0  = S_AC1 + 524288;       // 524288
constexpr size_t S_C1  = S_C0  + 524288;       // 524288
constexpr size_t S_H1F = S_C1  + 524288;       // 524288: h1 f32
constexpr size_t S_ZP  = S_H1F + 524288;       // 16777216: split-K partials (8 x [128*4096] f32)
constexpr size_t S_E   = S_ZP  + 16777216;     // 32768: s2s scores e[8192]
constexpr size_t S_H0U = S_E   + 32768;        // 4096: step-0 uniform h0 f32[1024]
constexpr size_t S_Z1U = S_H0U + 4096;         // 16384: step-0 uniform z1 f32[4096]

// ---------------- fused big converters (5 strided f32->bf16 copies) ----------------
__global__ __launch_bounds__(256) void cvt_big(
    const float* __restrict__ x, const float* __restrict__ Wih0, const float* __restrict__ Whh0,
    const float* __restrict__ Wih1, const float* __restrict__ Whh1,
    u16* __restrict__ xbf, u16* __restrict__ lw0, u16* __restrict__ lw1){
  int bx = blockIdx.x;
  int idx, cq, dld, doff;
  const float* src; u16* dst;
  if(bx < 16384){      src = x;    dst = xbf; idx = bx * 256 + threadIdx.x;            cq = 512; dld = 2048; doff = 0; }
  else if(bx < 24576){ src = Wih0; dst = lw0; idx = (bx - 16384) * 256 + threadIdx.x;  cq = 512; dld = 3072; doff = 0; }
  else if(bx < 28672){ src = Whh0; dst = lw0; idx = (bx - 24576) * 256 + threadIdx.x;  cq = 256; dld = 3072; doff = 2048; }
  else if(bx < 32768){ src = Wih1; dst = lw1; idx = (bx - 28672) * 256 + threadIdx.x;  cq = 256; dld = 2048; doff = 0; }
  else {               src = Whh1; dst = lw1; idx = (bx - 32768) * 256 + threadIdx.x;  cq = 256; dld = 2048; doff = 1024; }
  int r = idx / cq, c4 = (idx - r * cq) << 2;
  float4 v = *(const float4*)(src + (size_t)r * (cq << 2) + c4);
  u16 o[4] = { f2b(v.x), f2b(v.y), f2b(v.z), f2b(v.w) };
  *(ushort4*)(dst + (size_t)r * dld + doff + c4) = *(ushort4*)o;
}

// ---------------- fused f32->bf16 transposes: W0, Wg1, Wg2, W2 ----------------
__global__ void cvt_tr(const float* __restrict__ W0, const float* __restrict__ Wg1,
                       const float* __restrict__ Wg2, const float* __restrict__ W2,
                       u16* __restrict__ w0t, u16* __restrict__ wgt, u16* __restrict__ w2t){
  __shared__ float tile[32][33];
  int bx = blockIdx.x;
  const float* src; u16* dst; int C, droff;
  if(bx < 64){      src = W0;  dst = w0t; C = 2048; droff = 0; }
  else if(bx < 80){ src = Wg1; dst = wgt; C = 512;  droff = 0;   bx -= 64; }
  else if(bx < 96){ src = Wg2; dst = wgt; C = 512;  droff = 512; bx -= 80; }
  else {            src = W2;  dst = w2t; C = 1024; droff = 0;   bx -= 96; }
  int c0 = bx * 32, r0 = blockIdx.y * 32;
  int tx = threadIdx.x, ty = threadIdx.y;  // (32,8)
  for(int i = 0; i < 4; i++)
    tile[ty + 8*i][tx] = src[(size_t)(r0 + ty + 8*i) * C + c0 + tx];
  __syncthreads();
  for(int i = 0; i < 4; i++)
    dst[(size_t)(droff + c0 + ty + 8*i) * 2048 + r0 + tx] = f2b(tile[tx][ty + 8*i]);
}

__global__ void prep(const float* g0, const float* b0, const float* m0, const float* v0,
                     const float* g2, const float* b2, const float* m2, const float* v2,
                     const float* bih0, const float* bhh0, const float* bih1, const float* bhh1,
                     float* sc0, float* sh0, float* sc2, float* sh2, float* lb0, float* lb1){
  int t = blockIdx.x * 256 + threadIdx.x;
  if(t < 2048){ float s = g0[t] * rsqrtf(v0[t] + 0.1f); sc0[t] = s; sh0[t] = b0[t] - m0[t] * s; }
  if(t < 1024){ float s = g2[t] * rsqrtf(v2[t] + 0.1f); sc2[t] = s; sh2[t] = b2[t] - m2[t] * s; }
  if(t < 4096){ lb0[t] = bih0[t] + bhh0[t]; lb1[t] = bih1[t] + bhh1[t]; }
}

__global__ void adj_kernel(const float* __restrict__ pos, u64* __restrict__ adjm){
  int b = blockIdx.x, l = threadIdx.x;  // 64 threads
  __shared__ float px[64], py[64];
  float2 p = ((const float2*)pos)[b * 64 + l];
  px[l] = p.x; py[l] = p.y;
  __syncthreads();
  float xi = px[l], yi = py[l];
  u64 m = 0;
  for(int j = 0; j < 64; j++){
    float dx = xi - px[j], dy = yi - py[j];
    if(dx * dx + dy * dy <= 16.0f) m |= (1ull << j);
  }
  adjm[b * 64 + l] = m;
}

// ---------------- bf16 MFMA GEMM (m97 structure) ----------------
// MODE 1: relu+bn -> bf16 Cb.  MODE 3: plain bf16 Cb.
template<int MODE>
__global__ __launch_bounds__(256) void gemm_bf16(
    const u16* __restrict__ A, const u16* __restrict__ Bt,
    float* __restrict__ Cf, u16* __restrict__ Cb,
    const float* __restrict__ p1, const float* __restrict__ p2,
    int M, int N, int K)
{
  constexpr int BM = 128, BN = 128, BK = 64;
  __shared__ alignas(16) u16 Al[BM * BK];
  __shared__ alignas(16) u16 Bl[BN * BK];
  int m0 = blockIdx.x * BM, n0 = blockIdx.y * BN;
  int t = threadIdx.x, w = t >> 6, l = t & 63;
  int wm = (w >> 1) * 64, wn = (w & 1) * 64;
  f32x4 acc[4][4];
  for(int a = 0; a < 4; a++) for(int b = 0; b < 4; b++) acc[a][b] = {0.f, 0.f, 0.f, 0.f};

  const short8* Ap = (const short8*)Al;
  const short8* Bp = (const short8*)Bl;

  for(int k0 = 0; k0 < K; k0 += BK){
    #pragma unroll
    for(int u = t; u < BM * 8; u += 256){
      int r = u >> 3, c = u & 7;
      gl_lds16(A + (size_t)(m0 + r) * K + k0 + ((c ^ (r & 7)) << 3), Al + u * 8);
    }
    #pragma unroll
    for(int u = t; u < BN * 8; u += 256){
      int r = u >> 3, c = u & 7;
      gl_lds16(Bt + (size_t)(n0 + r) * K + k0 + ((c ^ (r & 7)) << 3), Bl + u * 8);
    }
    __syncthreads();
    #pragma unroll
    for(int ks = 0; ks < 2; ks++){
      int kc = ks * 4 + (l >> 4);
      short8 av[4], bv[4];
      #pragma unroll
      for(int mi = 0; mi < 4; mi++){ int r = wm + mi * 16 + (l & 15); av[mi] = Ap[r * 8 + (kc ^ (r & 7))]; }
      #pragma unroll
      for(int ni = 0; ni < 4; ni++){ int r = wn + ni * 16 + (l & 15); bv[ni] = Bp[r * 8 + (kc ^ (r & 7))]; }
      #pragma unroll
      for(int mi = 0; mi < 4; mi++)
        #pragma unroll
        for(int ni = 0; ni < 4; ni++)
          acc[mi][ni] = __builtin_amdgcn_mfma_f32_16x16x32_bf16(av[mi], bv[ni], acc[mi][ni], 0, 0, 0);
    }
    __syncthreads();
  }

  int cr = m0 + wm + ((l >> 4) << 2);
  int cc = n0 + wn + (l & 15);
  for(int mi = 0; mi < 4; mi++)
    for(int ni = 0; ni < 4; ni++)
      for(int r = 0; r < 4; r++){
        int row = cr + mi * 16 + r, col = cc + ni * 16;
        float v = acc[mi][ni][r];
        if(MODE == 1){ v = fmaxf(v, 0.f) * p1[col] + p2[col]; Cb[(size_t)row * N + col] = f2b(v); }
        else if(MODE == 3){ Cb[(size_t)row * N + col] = f2b(v); }
        else { Cf[(size_t)row * N + col] = v; }
      }
}

// ---------------- split-K skinny GEMM: M=128=BM, BN=64; partial s -> Cf + s*128*N ----------------
__global__ __launch_bounds__(256) void gemm_sk(
    const u16* __restrict__ A, const u16* __restrict__ Bt, float* __restrict__ Cf,
    int N, int lda, int ldb, int kPer)
{
  constexpr int BM = 128, BN = 64, BK = 64;
  __shared__ alignas(16) u16 Al[BM * BK];
  __shared__ alignas(16) u16 Bl[BN * BK];
  int n0 = blockIdx.x * BN;
  int kb = blockIdx.y * kPer;
  float* C = Cf + (size_t)blockIdx.y * 128 * N;
  int t = threadIdx.x, w = t >> 6, l = t & 63;
  int wm = (w >> 1) * 64, wn = (w & 1) * 32;
  f32x4 acc[4][2];
  for(int a = 0; a < 4; a++) for(int b = 0; b < 2; b++) acc[a][b] = {0.f, 0.f, 0.f, 0.f};

  const short8* Ap = (const short8*)Al;
  const short8* Bp = (const short8*)Bl;

  for(int k0 = kb; k0 < kb + kPer; k0 += BK){
    #pragma unroll
    for(int u = t; u < BM * 8; u += 256){
      int r = u >> 3, c = u & 7;
      gl_lds16(A + (size_t)r * lda + k0 + ((c ^ (r & 7)) << 3), Al + u * 8);
    }
    #pragma unroll
    for(int u = t; u < BN * 8; u += 256){
      int r = u >> 3, c = u & 7;
      gl_lds16(Bt + (size_t)(n0 + r) * ldb + k0 + ((c ^ (r & 7)) << 3), Bl + u * 8);
    }
    __syncthreads();
    #pragma unroll
    for(int ks = 0; ks < 2; ks++){
      int kc = ks * 4 + (l >> 4);
      short8 av[4], bv[2];
      #pragma unroll
      for(int mi = 0; mi < 4; mi++){ int r = wm + mi * 16 + (l & 15); av[mi] = Ap[r * 8 + (kc ^ (r & 7))]; }
      #pragma unroll
      for(int ni = 0; ni < 2; ni++){ int r = wn + ni * 16 + (l & 15); bv[ni] = Bp[r * 8 + (kc ^ (r & 7))]; }
      #pragma unroll
      for(int mi = 0; mi < 4; mi++)
        #pragma unroll
        for(int ni = 0; ni < 2; ni++)
          acc[mi][ni] = __builtin_amdgcn_mfma_f32_16x16x32_bf16(av[mi], bv[ni], acc[mi][ni], 0, 0, 0);
    }
    __syncthreads();
  }

  int cr = wm + ((l >> 4) << 2);
  int cc = n0 + wn + (l & 15);
  for(int mi = 0; mi < 4; mi++)
    for(int ni = 0; ni < 2; ni++)
      for(int r = 0; r < 4; r++)
        C[(size_t)(cr + mi * 16 + r) * N + cc + ni * 16] = acc[mi][ni][r];
}

// ---------------- GAT attention scores es/ed (bf16 h, scalar loads) ----------------
__global__ __launch_bounds__(256) void gat_scores(const u16* __restrict__ h,
    const float* __restrict__ as1, const float* __restrict__ ad1,
    const float* __restrict__ as2, const float* __restrict__ ad2,
    float* __restrict__ es, float* __restrict__ ed){
  __shared__ float aS[16][64], aD[16][64];
  int t = threadIdx.x;
  for(int i = t; i < 1024; i += 256){
    int cc = i >> 6, d = i & 63;
    aS[cc][d] = (cc < 8) ? as1[i] : as2[i - 512];
    aD[cc][d] = (cc < 8) ? ad1[i] : ad2[i - 512];
  }
  __syncthreads();
  int w = t >> 6, l = t & 63;
  int node = blockIdx.x * 4 + w;
  const u16* hr = h + (size_t)node * 1024;
  for(int cc = 0; cc < 16; cc++){
    float v = b2f(hr[cc * 64 + l]);
    float ps = v * aS[cc][l], pd = v * aD[cc][l];
    for(int o = 32; o; o >>= 1){ ps += __shfl_down(ps, o); pd += __shfl_down(pd, o); }
    if(l == 0){ es[node * 16 + cc] = ps; ed[node * 16 + cc] = pd; }
  }
}

// ---------------- GAT attention+aggregate ----------------
__global__ __launch_bounds__(256) void gat_attn2(const u64* __restrict__ adjm,
    const float* __restrict__ es, const float* __restrict__ ed,
    const u16* __restrict__ h, const float* __restrict__ b1, const float* __restrict__ b2,
    float* __restrict__ x2){
  int b = blockIdx.x;
  int cv = blockIdx.y >> 3, hh = blockIdx.y & 7;
  __shared__ float hst[64][64];
  __shared__ float alphaL[64][65];
  __shared__ float esl[64], edl[64];
  __shared__ u64 adjs[64];
  int t = threadIdx.x, w = t >> 6, l = t & 63;
  {
    int j = t >> 2, d0 = (t & 3) * 16;
    const u16* hr = h + (size_t)(b * 64 + j) * 1024 + cv * 512 + hh * 64 + d0;
    #pragma unroll
    for(int k = 0; k < 16; k++) hst[j][d0 + k] = b2f(hr[k]);
  }
  if(t < 64){
    esl[t] = es[(b * 64 + t) * 16 + cv * 8 + hh];
    edl[t] = ed[(b * 64 + t) * 16 + cv * 8 + hh];
    adjs[t] = adjm[b * 64 + t];
  }
  __syncthreads();
  for(int it = 0; it < 16; it++){
    int i = it * 4 + w;
    bool on = (adjs[i] >> l) & 1;
    float e = edl[i] + esl[l];
    e = e > 0.f ? e : 0.2f * e;
    float mx = on ? e : -1e30f;
    for(int o = 32; o; o >>= 1) mx = fmaxf(mx, __shfl_xor(mx, o));
    float p = on ? __expf(e - mx) : 0.f;
    float s = p;
    for(int o = 32; o; o >>= 1) s += __shfl_xor(s, o);
    alphaL[i][l] = p / s;
  }
  __syncthreads();
  int i = t >> 2, q = t & 3;
  float acc[16];
  #pragma unroll
  for(int k = 0; k < 16; k++) acc[k] = 0.f;
  for(int j = 0; j < 64; j++){
    float al = alphaL[i][j];
    const float* hr = &hst[j][q * 16];
    #pragma unroll
    for(int k = 0; k < 16; k++) acc[k] += al * hr[k];
  }
  const float* bias = (cv ? b2 : b1) + hh * 64 + q * 16;
  float* op = x2 + (size_t)(b * 64 + i) * 1024 + cv * 512 + hh * 64 + q * 16;
  #pragma unroll
  for(int k = 0; k < 16; k += 4){
    float4 o;
    o.x = fmaxf(acc[k] + bias[k], 0.f);
    o.y = fmaxf(acc[k+1] + bias[k+1], 0.f);
    o.z = fmaxf(acc[k+2] + bias[k+2], 0.f);
    o.w = fmaxf(acc[k+3] + bias[k+3], 0.f);
    *(float4*)(op + k) = o;
  }
}

// ---------------- Set2Set step-0 shortcut (input == 0 for all graphs) ----------------
// layer-0 cell with zero input/state: z = lb0, c = sig(zi)*tanh(zg), h = sig(zo)*tanh(c)
__global__ void s2s0_h0(const float* __restrict__ lb0, float* __restrict__ h0u){
  int j = blockIdx.x * 256 + threadIdx.x;
  if(j >= 1024) return;
  float zi = lb0[j], zg = lb0[2048 + j], zo = lb0[3072 + j];
  float si = 1.f / (1.f + __expf(-zi));
  float so = 1.f / (1.f + __expf(-zo));
  float cn = si * tanhf(zg);
  h0u[j] = so * tanhf(cn);
}

// z1 = Wih1 @ h0u + lb1  (f32 GEMV, 4096 rows; one wave per row)
__global__ __launch_bounds__(256) void s2s0_gemv(const float* __restrict__ Wih1,
    const float* __restrict__ lb1, const float* __restrict__ h0u, float* __restrict__ z1u){
  __shared__ float hs[1024];
  int t = threadIdx.x;
  for(int i = t; i < 1024; i += 256) hs[i] = h0u[i];
  __syncthreads();
  int w = t >> 6, l = t & 63;
  int r = blockIdx.x * 4 + w;
  const float* wr = Wih1 + (size_t)r * 1024;
  float s = 0.f;
  #pragma unroll
  for(int k = 0; k < 16; k++) s += wr[l + 64 * k] * hs[l + 64 * k];
  for(int o = 32; o; o >>= 1) s += __shfl_xor(s, o);
  if(l == 0) z1u[r] = s + lb1[r];
}

// broadcast step-0 state to all 128 graphs: c0,c1,h1f (f32), ac0/ac1 bf16 slices
__global__ void s2s0_bcast(const float* __restrict__ lb0, const float* __restrict__ z1u,
    float* __restrict__ c0b, float* __restrict__ c1b, float* __restrict__ h1f,
    u16* __restrict__ ac0, u16* __restrict__ ac1){
  int t = blockIdx.x * 256 + threadIdx.x;  // 128*1024
  int b = t >> 10, j = t & 1023;
  // layer0 (from lb0)
  float zi0 = lb0[j], zg0 = lb0[2048 + j], zo0 = lb0[3072 + j];
  float c0 = (1.f / (1.f + __expf(-zi0))) * tanhf(zg0);
  float h0 = (1.f / (1.f + __expf(-zo0))) * tanhf(c0);
  // layer1 (from z1u)
  float zi1 = z1u[j], zg1 = z1u[2048 + j], zo1 = z1u[3072 + j];
  float c1 = (1.f / (1.f + __expf(-zi1))) * tanhf(zg1);
  float h1 = (1.f / (1.f + __expf(-zo1))) * tanhf(c1);
  c0b[t] = c0;
  c1b[t] = c1;
  h1f[t] = h1;
  u16 h0b = f2b(h0), h1b = f2b(h1);
  ac0[(size_t)b * 3072 + j] = h1b;          // q_star[:1024] = h1
  ac0[(size_t)b * 3072 + 2048 + j] = h0b;   // layer0 recurrent input = h0
  ac1[(size_t)b * 2048 + j] = h0b;          // layer1 input = [h0 | h1_prev]
  ac1[(size_t)b * 2048 + 1024 + j] = h1b;
}

// ---------------- LSTM gates (sum ns split-K partials) ----------------
__global__ void lstm_gate0(const float* __restrict__ zp, const float* __restrict__ lb,
                           float* __restrict__ c, u16* __restrict__ ac0, u16* __restrict__ ac1,
                           int ns){
  int t = blockIdx.x * 256 + threadIdx.x;  // 128*1024
  int b = t >> 10, j = t & 1023;
  size_t base = (size_t)b * 4096;
  float zi = 0, zf = 0, zg = 0, zo = 0;
  for(int s = 0; s < ns; s++){
    const float* zr = zp + (size_t)s * 524288 + base;
    zi += zr[j]; zf += zr[1024 + j]; zg += zr[2048 + j]; zo += zr[3072 + j];
  }
  zi += lb[j]; zf += lb[1024 + j]; zg += lb[2048 + j]; zo += lb[3072 + j];
  float ci = c[t];
  float si = 1.f / (1.f + __expf(-zi)), sf = 1.f / (1.f + __expf(-zf)), so = 1.f / (1.f + __expf(-zo));
  float cn = sf * ci + si * tanhf(zg);
  c[t] = cn;
  u16 hb = f2b(so * tanhf(cn));
  ac0[(size_t)b * 3072 + 2048 + j] = hb;
  ac1[(size_t)b * 2048 + j] = hb;
}

__global__ void lstm_gate1(const float* __restrict__ zp, const float* __restrict__ lb,
                           float* __restrict__ c, float* __restrict__ h1f,
                           u16* __restrict__ ac1, u16* __restrict__ ac0, int ns){
  int t = blockIdx.x * 256 + threadIdx.x;
  int b = t >> 10, j = t & 1023;
  size_t base = (size_t)b * 4096;
  float zi = 0, zf = 0, zg = 0, zo = 0;
  for(int s = 0; s < ns; s++){
    const float* zr = zp + (size_t)s * 524288 + base;
    zi += zr[j]; zf += zr[1024 + j]; zg += zr[2048 + j]; zo += zr[3072 + j];
  }
  zi += lb[j]; zf += lb[1024 + j]; zg += lb[2048 + j]; zo += lb[3072 + j];
  float ci = c[t];
  float si = 1.f / (1.f + __expf(-zi)), sf = 1.f / (1.f + __expf(-zf)), so = 1.f / (1.f + __expf(-zo));
  float cn = sf * ci + si * tanhf(zg);
  c[t] = cn;
  float hn = so * tanhf(cn);
  h1f[t] = hn;
  u16 hb = f2b(hn);
  ac1[(size_t)b * 2048 + 1024 + j] = hb;
  ac0[(size_t)b * 3072 + j] = hb;
}

// ---------------- Set2Set attention (f32 x2) ----------------
__global__ __launch_bounds__(256) void s2s_e(const float* __restrict__ x2,
    const float* __restrict__ h1, float* __restrict__ e){
  int t = threadIdx.x, w = t >> 6, l = t & 63;
  int node = blockIdx.x * 4 + w;
  int b = node >> 6;
  const float4* xr = (const float4*)(x2 + (size_t)node * 1024);
  const float4* hr = (const float4*)(h1 + (size_t)b * 1024);
  float s = 0.f;
  #pragma unroll
  for(int k = 0; k < 4; k++){
    float4 a = xr[l + 64 * k], c = hr[l + 64 * k];
    s += a.x * c.x + a.y * c.y + a.z * c.z + a.w * c.w;
  }
  for(int o = 32; o; o >>= 1) s += __shfl_xor(s, o);
  if(l == 0) e[node] = s;
}

__global__ __launch_bounds__(256) void s2s_r(const float* __restrict__ x2,
    const float* __restrict__ e, u16* __restrict__ ac0){
  int b = blockIdx.x, sl = blockIdx.y;
  __shared__ float al[64];
  int t = threadIdx.x;
  if(t < 64){
    float v = e[b * 64 + t];
    float mx = v;
    for(int o = 32; o; o >>= 1) mx = fmaxf(mx, __shfl_xor(mx, o));
    float p = __expf(v - mx);
    float ss = p;
    for(int o = 32; o; o >>= 1) ss += __shfl_xor(ss, o);
    al[t] = p / ss;
  }
  __syncthreads();
  int d = sl * 256 + t;
  const float* xp = x2 + (size_t)b * 64 * 1024 + d;
  float r = 0.f;
  #pragma unroll 8
  for(int j = 0; j < 64; j++) r += al[j] * xp[j * 1024];
  ac0[(size_t)b * 3072 + 1024 + d] = f2b(r);
}

// ---------------- lin2 combine (8 split partials) + bn + relu + lin3 ----------------
__global__ __launch_bounds__(256) void lin3(const float* __restrict__ zp2,
    const float* __restrict__ sc2, const float* __restrict__ sh2,
    const float* __restrict__ W3, const float* __restrict__ b3, float* __restrict__ out){
  int b = blockIdx.x;
  __shared__ float yl[1024];
  int t = threadIdx.x, w = t >> 6, l = t & 63;
  for(int d = t; d < 1024; d += 256){
    float v = 0.f;
    for(int s = 0; s < 8; s++) v += zp2[(size_t)s * 131072 + b * 1024 + d];
    yl[d] = fmaxf(v, 0.f) * sc2[d] + sh2[d];
  }
  __syncthreads();
  for(int n = w; n < 10; n += 4){
    float s = 0.f;
    for(int d = l; d < 1024; d += 64) s += yl[d] * W3[d * 10 + n];
    for(int o = 32; o; o >>= 1) s += __shfl_xor(s, o);
    if(l == 0) out[b * 10 + n] = s + b3[n];
  }
}

extern "C" void kernel_launch(void* const* d_in, const int* in_sizes, int n_in,
                              void* d_out, int out_size, void* d_ws, size_t ws_size,
                              hipStream_t stream){
  const float* x    = (const float*)d_in[0];
  const float* pos  = (const float*)d_in[1];
  const float* W0   = (const float*)d_in[3];
  const float* bn0g = (const float*)d_in[4];
  const float* bn0b = (const float*)d_in[5];
  const float* bn0m = (const float*)d_in[6];
  const float* bn0v = (const float*)d_in[7];
  const float* Wg1  = (const float*)d_in[8];
  const float* as1  = (const float*)d_in[9];
  const float* ad1  = (const float*)d_in[10];
  const float* b1   = (const float*)d_in[11];
  const float* Wg2  = (const float*)d_in[12];
  const float* as2  = (const float*)d_in[13];
  const float* ad2  = (const float*)d_in[14];
  const float* b2   = (const float*)d_in[15];
  const float* Wih0 = (const float*)d_in[16];
  const float* Whh0 = (const float*)d_in[17];
  const float* bih0 = (const float*)d_in[18];
  const float* bhh0 = (const float*)d_in[19];
  const float* Wih1 = (const float*)d_in[20];
  const float* Whh1 = (const float*)d_in[21];
  const float* bih1 = (const float*)d_in[22];
  const float* bhh1 = (const float*)d_in[23];
  const float* W2   = (const float*)d_in[24];
  const float* bn2g = (const float*)d_in[25];
  const float* bn2b = (const float*)d_in[26];
  const float* bn2m = (const float*)d_in[27];
  const float* bn2v = (const float*)d_in[28];
  const float* W3   = (const float*)d_in[29];
  const float* b3   = (const float*)d_in[30];

  char* ws = (char*)d_ws;
  u16*   xbf  = (u16*)(ws + O_XBF);
  float* x2   = (float*)(ws + O_XBF);   // alias: x bf16 dead after GEMM1
  u16*   w0t  = (u16*)(ws + O_W0T);
  u16*   wgt  = (u16*)(ws + O_WGT);
  u16*   w2t  = (u16*)(ws + O_W2T);
  u16*   lw0  = (u16*)(ws + O_LW0);
  u16*   lw1  = (u16*)(ws + O_LW1);
  u16*   xb   = (u16*)(ws + O_XB);
  u16*   hb   = (u16*)(ws + O_H);      // h bf16 (first 16MB of O_H region)
  float* es   = (float*)(ws + O_ES);
  float* ed   = (float*)(ws + O_ED);
  u64*   adjm = (u64*)(ws + O_ADJ);
  float* sc0  = (float*)(ws + O_SC0);
  float* sh0  = (float*)(ws + O_SH0);
  float* sc2  = (float*)(ws + O_SC2);
  float* sh2  = (float*)(ws + O_SH2);
  float* lb0  = (float*)(ws + O_LB0);
  float* lb1  = (float*)(ws + O_LB1);
  char*  s2sb = ws + O_H;               // s2s scratch overlays h after GAT
  u16*   ac0  = (u16*)(s2sb + S_AC0);
  u16*   ac1  = (u16*)(s2sb + S_AC1);
  float* c0b  = (float*)(s2sb + S_C0);
  float* c1b  = (float*)(s2sb + S_C1);
  float* h1f  = (float*)(s2sb + S_H1F);
  float* zp   = (float*)(s2sb + S_ZP);
  float* ebuf = (float*)(s2sb + S_E);
  float* h0u  = (float*)(s2sb + S_H0U);
  float* z1u  = (float*)(s2sb + S_Z1U);

  // --- prep + adjacency + fused weight conversions ---
  prep<<<16, 256, 0, stream>>>(bn0g, bn0b, bn0m, bn0v, bn2g, bn2b, bn2m, bn2v,
                               bih0, bhh0, bih1, bhh1, sc0, sh0, sc2, sh2, lb0, lb1);
  adj_kernel<<<128, 64, 0, stream>>>(pos, adjm);
  cvt_big<<<36864, 256, 0, stream>>>(x, Wih0, Whh0, Wih1, Whh1, xbf, lw0, lw1);
  cvt_tr<<<dim3(128, 64), dim3(32, 8), 0, stream>>>(W0, Wg1, Wg2, W2, w0t, wgt, w2t);

  // --- GEMM1: xb = bf16(bn0(relu(x @ W0))) ; GAT h = xb @ [Wg1|Wg2] (bf16 out) ---
  gemm_bf16<1><<<dim3(64, 16), 256, 0, stream>>>(xbf, w0t, nullptr, xb, sc0, sh0, 8192, 2048, 2048);
  gemm_bf16<3><<<dim3(64, 8), 256, 0, stream>>>(xb, wgt, nullptr, hb, nullptr, nullptr, 8192, 1024, 2048);
  // --- GAT attention ---
  gat_scores<<<2048, 256, 0, stream>>>(hb, as1, ad1, as2, ad2, es, ed);
  gat_attn2<<<dim3(128, 16), 256, 0, stream>>>(adjm, es, ed, hb, b1, b2, x2);

  // --- Set2Set step 0: LSTM input is 0 -> state is graph-uniform (bias-derived) ---
  s2s0_h0<<<4, 256, 0, stream>>>(lb0, h0u);
  s2s0_gemv<<<1024, 256, 0, stream>>>(Wih1, lb1, h0u, z1u);
  s2s0_bcast<<<512, 256, 0, stream>>>(lb0, z1u, c0b, c1b, h1f, ac0, ac1);
  s2s_e<<<2048, 256, 0, stream>>>(x2, h1f, ebuf);
  s2s_r<<<dim3(128, 4), 256, 0, stream>>>(x2, ebuf, ac0);

  // --- Set2Set step 1 (full) ---
  gemm_sk<<<dim3(64, 8), 256, 0, stream>>>(ac0, lw0, zp, 4096, 3072, 3072, 384);
  lstm_gate0<<<512, 256, 0, stream>>>(zp, lb0, c0b, ac0, ac1, 8);
  gemm_sk<<<dim3(64, 8), 256, 0, stream>>>(ac1, lw1, zp, 4096, 2048, 2048, 256);
  lstm_gate1<<<512, 256, 0, stream>>>(zp, lb1, c1b, h1f, ac1, ac0, 8);
  s2s_e<<<2048, 256, 0, stream>>>(x2, h1f, ebuf);
  s2s_r<<<dim3(128, 4), 256, 0, stream>>>(x2, ebuf, ac0);

  // --- lin2 (split-K 8) + lin3 ---
  gemm_sk<<<dim3(16, 8), 256, 0, stream>>>(ac0, w2t, zp, 1024, 3072, 2048, 256);
  lin3<<<128, 256, 0, stream>>>(zp, sc2, sh2, W3, b3, (float*)d_out);
}

// Round 9
// 318.618 us; speedup vs baseline: 5.0017x; 1.0683x over previous
//
#include <hip/hip_runtime.h>
#include <hip/hip_bf16.h>

typedef unsigned short u16;
typedef __attribute__((ext_vector_type(8))) short short8;
typedef __attribute__((ext_vector_type(4))) float f32x4;
typedef unsigned long long u64;

#define DI __device__ __forceinline__

DI u16 f2b(float f){
  unsigned u = __float_as_uint(f);
  unsigned r = 0x7fffu + ((u >> 16) & 1u);
  return (u16)((u + r) >> 16);
}
DI float b2f(u16 u){ return __uint_as_float((unsigned)u << 16); }

DI void gl_lds16(const void* g, void* l){
  __builtin_amdgcn_global_load_lds((const __attribute__((address_space(1))) void*)g,
                                   (__attribute__((address_space(3))) void*)l, 16, 0, 0);
}

// ---------------- workspace layout (bytes) ----------------
constexpr size_t O_XBF = 0;                    // 33554432: x bf16 [8192,2048]; later x2 bf16 [8192,1024] (16MB)
constexpr size_t O_W0T = O_XBF + 33554432;     // 8388608:  W0^T bf16 [2048,2048]
constexpr size_t O_WGT = O_W0T + 8388608;      // 4194304:  [Wg1|Wg2]^T bf16 [1024,2048]
constexpr size_t O_W2T = O_WGT + 4194304;      // 4194304:  W2^T bf16 [1024,2048]
constexpr size_t O_XB  = O_W2T + 4194304;      // 33554432: xb bf16 [8192,2048]
constexpr size_t O_H   = O_XB  + 33554432;     // region: h bf16 [8192,1024] (16MB); Set2Set scratch after GAT
constexpr size_t O_ES  = O_H   + 33554432;     // 524288
constexpr size_t O_ED  = O_ES  + 524288;       // 524288
constexpr size_t O_ADJ = O_ED  + 524288;       // 65536
constexpr size_t O_SC0 = O_ADJ + 65536;
constexpr size_t O_SH0 = O_SC0 + 8192;
constexpr size_t O_SC2 = O_SH0 + 8192;
constexpr size_t O_SH2 = O_SC2 + 4096;
constexpr size_t O_LB0 = O_SH2 + 4096;
constexpr size_t O_LB1 = O_LB0 + 16384;
// Set2Set scratch inside O_H (h is dead after gat_attn2):
constexpr size_t S_AC0 = 0;                    // 786432: acat0 bf16 [128][3072] = [q_star(2048) | h0(1024)]
constexpr size_t S_AC1 = S_AC0 + 786432;       // 524288: acat1 bf16 [128][2048] = [h0 | h1]
constexpr size_t S_C0  = S_AC1 + 524288;       // 524288
constexpr size_t S_C1  = S_C0  + 524288;       // 524288
constexpr size_t S_H1F = S_C1  + 524288;       // 524288: h1 f32
constexpr size_t S_ZP  = S_H1F + 524288;       // 16777216: split-K partials (8 x [128*4096] f32)
constexpr size_t S_E   = S_ZP  + 16777216;     // 32768: s2s scores e[8192]
constexpr size_t S_H0U = S_E   + 32768;        // 4096: step-0 uniform h0 f32[1024]
constexpr size_t S_Z1U = S_H0U + 4096;         // 16384: step-0 uniform z1 f32[4096]

// ---------------- x f32 -> bf16 ----------------
__global__ __launch_bounds__(256) void cvt_x(const float* __restrict__ x, u16* __restrict__ xbf){
  int idx = blockIdx.x * 256 + threadIdx.x;      // 16384 blocks: [8192,2048]/4
  int r = idx >> 9, c4 = (idx & 511) << 2;
  float4 v = *(const float4*)(x + (size_t)r * 2048 + c4);
  u16 o[4] = { f2b(v.x), f2b(v.y), f2b(v.z), f2b(v.w) };
  *(ushort4*)(xbf + (size_t)r * 2048 + c4) = *(ushort4*)o;
}

// ---------------- fused f32->bf16 transposes: W0, Wg1, Wg2, W2 ----------------
__global__ void cvt_tr(const float* __restrict__ W0, const float* __restrict__ Wg1,
                       const float* __restrict__ Wg2, const float* __restrict__ W2,
                       u16* __restrict__ w0t, u16* __restrict__ wgt, u16* __restrict__ w2t){
  __shared__ float tile[32][33];
  int bx = blockIdx.x;
  const float* src; u16* dst; int C, droff;
  if(bx < 64){      src = W0;  dst = w0t; C = 2048; droff = 0; }
  else if(bx < 80){ src = Wg1; dst = wgt; C = 512;  droff = 0;   bx -= 64; }
  else if(bx < 96){ src = Wg2; dst = wgt; C = 512;  droff = 512; bx -= 80; }
  else {            src = W2;  dst = w2t; C = 1024; droff = 0;   bx -= 96; }
  int c0 = bx * 32, r0 = blockIdx.y * 32;
  int tx = threadIdx.x, ty = threadIdx.y;  // (32,8)
  for(int i = 0; i < 4; i++)
    tile[ty + 8*i][tx] = src[(size_t)(r0 + ty + 8*i) * C + c0 + tx];
  __syncthreads();
  for(int i = 0; i < 4; i++)
    dst[(size_t)(droff + c0 + ty + 8*i) * 2048 + r0 + tx] = f2b(tile[tx][ty + 8*i]);
}

__global__ void prep(const float* g0, const float* b0, const float* m0, const float* v0,
                     const float* g2, const float* b2, const float* m2, const float* v2,
                     const float* bih0, const float* bhh0, const float* bih1, const float* bhh1,
                     float* sc0, float* sh0, float* sc2, float* sh2, float* lb0, float* lb1){
  int t = blockIdx.x * 256 + threadIdx.x;
  if(t < 2048){ float s = g0[t] * rsqrtf(v0[t] + 0.1f); sc0[t] = s; sh0[t] = b0[t] - m0[t] * s; }
  if(t < 1024){ float s = g2[t] * rsqrtf(v2[t] + 0.1f); sc2[t] = s; sh2[t] = b2[t] - m2[t] * s; }
  if(t < 4096){ lb0[t] = bih0[t] + bhh0[t]; lb1[t] = bih1[t] + bhh1[t]; }
}

__global__ void adj_kernel(const float* __restrict__ pos, u64* __restrict__ adjm){
  int b = blockIdx.x, l = threadIdx.x;  // 64 threads
  __shared__ float px[64], py[64];
  float2 p = ((const float2*)pos)[b * 64 + l];
  px[l] = p.x; py[l] = p.y;
  __syncthreads();
  float xi = px[l], yi = py[l];
  u64 m = 0;
  for(int j = 0; j < 64; j++){
    float dx = xi - px[j], dy = yi - py[j];
    if(dx * dx + dy * dy <= 16.0f) m |= (1ull << j);
  }
  adjm[b * 64 + l] = m;
}

// ---------------- bf16 MFMA GEMM (m97 structure) ----------------
// MODE 1: relu+bn -> bf16 Cb.  MODE 3: plain bf16 Cb.
template<int MODE>
__global__ __launch_bounds__(256) void gemm_bf16(
    const u16* __restrict__ A, const u16* __restrict__ Bt,
    float* __restrict__ Cf, u16* __restrict__ Cb,
    const float* __restrict__ p1, const float* __restrict__ p2,
    int M, int N, int K)
{
  constexpr int BM = 128, BN = 128, BK = 64;
  __shared__ alignas(16) u16 Al[BM * BK];
  __shared__ alignas(16) u16 Bl[BN * BK];
  int m0 = blockIdx.x * BM, n0 = blockIdx.y * BN;
  int t = threadIdx.x, w = t >> 6, l = t & 63;
  int wm = (w >> 1) * 64, wn = (w & 1) * 64;
  f32x4 acc[4][4];
  for(int a = 0; a < 4; a++) for(int b = 0; b < 4; b++) acc[a][b] = {0.f, 0.f, 0.f, 0.f};

  const short8* Ap = (const short8*)Al;
  const short8* Bp = (const short8*)Bl;

  for(int k0 = 0; k0 < K; k0 += BK){
    #pragma unroll
    for(int u = t; u < BM * 8; u += 256){
      int r = u >> 3, c = u & 7;
      gl_lds16(A + (size_t)(m0 + r) * K + k0 + ((c ^ (r & 7)) << 3), Al + u * 8);
    }
    #pragma unroll
    for(int u = t; u < BN * 8; u += 256){
      int r = u >> 3, c = u & 7;
      gl_lds16(Bt + (size_t)(n0 + r) * K + k0 + ((c ^ (r & 7)) << 3), Bl + u * 8);
    }
    __syncthreads();
    #pragma unroll
    for(int ks = 0; ks < 2; ks++){
      int kc = ks * 4 + (l >> 4);
      short8 av[4], bv[4];
      #pragma unroll
      for(int mi = 0; mi < 4; mi++){ int r = wm + mi * 16 + (l & 15); av[mi] = Ap[r * 8 + (kc ^ (r & 7))]; }
      #pragma unroll
      for(int ni = 0; ni < 4; ni++){ int r = wn + ni * 16 + (l & 15); bv[ni] = Bp[r * 8 + (kc ^ (r & 7))]; }
      #pragma unroll
      for(int mi = 0; mi < 4; mi++)
        #pragma unroll
        for(int ni = 0; ni < 4; ni++)
          acc[mi][ni] = __builtin_amdgcn_mfma_f32_16x16x32_bf16(av[mi], bv[ni], acc[mi][ni], 0, 0, 0);
    }
    __syncthreads();
  }

  int cr = m0 + wm + ((l >> 4) << 2);
  int cc = n0 + wn + (l & 15);
  for(int mi = 0; mi < 4; mi++)
    for(int ni = 0; ni < 4; ni++)
      for(int r = 0; r < 4; r++){
        int row = cr + mi * 16 + r, col = cc + ni * 16;
        float v = acc[mi][ni][r];
        if(MODE == 1){ v = fmaxf(v, 0.f) * p1[col] + p2[col]; Cb[(size_t)row * N + col] = f2b(v); }
        else if(MODE == 3){ Cb[(size_t)row * N + col] = f2b(v); }
        else { Cf[(size_t)row * N + col] = v; }
      }
}

// ---------------- split-K skinny GEMM (bf16 B), used for lin2 ----------------
__global__ __launch_bounds__(256) void gemm_sk(
    const u16* __restrict__ A, const u16* __restrict__ Bt, float* __restrict__ Cf,
    int N, int lda, int ldb, int kPer)
{
  constexpr int BM = 128, BN = 64, BK = 64;
  __shared__ alignas(16) u16 Al[BM * BK];
  __shared__ alignas(16) u16 Bl[BN * BK];
  int n0 = blockIdx.x * BN;
  int kb = blockIdx.y * kPer;
  float* C = Cf + (size_t)blockIdx.y * 128 * N;
  int t = threadIdx.x, w = t >> 6, l = t & 63;
  int wm = (w >> 1) * 64, wn = (w & 1) * 32;
  f32x4 acc[4][2];
  for(int a = 0; a < 4; a++) for(int b = 0; b < 2; b++) acc[a][b] = {0.f, 0.f, 0.f, 0.f};

  const short8* Ap = (const short8*)Al;
  const short8* Bp = (const short8*)Bl;

  for(int k0 = kb; k0 < kb + kPer; k0 += BK){
    #pragma unroll
    for(int u = t; u < BM * 8; u += 256){
      int r = u >> 3, c = u & 7;
      gl_lds16(A + (size_t)r * lda + k0 + ((c ^ (r & 7)) << 3), Al + u * 8);
    }
    #pragma unroll
    for(int u = t; u < BN * 8; u += 256){
      int r = u >> 3, c = u & 7;
      gl_lds16(Bt + (size_t)(n0 + r) * ldb + k0 + ((c ^ (r & 7)) << 3), Bl + u * 8);
    }
    __syncthreads();
    #pragma unroll
    for(int ks = 0; ks < 2; ks++){
      int kc = ks * 4 + (l >> 4);
      short8 av[4], bv[2];
      #pragma unroll
      for(int mi = 0; mi < 4; mi++){ int r = wm + mi * 16 + (l & 15); av[mi] = Ap[r * 8 + (kc ^ (r & 7))]; }
      #pragma unroll
      for(int ni = 0; ni < 2; ni++){ int r = wn + ni * 16 + (l & 15); bv[ni] = Bp[r * 8 + (kc ^ (r & 7))]; }
      #pragma unroll
      for(int mi = 0; mi < 4; mi++)
        #pragma unroll
        for(int ni = 0; ni < 2; ni++)
          acc[mi][ni] = __builtin_amdgcn_mfma_f32_16x16x32_bf16(av[mi], bv[ni], acc[mi][ni], 0, 0, 0);
    }
    __syncthreads();
  }

  int cr = wm + ((l >> 4) << 2);
  int cc = n0 + wn + (l & 15);
  for(int mi = 0; mi < 4; mi++)
    for(int ni = 0; ni < 2; ni++)
      for(int r = 0; r < 4; r++)
        C[(size_t)(cr + mi * 16 + r) * N + cc + ni * 16] = acc[mi][ni][r];
}

// ---------------- split-K skinny GEMM with f32 B (in-kernel bf16 conversion) ----------------
// Bt row n, col k: k < Kih ? Wih[n][k] : Whh[n][k - Kih]   (no pre-converted weights needed)
__global__ __launch_bounds__(256) void gemm_skf(
    const u16* __restrict__ A, const float* __restrict__ Wih, const float* __restrict__ Whh,
    float* __restrict__ Cf, int N, int lda, int Kih, int Khh, int kPer)
{
  constexpr int BM = 128, BN = 64, BK = 64;
  __shared__ alignas(16) u16 Al[BM * BK];
  __shared__ alignas(16) u16 Bl[BN * BK];
  int n0 = blockIdx.x * BN;
  int kb = blockIdx.y * kPer;
  float* C = Cf + (size_t)blockIdx.y * 128 * N;
  int t = threadIdx.x, w = t >> 6, l = t & 63;
  int wm = (w >> 1) * 64, wn = (w & 1) * 32;
  f32x4 acc[4][2];
  for(int a = 0; a < 4; a++) for(int b = 0; b < 2; b++) acc[a][b] = {0.f, 0.f, 0.f, 0.f};

  const short8* Ap = (const short8*)Al;
  const short8* Bp = (const short8*)Bl;

  for(int k0 = kb; k0 < kb + kPer; k0 += BK){
    // A: async global->LDS (bf16, pre-swizzled source)
    #pragma unroll
    for(int u = t; u < BM * 8; u += 256){
      int r = u >> 3, c = u & 7;
      gl_lds16(A + (size_t)r * lda + k0 + ((c ^ (r & 7)) << 3), Al + u * 8);
    }
    // B: reg-staged f32 -> bf16 -> swizzled LDS slot (64 rows x 8 chunks; 2 per thread)
    #pragma unroll
    for(int u = t; u < BN * 8; u += 256){
      int r = u >> 3, c = u & 7;
      int gk = k0 + c * 8;
      const float* src = (gk < Kih) ? (Wih + (size_t)(n0 + r) * Kih + gk)
                                    : (Whh + (size_t)(n0 + r) * Khh + (gk - Kih));
      float4 v0 = *(const float4*)src;
      float4 v1 = *(const float4*)(src + 4);
      short8 ov;
      ov[0] = (short)f2b(v0.x); ov[1] = (short)f2b(v0.y); ov[2] = (short)f2b(v0.z); ov[3] = (short)f2b(v0.w);
      ov[4] = (short)f2b(v1.x); ov[5] = (short)f2b(v1.y); ov[6] = (short)f2b(v1.z); ov[7] = (short)f2b(v1.w);
      ((short8*)Bl)[r * 8 + (c ^ (r & 7))] = ov;
    }
    __syncthreads();
    #pragma unroll
    for(int ks = 0; ks < 2; ks++){
      int kc = ks * 4 + (l >> 4);
      short8 av[4], bv[2];
      #pragma unroll
      for(int mi = 0; mi < 4; mi++){ int r = wm + mi * 16 + (l & 15); av[mi] = Ap[r * 8 + (kc ^ (r & 7))]; }
      #pragma unroll
      for(int ni = 0; ni < 2; ni++){ int r = wn + ni * 16 + (l & 15); bv[ni] = Bp[r * 8 + (kc ^ (r & 7))]; }
      #pragma unroll
      for(int mi = 0; mi < 4; mi++)
        #pragma unroll
        for(int ni = 0; ni < 2; ni++)
          acc[mi][ni] = __builtin_amdgcn_mfma_f32_16x16x32_bf16(av[mi], bv[ni], acc[mi][ni], 0, 0, 0);
    }
    __syncthreads();
  }

  int cr = wm + ((l >> 4) << 2);
  int cc = n0 + wn + (l & 15);
  for(int mi = 0; mi < 4; mi++)
    for(int ni = 0; ni < 2; ni++)
      for(int r = 0; r < 4; r++)
        C[(size_t)(cr + mi * 16 + r) * N + cc + ni * 16] = acc[mi][ni][r];
}

// ---------------- GAT attention scores es/ed (bf16 h, scalar loads) ----------------
__global__ __launch_bounds__(256) void gat_scores(const u16* __restrict__ h,
    const float* __restrict__ as1, const float* __restrict__ ad1,
    const float* __restrict__ as2, const float* __restrict__ ad2,
    float* __restrict__ es, float* __restrict__ ed){
  __shared__ float aS[16][64], aD[16][64];
  int t = threadIdx.x;
  for(int i = t; i < 1024; i += 256){
    int cc = i >> 6, d = i & 63;
    aS[cc][d] = (cc < 8) ? as1[i] : as2[i - 512];
    aD[cc][d] = (cc < 8) ? ad1[i] : ad2[i - 512];
  }
  __syncthreads();
  int w = t >> 6, l = t & 63;
  int node = blockIdx.x * 4 + w;
  const u16* hr = h + (size_t)node * 1024;
  for(int cc = 0; cc < 16; cc++){
    float v = b2f(hr[cc * 64 + l]);
    float ps = v * aS[cc][l], pd = v * aD[cc][l];
    for(int o = 32; o; o >>= 1){ ps += __shfl_down(ps, o); pd += __shfl_down(pd, o); }
    if(l == 0){ es[node * 16 + cc] = ps; ed[node * 16 + cc] = pd; }
  }
}

// ---------------- GAT attention+aggregate (bf16 x2 out, scalar stores) ----------------
__global__ __launch_bounds__(256) void gat_attn2(const u64* __restrict__ adjm,
    const float* __restrict__ es, const float* __restrict__ ed,
    const u16* __restrict__ h, const float* __restrict__ b1, const float* __restrict__ b2,
    u16* __restrict__ x2b){
  int b = blockIdx.x;
  int cv = blockIdx.y >> 3, hh = blockIdx.y & 7;
  __shared__ float hst[64][64];
  __shared__ float alphaL[64][65];
  __shared__ float esl[64], edl[64];
  __shared__ u64 adjs[64];
  int t = threadIdx.x, w = t >> 6, l = t & 63;
  {
    int j = t >> 2, d0 = (t & 3) * 16;
    const u16* hr = h + (size_t)(b * 64 + j) * 1024 + cv * 512 + hh * 64 + d0;
    #pragma unroll
    for(int k = 0; k < 16; k++) hst[j][d0 + k] = b2f(hr[k]);
  }
  if(t < 64){
    esl[t] = es[(b * 64 + t) * 16 + cv * 8 + hh];
    edl[t] = ed[(b * 64 + t) * 16 + cv * 8 + hh];
    adjs[t] = adjm[b * 64 + t];
  }
  __syncthreads();
  for(int it = 0; it < 16; it++){
    int i = it * 4 + w;
    bool on = (adjs[i] >> l) & 1;
    float e = edl[i] + esl[l];
    e = e > 0.f ? e : 0.2f * e;
    float mx = on ? e : -1e30f;
    for(int o = 32; o; o >>= 1) mx = fmaxf(mx, __shfl_xor(mx, o));
    float p = on ? __expf(e - mx) : 0.f;
    float s = p;
    for(int o = 32; o; o >>= 1) s += __shfl_xor(s, o);
    alphaL[i][l] = p / s;
  }
  __syncthreads();
  int i = t >> 2, q = t & 3;
  float acc[16];
  #pragma unroll
  for(int k = 0; k < 16; k++) acc[k] = 0.f;
  for(int j = 0; j < 64; j++){
    float al = alphaL[i][j];
    const float* hr = &hst[j][q * 16];
    #pragma unroll
    for(int k = 0; k < 16; k++) acc[k] += al * hr[k];
  }
  const float* bias = (cv ? b2 : b1) + hh * 64 + q * 16;
  u16* op = x2b + (size_t)(b * 64 + i) * 1024 + cv * 512 + hh * 64 + q * 16;
  #pragma unroll
  for(int k = 0; k < 16; k++) op[k] = f2b(fmaxf(acc[k] + bias[k], 0.f));
}

// ---------------- Set2Set step-0 shortcut (input == 0 for all graphs) ----------------
__global__ void s2s0_h0(const float* __restrict__ lb0, float* __restrict__ h0u){
  int j = blockIdx.x * 256 + threadIdx.x;
  if(j >= 1024) return;
  float zi = lb0[j], zg = lb0[2048 + j], zo = lb0[3072 + j];
  float si = 1.f / (1.f + __expf(-zi));
  float so = 1.f / (1.f + __expf(-zo));
  float cn = si * tanhf(zg);
  h0u[j] = so * tanhf(cn);
}

__global__ __launch_bounds__(256) void s2s0_gemv(const float* __restrict__ Wih1,
    const float* __restrict__ lb1, const float* __restrict__ h0u, float* __restrict__ z1u){
  __shared__ float hs[1024];
  int t = threadIdx.x;
  for(int i = t; i < 1024; i += 256) hs[i] = h0u[i];
  __syncthreads();
  int w = t >> 6, l = t & 63;
  int r = blockIdx.x * 4 + w;
  const float* wr = Wih1 + (size_t)r * 1024;
  float s = 0.f;
  #pragma unroll
  for(int k = 0; k < 16; k++) s += wr[l + 64 * k] * hs[l + 64 * k];
  for(int o = 32; o; o >>= 1) s += __shfl_xor(s, o);
  if(l == 0) z1u[r] = s + lb1[r];
}

__global__ void s2s0_bcast(const float* __restrict__ lb0, const float* __restrict__ z1u,
    float* __restrict__ c0b, float* __restrict__ c1b, float* __restrict__ h1f,
    u16* __restrict__ ac0, u16* __restrict__ ac1){
  int t = blockIdx.x * 256 + threadIdx.x;  // 128*1024
  int b = t >> 10, j = t & 1023;
  float zi0 = lb0[j], zg0 = lb0[2048 + j], zo0 = lb0[3072 + j];
  float c0 = (1.f / (1.f + __expf(-zi0))) * tanhf(zg0);
  float h0 = (1.f / (1.f + __expf(-zo0))) * tanhf(c0);
  float zi1 = z1u[j], zg1 = z1u[2048 + j], zo1 = z1u[3072 + j];
  float c1 = (1.f / (1.f + __expf(-zi1))) * tanhf(zg1);
  float h1 = (1.f / (1.f + __expf(-zo1))) * tanhf(c1);
  c0b[t] = c0;
  c1b[t] = c1;
  h1f[t] = h1;
  u16 h0b = f2b(h0), h1b = f2b(h1);
  ac0[(size_t)b * 3072 + j] = h1b;
  ac0[(size_t)b * 3072 + 2048 + j] = h0b;
  ac1[(size_t)b * 2048 + j] = h0b;
  ac1[(size_t)b * 2048 + 1024 + j] = h1b;
}

// ---------------- LSTM gates (sum ns split-K partials) ----------------
__global__ void lstm_gate0(const float* __restrict__ zp, const float* __restrict__ lb,
                           float* __restrict__ c, u16* __restrict__ ac0, u16* __restrict__ ac1,
                           int ns){
  int t = blockIdx.x * 256 + threadIdx.x;  // 128*1024
  int b = t >> 10, j = t & 1023;
  size_t base = (size_t)b * 4096;
  float zi = 0, zf = 0, zg = 0, zo = 0;
  for(int s = 0; s < ns; s++){
    const float* zr = zp + (size_t)s * 524288 + base;
    zi += zr[j]; zf += zr[1024 + j]; zg += zr[2048 + j]; zo += zr[3072 + j];
  }
  zi += lb[j]; zf += lb[1024 + j]; zg += lb[2048 + j]; zo += lb[3072 + j];
  float ci = c[t];
  float si = 1.f / (1.f + __expf(-zi)), sf = 1.f / (1.f + __expf(-zf)), so = 1.f / (1.f + __expf(-zo));
  float cn = sf * ci + si * tanhf(zg);
  c[t] = cn;
  u16 hb = f2b(so * tanhf(cn));
  ac0[(size_t)b * 3072 + 2048 + j] = hb;
  ac1[(size_t)b * 2048 + j] = hb;
}

__global__ void lstm_gate1(const float* __restrict__ zp, const float* __restrict__ lb,
                           float* __restrict__ c, float* __restrict__ h1f,
                           u16* __restrict__ ac1, u16* __restrict__ ac0, int ns){
  int t = blockIdx.x * 256 + threadIdx.x;
  int b = t >> 10, j = t & 1023;
  size_t base = (size_t)b * 4096;
  float zi = 0, zf = 0, zg = 0, zo = 0;
  for(int s = 0; s < ns; s++){
    const float* zr = zp + (size_t)s * 524288 + base;
    zi += zr[j]; zf += zr[1024 + j]; zg += zr[2048 + j]; zo += zr[3072 + j];
  }
  zi += lb[j]; zf += lb[1024 + j]; zg += lb[2048 + j]; zo += lb[3072 + j];
  float ci = c[t];
  float si = 1.f / (1.f + __expf(-zi)), sf = 1.f / (1.f + __expf(-zf)), so = 1.f / (1.f + __expf(-zo));
  float cn = sf * ci + si * tanhf(zg);
  c[t] = cn;
  float hn = so * tanhf(cn);
  h1f[t] = hn;
  u16 hb = f2b(hn);
  ac1[(size_t)b * 2048 + 1024 + j] = hb;
  ac0[(size_t)b * 3072 + j] = hb;
}

// ---------------- Set2Set attention (bf16 x2, scalar loads) ----------------
__global__ __launch_bounds__(256) void s2s_e(const u16* __restrict__ x2b,
    const float* __restrict__ h1, float* __restrict__ e){
  int t = threadIdx.x, w = t >> 6, l = t & 63;
  int node = blockIdx.x * 4 + w;
  int b = node >> 6;
  const u16* xr = x2b + (size_t)node * 1024;
  const float* hr = h1 + (size_t)b * 1024;
  float s = 0.f;
  #pragma unroll
  for(int k = 0; k < 16; k++){
    int d = k * 64 + l;
    s += b2f(xr[d]) * hr[d];
  }
  for(int o = 32; o; o >>= 1) s += __shfl_xor(s, o);
  if(l == 0) e[node] = s;
}

__global__ __launch_bounds__(256) void s2s_r(const u16* __restrict__ x2b,
    const float* __restrict__ e, u16* __restrict__ ac0){
  int b = blockIdx.x, sl = blockIdx.y;
  __shared__ float al[64];
  int t = threadIdx.x;
  if(t < 64){
    float v = e[b * 64 + t];
    float mx = v;
    for(int o = 32; o; o >>= 1) mx = fmaxf(mx, __shfl_xor(mx, o));
    float p = __expf(v - mx);
    float ss = p;
    for(int o = 32; o; o >>= 1) ss += __shfl_xor(ss, o);
    al[t] = p / ss;
  }
  __syncthreads();
  int d = sl * 256 + t;
  const u16* xp = x2b + (size_t)b * 65536 + d;
  float r = 0.f;
  #pragma unroll 8
  for(int j = 0; j < 64; j++) r += al[j] * b2f(xp[j * 1024]);
  ac0[(size_t)b * 3072 + 1024 + d] = f2b(r);
}

// ---------------- lin2 combine (8 split partials) + bn + relu + lin3 ----------------
__global__ __launch_bounds__(256) void lin3(const float* __restrict__ zp2,
    const float* __restrict__ sc2, const float* __restrict__ sh2,
    const float* __restrict__ W3, const float* __restrict__ b3, float* __restrict__ out){
  int b = blockIdx.x;
  __shared__ float yl[1024];
  int t = threadIdx.x, w = t >> 6, l = t & 63;
  for(int d = t; d < 1024; d += 256){
    float v = 0.f;
    for(int s = 0; s < 8; s++) v += zp2[(size_t)s * 131072 + b * 1024 + d];
    yl[d] = fmaxf(v, 0.f) * sc2[d] + sh2[d];
  }
  __syncthreads();
  for(int n = w; n < 10; n += 4){
    float s = 0.f;
    for(int d = l; d < 1024; d += 64) s += yl[d] * W3[d * 10 + n];
    for(int o = 32; o; o >>= 1) s += __shfl_xor(s, o);
    if(l == 0) out[b * 10 + n] = s + b3[n];
  }
}

extern "C" void kernel_launch(void* const* d_in, const int* in_sizes, int n_in,
                              void* d_out, int out_size, void* d_ws, size_t ws_size,
                              hipStream_t stream){
  const float* x    = (const float*)d_in[0];
  const float* pos  = (const float*)d_in[1];
  const float* W0   = (const float*)d_in[3];
  const float* bn0g = (const float*)d_in[4];
  const float* bn0b = (const float*)d_in[5];
  const float* bn0m = (const float*)d_in[6];
  const float* bn0v = (const float*)d_in[7];
  const float* Wg1  = (const float*)d_in[8];
  const float* as1  = (const float*)d_in[9];
  const float* ad1  = (const float*)d_in[10];
  const float* b1   = (const float*)d_in[11];
  const float* Wg2  = (const float*)d_in[12];
  const float* as2  = (const float*)d_in[13];
  const float* ad2  = (const float*)d_in[14];
  const float* b2   = (const float*)d_in[15];
  const float* Wih0 = (const float*)d_in[16];
  const float* Whh0 = (const float*)d_in[17];
  const float* bih0 = (const float*)d_in[18];
  const float* bhh0 = (const float*)d_in[19];
  const float* Wih1 = (const float*)d_in[20];
  const float* Whh1 = (const float*)d_in[21];
  const float* bih1 = (const float*)d_in[22];
  const float* bhh1 = (const float*)d_in[23];
  const float* W2   = (const float*)d_in[24];
  const float* bn2g = (const float*)d_in[25];
  const float* bn2b = (const float*)d_in[26];
  const float* bn2m = (const float*)d_in[27];
  const float* bn2v = (const float*)d_in[28];
  const float* W3   = (const float*)d_in[29];
  const float* b3   = (const float*)d_in[30];

  char* ws = (char*)d_ws;
  u16*   xbf  = (u16*)(ws + O_XBF);
  u16*   x2b  = (u16*)(ws + O_XBF);   // alias: x bf16 dead after GEMM1
  u16*   w0t  = (u16*)(ws + O_W0T);
  u16*   wgt  = (u16*)(ws + O_WGT);
  u16*   w2t  = (u16*)(ws + O_W2T);
  u16*   xb   = (u16*)(ws + O_XB);
  u16*   hb   = (u16*)(ws + O_H);      // h bf16 (first 16MB of O_H region)
  float* es   = (float*)(ws + O_ES);
  float* ed   = (float*)(ws + O_ED);
  u64*   adjm = (u64*)(ws + O_ADJ);
  float* sc0  = (float*)(ws + O_SC0);
  float* sh0  = (float*)(ws + O_SH0);
  float* sc2  = (float*)(ws + O_SC2);
  float* sh2  = (float*)(ws + O_SH2);
  float* lb0  = (float*)(ws + O_LB0);
  float* lb1  = (float*)(ws + O_LB1);
  char*  s2sb = ws + O_H;               // s2s scratch overlays h after GAT
  u16*   ac0  = (u16*)(s2sb + S_AC0);
  u16*   ac1  = (u16*)(s2sb + S_AC1);
  float* c0b  = (float*)(s2sb + S_C0);
  float* c1b  = (float*)(s2sb + S_C1);
  float* h1f  = (float*)(s2sb + S_H1F);
  float* zp   = (float*)(s2sb + S_ZP);
  float* ebuf = (float*)(s2sb + S_E);
  float* h0u  = (float*)(s2sb + S_H0U);
  float* z1u  = (float*)(s2sb + S_Z1U);

  // --- prep + adjacency + conversions (x + transposed weights only; LSTM weights stay f32) ---
  prep<<<16, 256, 0, stream>>>(bn0g, bn0b, bn0m, bn0v, bn2g, bn2b, bn2m, bn2v,
                               bih0, bhh0, bih1, bhh1, sc0, sh0, sc2, sh2, lb0, lb1);
  adj_kernel<<<128, 64, 0, stream>>>(pos, adjm);
  cvt_x<<<16384, 256, 0, stream>>>(x, xbf);
  cvt_tr<<<dim3(128, 64), dim3(32, 8), 0, stream>>>(W0, Wg1, Wg2, W2, w0t, wgt, w2t);

  // --- GEMM1: xb = bf16(bn0(relu(x @ W0))) ; GAT h = xb @ [Wg1|Wg2] (bf16 out) ---
  gemm_bf16<1><<<dim3(64, 16), 256, 0, stream>>>(xbf, w0t, nullptr, xb, sc0, sh0, 8192, 2048, 2048);
  gemm_bf16<3><<<dim3(64, 8), 256, 0, stream>>>(xb, wgt, nullptr, hb, nullptr, nullptr, 8192, 1024, 2048);
  // --- GAT attention ---
  gat_scores<<<2048, 256, 0, stream>>>(hb, as1, ad1, as2, ad2, es, ed);
  gat_attn2<<<dim3(128, 16), 256, 0, stream>>>(adjm, es, ed, hb, b1, b2, x2b);

  // --- Set2Set step 0: LSTM input is 0 -> state is graph-uniform (bias-derived) ---
  s2s0_h0<<<4, 256, 0, stream>>>(lb0, h0u);
  s2s0_gemv<<<1024, 256, 0, stream>>>(Wih1, lb1, h0u, z1u);
  s2s0_bcast<<<512, 256, 0, stream>>>(lb0, z1u, c0b, c1b, h1f, ac0, ac1);
  s2s_e<<<2048, 256, 0, stream>>>(x2b, h1f, ebuf);
  s2s_r<<<dim3(128, 4), 256, 0, stream>>>(x2b, ebuf, ac0);

  // --- Set2Set step 1 (full; LSTM weights read directly as f32) ---
  gemm_skf<<<dim3(64, 8), 256, 0, stream>>>(ac0, Wih0, Whh0, zp, 4096, 3072, 2048, 1024, 384);
  lstm_gate0<<<512, 256, 0, stream>>>(zp, lb0, c0b, ac0, ac1, 8);
  gemm_skf<<<dim3(64, 8), 256, 0, stream>>>(ac1, Wih1, Whh1, zp, 4096, 2048, 1024, 1024, 256);
  lstm_gate1<<<512, 256, 0, stream>>>(zp, lb1, c1b, h1f, ac1, ac0, 8);
  s2s_e<<<2048, 256, 0, stream>>>(x2b, h1f, ebuf);
  s2s_r<<<dim3(128, 4), 256, 0, stream>>>(x2b, ebuf, ac0);

  // --- lin2 (split-K 8) + lin3 ---
  gemm_sk<<<dim3(16, 8), 256, 0, stream>>>(ac0, w2t, zp, 1024, 3072, 2048, 256);
  lin3<<<128, 256, 0, stream>>>(zp, sc2, sh2, W3, b3, (float*)d_out);
}

// Round 10
// 308.391 us; speedup vs baseline: 5.1676x; 1.0332x over previous
//
#include <hip/hip_runtime.h>
#include <hip/hip_bf16.h>

typedef unsigned short u16;
typedef __attribute__((ext_vector_type(8))) short short8;
typedef __attribute__((ext_vector_type(4))) float f32x4;
typedef unsigned long long u64;

#define DI __device__ __forceinline__

DI u16 f2b(float f){
  unsigned u = __float_as_uint(f);
  unsigned r = 0x7fffu + ((u >> 16) & 1u);
  return (u16)((u + r) >> 16);
}
DI float b2f(u16 u){ return __uint_as_float((unsigned)u << 16); }

DI void gl_lds16(const void* g, void* l){
  __builtin_amdgcn_global_load_lds((const __attribute__((address_space(1))) void*)g,
                                   (__attribute__((address_space(3))) void*)l, 16, 0, 0);
}

// ---------------- workspace layout (bytes) ----------------
constexpr size_t O_XBF = 0;                    // 33554432: x bf16 [8192,2048]; later x2 bf16 [8192,1024] (16MB)
constexpr size_t O_W0T = O_XBF + 33554432;     // 8388608:  W0^T bf16 [2048,2048]
constexpr size_t O_WGT = O_W0T + 8388608;      // 4194304:  [Wg1|Wg2]^T bf16 [1024,2048]
constexpr size_t O_W2T = O_WGT + 4194304;      // 4194304:  W2^T bf16 [1024,2048]
constexpr size_t O_XB  = O_W2T + 4194304;      // 33554432: xb bf16 [8192,2048]
constexpr size_t O_H   = O_XB  + 33554432;     // region: h bf16 [8192,1024] (16MB); Set2Set scratch after GAT
constexpr size_t O_ES  = O_H   + 33554432;     // 524288 (unused now)
constexpr size_t O_ED  = O_ES  + 524288;       // 524288 (unused now)
constexpr size_t O_ADJ = O_ED  + 524288;       // 65536
constexpr size_t O_SC0 = O_ADJ + 65536;
constexpr size_t O_SH0 = O_SC0 + 8192;
constexpr size_t O_SC2 = O_SH0 + 8192;
constexpr size_t O_SH2 = O_SC2 + 4096;
constexpr size_t O_LB0 = O_SH2 + 4096;
constexpr size_t O_LB1 = O_LB0 + 16384;
// Set2Set scratch inside O_H (h is dead after gat_attn2):
constexpr size_t S_AC0 = 0;                    // 786432: acat0 bf16 [128][3072] = [q_star(2048) | h0(1024)]
constexpr size_t S_AC1 = S_AC0 + 786432;       // 524288: acat1 bf16 [128][2048] = [h0 | h1]
constexpr size_t S_C0  = S_AC1 + 524288;       // 524288
constexpr size_t S_C1  = S_C0  + 524288;       // 524288
constexpr size_t S_H1F = S_C1  + 524288;       // 524288: h1 f32
constexpr size_t S_ZP  = S_H1F + 524288;       // 16777216: split-K partials (8 x [128*4096] f32)
constexpr size_t S_E   = S_ZP  + 16777216;     // 32768: s2s scores e[8192]
constexpr size_t S_Z1U = S_E   + 32768;        // 16384: step-0 uniform z1 f32[4096]

// ---------------- x f32 -> bf16 ----------------
__global__ __launch_bounds__(256) void cvt_x(const float* __restrict__ x, u16* __restrict__ xbf){
  int idx = blockIdx.x * 256 + threadIdx.x;      // 16384 blocks: [8192,2048]/4
  int r = idx >> 9, c4 = (idx & 511) << 2;
  float4 v = *(const float4*)(x + (size_t)r * 2048 + c4);
  u16 o[4] = { f2b(v.x), f2b(v.y), f2b(v.z), f2b(v.w) };
  *(ushort4*)(xbf + (size_t)r * 2048 + c4) = *(ushort4*)o;
}

// ---------------- fused f32->bf16 transposes: W0, Wg1, Wg2, W2 ----------------
__global__ void cvt_tr(const float* __restrict__ W0, const float* __restrict__ Wg1,
                       const float* __restrict__ Wg2, const float* __restrict__ W2,
                       u16* __restrict__ w0t, u16* __restrict__ wgt, u16* __restrict__ w2t){
  __shared__ float tile[32][33];
  int bx = blockIdx.x;
  const float* src; u16* dst; int C, droff;
  if(bx < 64){      src = W0;  dst = w0t; C = 2048; droff = 0; }
  else if(bx < 80){ src = Wg1; dst = wgt; C = 512;  droff = 0;   bx -= 64; }
  else if(bx < 96){ src = Wg2; dst = wgt; C = 512;  droff = 512; bx -= 80; }
  else {            src = W2;  dst = w2t; C = 1024; droff = 0;   bx -= 96; }
  int c0 = bx * 32, r0 = blockIdx.y * 32;
  int tx = threadIdx.x, ty = threadIdx.y;  // (32,8)
  for(int i = 0; i < 4; i++)
    tile[ty + 8*i][tx] = src[(size_t)(r0 + ty + 8*i) * C + c0 + tx];
  __syncthreads();
  for(int i = 0; i < 4; i++)
    dst[(size_t)(droff + c0 + ty + 8*i) * 2048 + r0 + tx] = f2b(tile[tx][ty + 8*i]);
}

// ---------------- merged prep + adjacency ----------------
__global__ __launch_bounds__(256) void prep_adj(
    const float* __restrict__ g0, const float* __restrict__ b0, const float* __restrict__ m0, const float* __restrict__ v0,
    const float* __restrict__ g2, const float* __restrict__ b2, const float* __restrict__ m2, const float* __restrict__ v2,
    const float* __restrict__ bih0, const float* __restrict__ bhh0,
    const float* __restrict__ bih1, const float* __restrict__ bhh1,
    float* __restrict__ sc0, float* __restrict__ sh0, float* __restrict__ sc2, float* __restrict__ sh2,
    float* __restrict__ lb0, float* __restrict__ lb1,
    const float* __restrict__ pos, u64* __restrict__ adjm){
  int bx = blockIdx.x, tid = threadIdx.x;
  if(bx < 16){
    int t = bx * 256 + tid;
    if(t < 2048){ float s = g0[t] * rsqrtf(v0[t] + 0.1f); sc0[t] = s; sh0[t] = b0[t] - m0[t] * s; }
    if(t < 1024){ float s = g2[t] * rsqrtf(v2[t] + 0.1f); sc2[t] = s; sh2[t] = b2[t] - m2[t] * s; }
    lb0[t] = bih0[t] + bhh0[t];
    lb1[t] = bih1[t] + bhh1[t];
  } else {
    __shared__ float px[4][64], py[4][64];
    int w = tid >> 6, l = tid & 63;
    int g = (bx - 16) * 4 + w;              // 32 blocks -> 128 graphs
    float2 p = ((const float2*)pos)[g * 64 + l];
    px[w][l] = p.x; py[w][l] = p.y;
    __syncthreads();
    float xi = p.x, yi = p.y;
    u64 m = 0;
    for(int j = 0; j < 64; j++){
      float dx = xi - px[w][j], dy = yi - py[w][j];
      if(dx * dx + dy * dy <= 16.0f) m |= (1ull << j);
    }
    adjm[g * 64 + l] = m;
  }
}

// ---------------- bf16 MFMA GEMM (m97 structure) ----------------
// MODE 1: relu+bn -> bf16 Cb.  MODE 3: plain bf16 Cb.
template<int MODE>
__global__ __launch_bounds__(256) void gemm_bf16(
    const u16* __restrict__ A, const u16* __restrict__ Bt,
    float* __restrict__ Cf, u16* __restrict__ Cb,
    const float* __restrict__ p1, const float* __restrict__ p2,
    int M, int N, int K)
{
  constexpr int BM = 128, BN = 128, BK = 64;
  __shared__ alignas(16) u16 Al[BM * BK];
  __shared__ alignas(16) u16 Bl[BN * BK];
  int m0 = blockIdx.x * BM, n0 = blockIdx.y * BN;
  int t = threadIdx.x, w = t >> 6, l = t & 63;
  int wm = (w >> 1) * 64, wn = (w & 1) * 64;
  f32x4 acc[4][4];
  for(int a = 0; a < 4; a++) for(int b = 0; b < 4; b++) acc[a][b] = {0.f, 0.f, 0.f, 0.f};

  const short8* Ap = (const short8*)Al;
  const short8* Bp = (const short8*)Bl;

  for(int k0 = 0; k0 < K; k0 += BK){
    #pragma unroll
    for(int u = t; u < BM * 8; u += 256){
      int r = u >> 3, c = u & 7;
      gl_lds16(A + (size_t)(m0 + r) * K + k0 + ((c ^ (r & 7)) << 3), Al + u * 8);
    }
    #pragma unroll
    for(int u = t; u < BN * 8; u += 256){
      int r = u >> 3, c = u & 7;
      gl_lds16(Bt + (size_t)(n0 + r) * K + k0 + ((c ^ (r & 7)) << 3), Bl + u * 8);
    }
    __syncthreads();
    #pragma unroll
    for(int ks = 0; ks < 2; ks++){
      int kc = ks * 4 + (l >> 4);
      short8 av[4], bv[4];
      #pragma unroll
      for(int mi = 0; mi < 4; mi++){ int r = wm + mi * 16 + (l & 15); av[mi] = Ap[r * 8 + (kc ^ (r & 7))]; }
      #pragma unroll
      for(int ni = 0; ni < 4; ni++){ int r = wn + ni * 16 + (l & 15); bv[ni] = Bp[r * 8 + (kc ^ (r & 7))]; }
      #pragma unroll
      for(int mi = 0; mi < 4; mi++)
        #pragma unroll
        for(int ni = 0; ni < 4; ni++)
          acc[mi][ni] = __builtin_amdgcn_mfma_f32_16x16x32_bf16(av[mi], bv[ni], acc[mi][ni], 0, 0, 0);
    }
    __syncthreads();
  }

  int cr = m0 + wm + ((l >> 4) << 2);
  int cc = n0 + wn + (l & 15);
  for(int mi = 0; mi < 4; mi++)
    for(int ni = 0; ni < 4; ni++)
      for(int r = 0; r < 4; r++){
        int row = cr + mi * 16 + r, col = cc + ni * 16;
        float v = acc[mi][ni][r];
        if(MODE == 1){ v = fmaxf(v, 0.f) * p1[col] + p2[col]; Cb[(size_t)row * N + col] = f2b(v); }
        else if(MODE == 3){ Cb[(size_t)row * N + col] = f2b(v); }
        else { Cf[(size_t)row * N + col] = v; }
      }
}

// ---------------- split-K skinny GEMM (bf16 B), used for lin2 ----------------
__global__ __launch_bounds__(256) void gemm_sk(
    const u16* __restrict__ A, const u16* __restrict__ Bt, float* __restrict__ Cf,
    int N, int lda, int ldb, int kPer)
{
  constexpr int BM = 128, BN = 64, BK = 64;
  __shared__ alignas(16) u16 Al[BM * BK];
  __shared__ alignas(16) u16 Bl[BN * BK];
  int n0 = blockIdx.x * BN;
  int kb = blockIdx.y * kPer;
  float* C = Cf + (size_t)blockIdx.y * 128 * N;
  int t = threadIdx.x, w = t >> 6, l = t & 63;
  int wm = (w >> 1) * 64, wn = (w & 1) * 32;
  f32x4 acc[4][2];
  for(int a = 0; a < 4; a++) for(int b = 0; b < 2; b++) acc[a][b] = {0.f, 0.f, 0.f, 0.f};

  const short8* Ap = (const short8*)Al;
  const short8* Bp = (const short8*)Bl;

  for(int k0 = kb; k0 < kb + kPer; k0 += BK){
    #pragma unroll
    for(int u = t; u < BM * 8; u += 256){
      int r = u >> 3, c = u & 7;
      gl_lds16(A + (size_t)r * lda + k0 + ((c ^ (r & 7)) << 3), Al + u * 8);
    }
    #pragma unroll
    for(int u = t; u < BN * 8; u += 256){
      int r = u >> 3, c = u & 7;
      gl_lds16(Bt + (size_t)(n0 + r) * ldb + k0 + ((c ^ (r & 7)) << 3), Bl + u * 8);
    }
    __syncthreads();
    #pragma unroll
    for(int ks = 0; ks < 2; ks++){
      int kc = ks * 4 + (l >> 4);
      short8 av[4], bv[2];
      #pragma unroll
      for(int mi = 0; mi < 4; mi++){ int r = wm + mi * 16 + (l & 15); av[mi] = Ap[r * 8 + (kc ^ (r & 7))]; }
      #pragma unroll
      for(int ni = 0; ni < 2; ni++){ int r = wn + ni * 16 + (l & 15); bv[ni] = Bp[r * 8 + (kc ^ (r & 7))]; }
      #pragma unroll
      for(int mi = 0; mi < 4; mi++)
        #pragma unroll
        for(int ni = 0; ni < 2; ni++)
          acc[mi][ni] = __builtin_amdgcn_mfma_f32_16x16x32_bf16(av[mi], bv[ni], acc[mi][ni], 0, 0, 0);
    }
    __syncthreads();
  }

  int cr = wm + ((l >> 4) << 2);
  int cc = n0 + wn + (l & 15);
  for(int mi = 0; mi < 4; mi++)
    for(int ni = 0; ni < 2; ni++)
      for(int r = 0; r < 4; r++)
        C[(size_t)(cr + mi * 16 + r) * N + cc + ni * 16] = acc[mi][ni][r];
}

// ---------------- split-K skinny GEMM with f32 B (in-kernel bf16 conversion) ----------------
__global__ __launch_bounds__(256) void gemm_skf(
    const u16* __restrict__ A, const float* __restrict__ Wih, const float* __restrict__ Whh,
    float* __restrict__ Cf, int N, int lda, int Kih, int Khh, int kPer)
{
  constexpr int BM = 128, BN = 64, BK = 64;
  __shared__ alignas(16) u16 Al[BM * BK];
  __shared__ alignas(16) u16 Bl[BN * BK];
  int n0 = blockIdx.x * BN;
  int kb = blockIdx.y * kPer;
  float* C = Cf + (size_t)blockIdx.y * 128 * N;
  int t = threadIdx.x, w = t >> 6, l = t & 63;
  int wm = (w >> 1) * 64, wn = (w & 1) * 32;
  f32x4 acc[4][2];
  for(int a = 0; a < 4; a++) for(int b = 0; b < 2; b++) acc[a][b] = {0.f, 0.f, 0.f, 0.f};

  const short8* Ap = (const short8*)Al;
  const short8* Bp = (const short8*)Bl;

  for(int k0 = kb; k0 < kb + kPer; k0 += BK){
    #pragma unroll
    for(int u = t; u < BM * 8; u += 256){
      int r = u >> 3, c = u & 7;
      gl_lds16(A + (size_t)r * lda + k0 + ((c ^ (r & 7)) << 3), Al + u * 8);
    }
    #pragma unroll
    for(int u = t; u < BN * 8; u += 256){
      int r = u >> 3, c = u & 7;
      int gk = k0 + c * 8;
      const float* src = (gk < Kih) ? (Wih + (size_t)(n0 + r) * Kih + gk)
                                    : (Whh + (size_t)(n0 + r) * Khh + (gk - Kih));
      float4 v0 = *(const float4*)src;
      float4 v1 = *(const float4*)(src + 4);
      short8 ov;
      ov[0] = (short)f2b(v0.x); ov[1] = (short)f2b(v0.y); ov[2] = (short)f2b(v0.z); ov[3] = (short)f2b(v0.w);
      ov[4] = (short)f2b(v1.x); ov[5] = (short)f2b(v1.y); ov[6] = (short)f2b(v1.z); ov[7] = (short)f2b(v1.w);
      ((short8*)Bl)[r * 8 + (c ^ (r & 7))] = ov;
    }
    __syncthreads();
    #pragma unroll
    for(int ks = 0; ks < 2; ks++){
      int kc = ks * 4 + (l >> 4);
      short8 av[4], bv[2];
      #pragma unroll
      for(int mi = 0; mi < 4; mi++){ int r = wm + mi * 16 + (l & 15); av[mi] = Ap[r * 8 + (kc ^ (r & 7))]; }
      #pragma unroll
      for(int ni = 0; ni < 2; ni++){ int r = wn + ni * 16 + (l & 15); bv[ni] = Bp[r * 8 + (kc ^ (r & 7))]; }
      #pragma unroll
      for(int mi = 0; mi < 4; mi++)
        #pragma unroll
        for(int ni = 0; ni < 2; ni++)
          acc[mi][ni] = __builtin_amdgcn_mfma_f32_16x16x32_bf16(av[mi], bv[ni], acc[mi][ni], 0, 0, 0);
    }
    __syncthreads();
  }

  int cr = wm + ((l >> 4) << 2);
  int cc = n0 + wn + (l & 15);
  for(int mi = 0; mi < 4; mi++)
    for(int ni = 0; ni < 2; ni++)
      for(int r = 0; r < 4; r++)
        C[(size_t)(cr + mi * 16 + r) * N + cc + ni * 16] = acc[mi][ni][r];
}

// ---------------- GAT: scores (fused) + softmax + aggregate, per (graph, conv, head) ----------------
__global__ __launch_bounds__(256) void gat_attn2(const u64* __restrict__ adjm,
    const u16* __restrict__ h,
    const float* __restrict__ as1, const float* __restrict__ ad1,
    const float* __restrict__ as2, const float* __restrict__ ad2,
    const float* __restrict__ b1, const float* __restrict__ b2,
    u16* __restrict__ x2b){
  int b = blockIdx.x;
  int cv = blockIdx.y >> 3, hh = blockIdx.y & 7;
  __shared__ float hst[64][64];
  __shared__ float alphaL[64][65];
  __shared__ float esl[64], edl[64];
  __shared__ u64 adjs[64];
  int t = threadIdx.x, w = t >> 6, l = t & 63;
  {
    int j = t >> 2, d0 = (t & 3) * 16;
    const u16* hr = h + (size_t)(b * 64 + j) * 1024 + cv * 512 + hh * 64 + d0;
    #pragma unroll
    for(int k = 0; k < 16; k++) hst[j][d0 + k] = b2f(hr[k]);
  }
  if(t < 64) adjs[t] = adjm[b * 64 + t];
  __syncthreads();
  // scores es/ed from staged tile (lane l = dim d)
  float aSl = ((cv ? as2 : as1) + hh * 64)[l];
  float aDl = ((cv ? ad2 : ad1) + hh * 64)[l];
  for(int it = 0; it < 16; it++){
    int j = it * 4 + w;
    float v = hst[j][l];
    float ps = v * aSl, pd = v * aDl;
    for(int o = 32; o; o >>= 1){ ps += __shfl_xor(ps, o); pd += __shfl_xor(pd, o); }
    if(l == 0){ esl[j] = ps; edl[j] = pd; }
  }
  __syncthreads();
  // per-row softmax (wave w handles rows {w, w+4, ...}; lane = neighbor j)
  for(int it = 0; it < 16; it++){
    int i = it * 4 + w;
    bool on = (adjs[i] >> l) & 1;
    float e = edl[i] + esl[l];
    e = e > 0.f ? e : 0.2f * e;
    float mx = on ? e : -1e30f;
    for(int o = 32; o; o >>= 1) mx = fmaxf(mx, __shfl_xor(mx, o));
    float p = on ? __expf(e - mx) : 0.f;
    float s = p;
    for(int o = 32; o; o >>= 1) s += __shfl_xor(s, o);
    alphaL[i][l] = p / s;
  }
  __syncthreads();
  // aggregate: thread -> row i = t>>2, col block q = t&3
  int i = t >> 2, q = t & 3;
  float acc[16];
  #pragma unroll
  for(int k = 0; k < 16; k++) acc[k] = 0.f;
  for(int j = 0; j < 64; j++){
    float al = alphaL[i][j];
    const float* hr = &hst[j][q * 16];
    #pragma unroll
    for(int k = 0; k < 16; k++) acc[k] += al * hr[k];
  }
  const float* bias = (cv ? b2 : b1) + hh * 64 + q * 16;
  u16* op = x2b + (size_t)(b * 64 + i) * 1024 + cv * 512 + hh * 64 + q * 16;
  #pragma unroll
  for(int k = 0; k < 16; k++) op[k] = f2b(fmaxf(acc[k] + bias[k], 0.f));
}

// ---------------- Set2Set step-0 shortcut (input == 0 for all graphs) ----------------
// z1 = Wih1 @ h0(lb0) + lb1  (f32 GEMV, 4096 rows; one wave per row; h0 recomputed in LDS)
__global__ __launch_bounds__(256) void s2s0_gemv(const float* __restrict__ Wih1,
    const float* __restrict__ lb1, const float* __restrict__ lb0, float* __restrict__ z1u){
  __shared__ float hs[1024];
  int t = threadIdx.x;
  for(int i = t; i < 1024; i += 256){
    float zi = lb0[i], zg = lb0[2048 + i], zo = lb0[3072 + i];
    float cn = (1.f / (1.f + __expf(-zi))) * tanhf(zg);
    hs[i] = (1.f / (1.f + __expf(-zo))) * tanhf(cn);
  }
  __syncthreads();
  int w = t >> 6, l = t & 63;
  int r = blockIdx.x * 4 + w;
  const float* wr = Wih1 + (size_t)r * 1024;
  float s = 0.f;
  #pragma unroll
  for(int k = 0; k < 16; k++) s += wr[l + 64 * k] * hs[l + 64 * k];
  for(int o = 32; o; o >>= 1) s += __shfl_xor(s, o);
  if(l == 0) z1u[r] = s + lb1[r];
}

__global__ void s2s0_bcast(const float* __restrict__ lb0, const float* __restrict__ z1u,
    float* __restrict__ c0b, float* __restrict__ c1b, float* __restrict__ h1f,
    u16* __restrict__ ac0, u16* __restrict__ ac1){
  int t = blockIdx.x * 256 + threadIdx.x;  // 128*1024
  int b = t >> 10, j = t & 1023;
  float zi0 = lb0[j], zg0 = lb0[2048 + j], zo0 = lb0[3072 + j];
  float c0 = (1.f / (1.f + __expf(-zi0))) * tanhf(zg0);
  float h0 = (1.f / (1.f + __expf(-zo0))) * tanhf(c0);
  float zi1 = z1u[j], zg1 = z1u[2048 + j], zo1 = z1u[3072 + j];
  float c1 = (1.f / (1.f + __expf(-zi1))) * tanhf(zg1);
  float h1 = (1.f / (1.f + __expf(-zo1))) * tanhf(c1);
  c0b[t] = c0;
  c1b[t] = c1;
  h1f[t] = h1;
  u16 h0b = f2b(h0), h1b = f2b(h1);
  ac0[(size_t)b * 3072 + j] = h1b;
  ac0[(size_t)b * 3072 + 2048 + j] = h0b;
  ac1[(size_t)b * 2048 + j] = h0b;
  ac1[(size_t)b * 2048 + 1024 + j] = h1b;
}

// ---------------- LSTM gates (sum ns split-K partials) ----------------
__global__ void lstm_gate0(const float* __restrict__ zp, const float* __restrict__ lb,
                           float* __restrict__ c, u16* __restrict__ ac0, u16* __restrict__ ac1,
                           int ns){
  int t = blockIdx.x * 256 + threadIdx.x;  // 128*1024
  int b = t >> 10, j = t & 1023;
  size_t base = (size_t)b * 4096;
  float zi = 0, zf = 0, zg = 0, zo = 0;
  for(int s = 0; s < ns; s++){
    const float* zr = zp + (size_t)s * 524288 + base;
    zi += zr[j]; zf += zr[1024 + j]; zg += zr[2048 + j]; zo += zr[3072 + j];
  }
  zi += lb[j]; zf += lb[1024 + j]; zg += lb[2048 + j]; zo += lb[3072 + j];
  float ci = c[t];
  float si = 1.f / (1.f + __expf(-zi)), sf = 1.f / (1.f + __expf(-zf)), so = 1.f / (1.f + __expf(-zo));
  float cn = sf * ci + si * tanhf(zg);
  c[t] = cn;
  u16 hb = f2b(so * tanhf(cn));
  ac0[(size_t)b * 3072 + 2048 + j] = hb;
  ac1[(size_t)b * 2048 + j] = hb;
}

__global__ void lstm_gate1(const float* __restrict__ zp, const float* __restrict__ lb,
                           float* __restrict__ c, float* __restrict__ h1f,
                           u16* __restrict__ ac1, u16* __restrict__ ac0, int ns){
  int t = blockIdx.x * 256 + threadIdx.x;
  int b = t >> 10, j = t & 1023;
  size_t base = (size_t)b * 4096;
  float zi = 0, zf = 0, zg = 0, zo = 0;
  for(int s = 0; s < ns; s++){
    const float* zr = zp + (size_t)s * 524288 + base;
    zi += zr[j]; zf += zr[1024 + j]; zg += zr[2048 + j]; zo += zr[3072 + j];
  }
  zi += lb[j]; zf += lb[1024 + j]; zg += lb[2048 + j]; zo += lb[3072 + j];
  float ci = c[t];
  float si = 1.f / (1.f + __expf(-zi)), sf = 1.f / (1.f + __expf(-zf)), so = 1.f / (1.f + __expf(-zo));
  float cn = sf * ci + si * tanhf(zg);
  c[t] = cn;
  float hn = so * tanhf(cn);
  h1f[t] = hn;
  u16 hb = f2b(hn);
  ac1[(size_t)b * 2048 + 1024 + j] = hb;
  ac0[(size_t)b * 3072 + j] = hb;
}

// ---------------- Set2Set attention (bf16 x2, scalar loads) ----------------
__global__ __launch_bounds__(256) void s2s_e(const u16* __restrict__ x2b,
    const float* __restrict__ h1, float* __restrict__ e){
  int t = threadIdx.x, w = t >> 6, l = t & 63;
  int node = blockIdx.x * 4 + w;
  int b = node >> 6;
  const u16* xr = x2b + (size_t)node * 1024;
  const float* hr = h1 + (size_t)b * 1024;
  float s = 0.f;
  #pragma unroll
  for(int k = 0; k < 16; k++){
    int d = k * 64 + l;
    s += b2f(xr[d]) * hr[d];
  }
  for(int o = 32; o; o >>= 1) s += __shfl_xor(s, o);
  if(l == 0) e[node] = s;
}

__global__ __launch_bounds__(256) void s2s_r(const u16* __restrict__ x2b,
    const float* __restrict__ e, u16* __restrict__ ac0){
  int b = blockIdx.x, sl = blockIdx.y;
  __shared__ float al[64];
  int t = threadIdx.x;
  if(t < 64){
    float v = e[b * 64 + t];
    float mx = v;
    for(int o = 32; o; o >>= 1) mx = fmaxf(mx, __shfl_xor(mx, o));
    float p = __expf(v - mx);
    float ss = p;
    for(int o = 32; o; o >>= 1) ss += __shfl_xor(ss, o);
    al[t] = p / ss;
  }
  __syncthreads();
  int d = sl * 256 + t;
  const u16* xp = x2b + (size_t)b * 65536 + d;
  float r = 0.f;
  #pragma unroll 8
  for(int j = 0; j < 64; j++) r += al[j] * b2f(xp[j * 1024]);
  ac0[(size_t)b * 3072 + 1024 + d] = f2b(r);
}

// ---------------- lin2 combine (8 split partials) + bn + relu + lin3 ----------------
__global__ __launch_bounds__(256) void lin3(const float* __restrict__ zp2,
    const float* __restrict__ sc2, const float* __restrict__ sh2,
    const float* __restrict__ W3, const float* __restrict__ b3, float* __restrict__ out){
  int b = blockIdx.x;
  __shared__ float yl[1024];
  int t = threadIdx.x, w = t >> 6, l = t & 63;
  for(int d = t; d < 1024; d += 256){
    float v = 0.f;
    for(int s = 0; s < 8; s++) v += zp2[(size_t)s * 131072 + b * 1024 + d];
    yl[d] = fmaxf(v, 0.f) * sc2[d] + sh2[d];
  }
  __syncthreads();
  for(int n = w; n < 10; n += 4){
    float s = 0.f;
    for(int d = l; d < 1024; d += 64) s += yl[d] * W3[d * 10 + n];
    for(int o = 32; o; o >>= 1) s += __shfl_xor(s, o);
    if(l == 0) out[b * 10 + n] = s + b3[n];
  }
}

extern "C" void kernel_launch(void* const* d_in, const int* in_sizes, int n_in,
                              void* d_out, int out_size, void* d_ws, size_t ws_size,
                              hipStream_t stream){
  const float* x    = (const float*)d_in[0];
  const float* pos  = (const float*)d_in[1];
  const float* W0   = (const float*)d_in[3];
  const float* bn0g = (const float*)d_in[4];
  const float* bn0b = (const float*)d_in[5];
  const float* bn0m = (const float*)d_in[6];
  const float* bn0v = (const float*)d_in[7];
  const float* Wg1  = (const float*)d_in[8];
  const float* as1  = (const float*)d_in[9];
  const float* ad1  = (const float*)d_in[10];
  const float* b1   = (const float*)d_in[11];
  const float* Wg2  = (const float*)d_in[12];
  const float* as2  = (const float*)d_in[13];
  const float* ad2  = (const float*)d_in[14];
  const float* b2   = (const float*)d_in[15];
  const float* Wih0 = (const float*)d_in[16];
  const float* Whh0 = (const float*)d_in[17];
  const float* bih0 = (const float*)d_in[18];
  const float* bhh0 = (const float*)d_in[19];
  const float* Wih1 = (const float*)d_in[20];
  const float* Whh1 = (const float*)d_in[21];
  const float* bih1 = (const float*)d_in[22];
  const float* bhh1 = (const float*)d_in[23];
  const float* W2   = (const float*)d_in[24];
  const float* bn2g = (const float*)d_in[25];
  const float* bn2b = (const float*)d_in[26];
  const float* bn2m = (const float*)d_in[27];
  const float* bn2v = (const float*)d_in[28];
  const float* W3   = (const float*)d_in[29];
  const float* b3   = (const float*)d_in[30];

  char* ws = (char*)d_ws;
  u16*   xbf  = (u16*)(ws + O_XBF);
  u16*   x2b  = (u16*)(ws + O_XBF);   // alias: x bf16 dead after GEMM1
  u16*   w0t  = (u16*)(ws + O_W0T);
  u16*   wgt  = (u16*)(ws + O_WGT);
  u16*   w2t  = (u16*)(ws + O_W2T);
  u16*   xb   = (u16*)(ws + O_XB);
  u16*   hb   = (u16*)(ws + O_H);      // h bf16 (first 16MB of O_H region)
  u64*   adjm = (u64*)(ws + O_ADJ);
  float* sc0  = (float*)(ws + O_SC0);
  float* sh0  = (float*)(ws + O_SH0);
  float* sc2  = (float*)(ws + O_SC2);
  float* sh2  = (float*)(ws + O_SH2);
  float* lb0  = (float*)(ws + O_LB0);
  float* lb1  = (float*)(ws + O_LB1);
  char*  s2sb = ws + O_H;               // s2s scratch overlays h after GAT
  u16*   ac0  = (u16*)(s2sb + S_AC0);
  u16*   ac1  = (u16*)(s2sb + S_AC1);
  float* c0b  = (float*)(s2sb + S_C0);
  float* c1b  = (float*)(s2sb + S_C1);
  float* h1f  = (float*)(s2sb + S_H1F);
  float* zp   = (float*)(s2sb + S_ZP);
  float* ebuf = (float*)(s2sb + S_E);
  float* z1u  = (float*)(s2sb + S_Z1U);

  // --- prep+adjacency + conversions (x + transposed weights only; LSTM weights stay f32) ---
  prep_adj<<<48, 256, 0, stream>>>(bn0g, bn0b, bn0m, bn0v, bn2g, bn2b, bn2m, bn2v,
                                   bih0, bhh0, bih1, bhh1, sc0, sh0, sc2, sh2, lb0, lb1,
                                   pos, adjm);
  cvt_x<<<16384, 256, 0, stream>>>(x, xbf);
  cvt_tr<<<dim3(128, 64), dim3(32, 8), 0, stream>>>(W0, Wg1, Wg2, W2, w0t, wgt, w2t);

  // --- GEMM1: xb = bf16(bn0(relu(x @ W0))) ; GAT h = xb @ [Wg1|Wg2] (bf16 out) ---
  gemm_bf16<1><<<dim3(64, 16), 256, 0, stream>>>(xbf, w0t, nullptr, xb, sc0, sh0, 8192, 2048, 2048);
  gemm_bf16<3><<<dim3(64, 8), 256, 0, stream>>>(xb, wgt, nullptr, hb, nullptr, nullptr, 8192, 1024, 2048);
  // --- GAT attention (scores fused) ---
  gat_attn2<<<dim3(128, 16), 256, 0, stream>>>(adjm, hb, as1, ad1, as2, ad2, b1, b2, x2b);

  // --- Set2Set step 0: LSTM input is 0 -> state is graph-uniform (bias-derived) ---
  s2s0_gemv<<<1024, 256, 0, stream>>>(Wih1, lb1, lb0, z1u);
  s2s0_bcast<<<512, 256, 0, stream>>>(lb0, z1u, c0b, c1b, h1f, ac0, ac1);
  s2s_e<<<2048, 256, 0, stream>>>(x2b, h1f, ebuf);
  s2s_r<<<dim3(128, 4), 256, 0, stream>>>(x2b, ebuf, ac0);

  // --- Set2Set step 1 (full; LSTM weights read directly as f32) ---
  gemm_skf<<<dim3(64, 8), 256, 0, stream>>>(ac0, Wih0, Whh0, zp, 4096, 3072, 2048, 1024, 384);
  lstm_gate0<<<512, 256, 0, stream>>>(zp, lb0, c0b, ac0, ac1, 8);
  gemm_skf<<<dim3(64, 8), 256, 0, stream>>>(ac1, Wih1, Whh1, zp, 4096, 2048, 1024, 1024, 256);
  lstm_gate1<<<512, 256, 0, stream>>>(zp, lb1, c1b, h1f, ac1, ac0, 8);
  s2s_e<<<2048, 256, 0, stream>>>(x2b, h1f, ebuf);
  s2s_r<<<dim3(128, 4), 256, 0, stream>>>(x2b, ebuf, ac0);

  // --- lin2 (split-K 8) + lin3 ---
  gemm_sk<<<dim3(16, 8), 256, 0, stream>>>(ac0, w2t, zp, 1024, 3072, 2048, 256);
  lin3<<<128, 256, 0, stream>>>(zp, sc2, sh2, W3, b3, (float*)d_out);
}

// Round 11
// 303.237 us; speedup vs baseline: 5.2554x; 1.0170x over previous
//
#include <hip/hip_runtime.h>
#include <hip/hip_bf16.h>

typedef unsigned short u16;
typedef __attribute__((ext_vector_type(8))) short short8;
typedef __attribute__((ext_vector_type(4))) float f32x4;
typedef unsigned long long u64;

#define DI __device__ __forceinline__

DI u16 f2b(float f){
  unsigned u = __float_as_uint(f);
  unsigned r = 0x7fffu + ((u >> 16) & 1u);
  return (u16)((u + r) >> 16);
}
DI float b2f(u16 u){ return __uint_as_float((unsigned)u << 16); }

DI void gl_lds16(const void* g, void* l){
  __builtin_amdgcn_global_load_lds((const __attribute__((address_space(1))) void*)g,
                                   (__attribute__((address_space(3))) void*)l, 16, 0, 0);
}

// ---------------- workspace layout (bytes) ----------------
constexpr size_t O_XBF = 0;                    // 33554432: x bf16 [8192,2048]; later x2 bf16 [8192,1024] (16MB)
constexpr size_t O_W0T = O_XBF + 33554432;     // 8388608:  W0^T bf16 [2048,2048]
constexpr size_t O_WGT = O_W0T + 8388608;      // 4194304:  [Wg1|Wg2]^T bf16 [1024,2048]
constexpr size_t O_W2T = O_WGT + 4194304;      // 4194304:  W2^T bf16 [1024,2048]
constexpr size_t O_XB  = O_W2T + 4194304;      // 33554432: xb bf16 [8192,2048]
constexpr size_t O_H   = O_XB  + 33554432;     // region: h bf16 [8192,1024] (16MB); Set2Set scratch after GAT
constexpr size_t O_ES  = O_H   + 33554432;     // 524288 (unused)
constexpr size_t O_ED  = O_ES  + 524288;       // 524288 (unused)
constexpr size_t O_ADJ = O_ED  + 524288;       // 65536
constexpr size_t O_SC0 = O_ADJ + 65536;
constexpr size_t O_SH0 = O_SC0 + 8192;
constexpr size_t O_SC2 = O_SH0 + 8192;
constexpr size_t O_SH2 = O_SC2 + 4096;
constexpr size_t O_LB0 = O_SH2 + 4096;
constexpr size_t O_LB1 = O_LB0 + 16384;
// Set2Set scratch inside O_H (h is dead after gat_attn2):
constexpr size_t S_AC0 = 0;                    // 786432: acat0 bf16 [128][3072] = [q_star(2048) | h0(1024)]
constexpr size_t S_AC1 = S_AC0 + 786432;       // 524288: acat1 bf16 [128][2048] = [h0 | h1]
constexpr size_t S_C0  = S_AC1 + 524288;       // 524288
constexpr size_t S_C1  = S_C0  + 524288;       // 524288
constexpr size_t S_H1F = S_C1  + 524288;       // 524288: h1 f32 (step 1 only)
constexpr size_t S_ZP  = S_H1F + 524288;       // 16777216: split-K partials (8 x [128*4096] f32)
constexpr size_t S_E   = S_ZP  + 16777216;     // 32768: s2s scores e[8192]
constexpr size_t S_Z1U = S_E   + 32768;        // 16384: step-0 uniform z1 f32[4096]

// ---------------- one setup kernel: x cvt + 4 transposes + prep + adjacency ----------------
__global__ __launch_bounds__(256) void setup_all(
    const float* __restrict__ x,
    const float* __restrict__ W0, const float* __restrict__ Wg1,
    const float* __restrict__ Wg2, const float* __restrict__ W2,
    const float* __restrict__ g0, const float* __restrict__ b0, const float* __restrict__ m0, const float* __restrict__ v0,
    const float* __restrict__ g2, const float* __restrict__ b2, const float* __restrict__ m2, const float* __restrict__ v2,
    const float* __restrict__ bih0, const float* __restrict__ bhh0,
    const float* __restrict__ bih1, const float* __restrict__ bhh1,
    const float* __restrict__ pos,
    u16* __restrict__ xbf, u16* __restrict__ w0t, u16* __restrict__ wgt, u16* __restrict__ w2t,
    float* __restrict__ sc0, float* __restrict__ sh0, float* __restrict__ sc2, float* __restrict__ sh2,
    float* __restrict__ lb0, float* __restrict__ lb1, u64* __restrict__ adjm)
{
  __shared__ float tile[32][33];
  __shared__ float px[4][64], py[4][64];
  int bx = blockIdx.x, t = threadIdx.x;
  if(bx < 8192){
    // x f32 -> bf16, 8 elems/thread
    int idx = bx * 256 + t;                  // [0, 2M)
    int r = idx >> 8, c8 = (idx & 255) << 3;
    const float* src = x + (size_t)r * 2048 + c8;
    float4 v0 = *(const float4*)src;
    float4 v1 = *(const float4*)(src + 4);
    short8 ov;
    ov[0] = (short)f2b(v0.x); ov[1] = (short)f2b(v0.y); ov[2] = (short)f2b(v0.z); ov[3] = (short)f2b(v0.w);
    ov[4] = (short)f2b(v1.x); ov[5] = (short)f2b(v1.y); ov[6] = (short)f2b(v1.z); ov[7] = (short)f2b(v1.w);
    *(short8*)(xbf + (size_t)r * 2048 + c8) = ov;
  } else if(bx < 16384){
    // transposes: W0 (64 col-tiles), Wg1 (16), Wg2 (16), W2 (32); 64 row-tiles each
    int bx2 = bx - 8192;
    int cx = bx2 & 127, by = bx2 >> 7;
    const float* src; u16* dst; int C, droff;
    if(cx < 64){      src = W0;  dst = w0t; C = 2048; droff = 0; }
    else if(cx < 80){ src = Wg1; dst = wgt; C = 512;  droff = 0;   cx -= 64; }
    else if(cx < 96){ src = Wg2; dst = wgt; C = 512;  droff = 512; cx -= 80; }
    else {            src = W2;  dst = w2t; C = 1024; droff = 0;   cx -= 96; }
    int c0 = cx * 32, r0 = by * 32;
    int tx = t & 31, ty = t >> 5;  // (32,8)
    for(int i = 0; i < 4; i++)
      tile[ty + 8*i][tx] = src[(size_t)(r0 + ty + 8*i) * C + c0 + tx];
    __syncthreads();
    for(int i = 0; i < 4; i++)
      dst[(size_t)(droff + c0 + ty + 8*i) * 2048 + r0 + tx] = f2b(tile[tx][ty + 8*i]);
  } else if(bx < 16400){
    int tt = (bx - 16384) * 256 + t;
    if(tt < 2048){ float s = g0[tt] * rsqrtf(v0[tt] + 0.1f); sc0[tt] = s; sh0[tt] = b0[tt] - m0[tt] * s; }
    if(tt < 1024){ float s = g2[tt] * rsqrtf(v2[tt] + 0.1f); sc2[tt] = s; sh2[tt] = b2[tt] - m2[tt] * s; }
    lb0[tt] = bih0[tt] + bhh0[tt];
    lb1[tt] = bih1[tt] + bhh1[tt];
  } else {
    // adjacency: 32 blocks x 4 graphs
    int w = t >> 6, l = t & 63;
    int g = (bx - 16400) * 4 + w;
    float2 p = ((const float2*)pos)[g * 64 + l];
    px[w][l] = p.x; py[w][l] = p.y;
    __syncthreads();
    float xi = p.x, yi = p.y;
    u64 m = 0;
    for(int j = 0; j < 64; j++){
      float dx = xi - px[w][j], dy = yi - py[w][j];
      if(dx * dx + dy * dy <= 16.0f) m |= (1ull << j);
    }
    adjm[g * 64 + l] = m;
  }
}

// ---------------- bf16 MFMA GEMM (m97 structure) ----------------
// MODE 1: relu+bn -> bf16 Cb.  MODE 3: plain bf16 Cb.
template<int MODE>
__global__ __launch_bounds__(256) void gemm_bf16(
    const u16* __restrict__ A, const u16* __restrict__ Bt,
    float* __restrict__ Cf, u16* __restrict__ Cb,
    const float* __restrict__ p1, const float* __restrict__ p2,
    int M, int N, int K)
{
  constexpr int BM = 128, BN = 128, BK = 64;
  __shared__ alignas(16) u16 Al[BM * BK];
  __shared__ alignas(16) u16 Bl[BN * BK];
  int m0 = blockIdx.x * BM, n0 = blockIdx.y * BN;
  int t = threadIdx.x, w = t >> 6, l = t & 63;
  int wm = (w >> 1) * 64, wn = (w & 1) * 64;
  f32x4 acc[4][4];
  for(int a = 0; a < 4; a++) for(int b = 0; b < 4; b++) acc[a][b] = {0.f, 0.f, 0.f, 0.f};

  const short8* Ap = (const short8*)Al;
  const short8* Bp = (const short8*)Bl;

  for(int k0 = 0; k0 < K; k0 += BK){
    #pragma unroll
    for(int u = t; u < BM * 8; u += 256){
      int r = u >> 3, c = u & 7;
      gl_lds16(A + (size_t)(m0 + r) * K + k0 + ((c ^ (r & 7)) << 3), Al + u * 8);
    }
    #pragma unroll
    for(int u = t; u < BN * 8; u += 256){
      int r = u >> 3, c = u & 7;
      gl_lds16(Bt + (size_t)(n0 + r) * K + k0 + ((c ^ (r & 7)) << 3), Bl + u * 8);
    }
    __syncthreads();
    #pragma unroll
    for(int ks = 0; ks < 2; ks++){
      int kc = ks * 4 + (l >> 4);
      short8 av[4], bv[4];
      #pragma unroll
      for(int mi = 0; mi < 4; mi++){ int r = wm + mi * 16 + (l & 15); av[mi] = Ap[r * 8 + (kc ^ (r & 7))]; }
      #pragma unroll
      for(int ni = 0; ni < 4; ni++){ int r = wn + ni * 16 + (l & 15); bv[ni] = Bp[r * 8 + (kc ^ (r & 7))]; }
      #pragma unroll
      for(int mi = 0; mi < 4; mi++)
        #pragma unroll
        for(int ni = 0; ni < 4; ni++)
          acc[mi][ni] = __builtin_amdgcn_mfma_f32_16x16x32_bf16(av[mi], bv[ni], acc[mi][ni], 0, 0, 0);
    }
    __syncthreads();
  }

  int cr = m0 + wm + ((l >> 4) << 2);
  int cc = n0 + wn + (l & 15);
  for(int mi = 0; mi < 4; mi++)
    for(int ni = 0; ni < 4; ni++)
      for(int r = 0; r < 4; r++){
        int row = cr + mi * 16 + r, col = cc + ni * 16;
        float v = acc[mi][ni][r];
        if(MODE == 1){ v = fmaxf(v, 0.f) * p1[col] + p2[col]; Cb[(size_t)row * N + col] = f2b(v); }
        else if(MODE == 3){ Cb[(size_t)row * N + col] = f2b(v); }
        else { Cf[(size_t)row * N + col] = v; }
      }
}

// ---------------- split-K skinny GEMM (bf16 B), used for lin2 ----------------
__global__ __launch_bounds__(256) void gemm_sk(
    const u16* __restrict__ A, const u16* __restrict__ Bt, float* __restrict__ Cf,
    int N, int lda, int ldb, int kPer)
{
  constexpr int BM = 128, BN = 64, BK = 64;
  __shared__ alignas(16) u16 Al[BM * BK];
  __shared__ alignas(16) u16 Bl[BN * BK];
  int n0 = blockIdx.x * BN;
  int kb = blockIdx.y * kPer;
  float* C = Cf + (size_t)blockIdx.y * 128 * N;
  int t = threadIdx.x, w = t >> 6, l = t & 63;
  int wm = (w >> 1) * 64, wn = (w & 1) * 32;
  f32x4 acc[4][2];
  for(int a = 0; a < 4; a++) for(int b = 0; b < 2; b++) acc[a][b] = {0.f, 0.f, 0.f, 0.f};

  const short8* Ap = (const short8*)Al;
  const short8* Bp = (const short8*)Bl;

  for(int k0 = kb; k0 < kb + kPer; k0 += BK){
    #pragma unroll
    for(int u = t; u < BM * 8; u += 256){
      int r = u >> 3, c = u & 7;
      gl_lds16(A + (size_t)r * lda + k0 + ((c ^ (r & 7)) << 3), Al + u * 8);
    }
    #pragma unroll
    for(int u = t; u < BN * 8; u += 256){
      int r = u >> 3, c = u & 7;
      gl_lds16(Bt + (size_t)(n0 + r) * ldb + k0 + ((c ^ (r & 7)) << 3), Bl + u * 8);
    }
    __syncthreads();
    #pragma unroll
    for(int ks = 0; ks < 2; ks++){
      int kc = ks * 4 + (l >> 4);
      short8 av[4], bv[2];
      #pragma unroll
      for(int mi = 0; mi < 4; mi++){ int r = wm + mi * 16 + (l & 15); av[mi] = Ap[r * 8 + (kc ^ (r & 7))]; }
      #pragma unroll
      for(int ni = 0; ni < 2; ni++){ int r = wn + ni * 16 + (l & 15); bv[ni] = Bp[r * 8 + (kc ^ (r & 7))]; }
      #pragma unroll
      for(int mi = 0; mi < 4; mi++)
        #pragma unroll
        for(int ni = 0; ni < 2; ni++)
          acc[mi][ni] = __builtin_amdgcn_mfma_f32_16x16x32_bf16(av[mi], bv[ni], acc[mi][ni], 0, 0, 0);
    }
    __syncthreads();
  }

  int cr = wm + ((l >> 4) << 2);
  int cc = n0 + wn + (l & 15);
  for(int mi = 0; mi < 4; mi++)
    for(int ni = 0; ni < 2; ni++)
      for(int r = 0; r < 4; r++)
        C[(size_t)(cr + mi * 16 + r) * N + cc + ni * 16] = acc[mi][ni][r];
}

// ---------------- split-K skinny GEMM with f32 B (in-kernel bf16 conversion) ----------------
__global__ __launch_bounds__(256) void gemm_skf(
    const u16* __restrict__ A, const float* __restrict__ Wih, const float* __restrict__ Whh,
    float* __restrict__ Cf, int N, int lda, int Kih, int Khh, int kPer)
{
  constexpr int BM = 128, BN = 64, BK = 64;
  __shared__ alignas(16) u16 Al[BM * BK];
  __shared__ alignas(16) u16 Bl[BN * BK];
  int n0 = blockIdx.x * BN;
  int kb = blockIdx.y * kPer;
  float* C = Cf + (size_t)blockIdx.y * 128 * N;
  int t = threadIdx.x, w = t >> 6, l = t & 63;
  int wm = (w >> 1) * 64, wn = (w & 1) * 32;
  f32x4 acc[4][2];
  for(int a = 0; a < 4; a++) for(int b = 0; b < 2; b++) acc[a][b] = {0.f, 0.f, 0.f, 0.f};

  const short8* Ap = (const short8*)Al;
  const short8* Bp = (const short8*)Bl;

  for(int k0 = kb; k0 < kb + kPer; k0 += BK){
    #pragma unroll
    for(int u = t; u < BM * 8; u += 256){
      int r = u >> 3, c = u & 7;
      gl_lds16(A + (size_t)r * lda + k0 + ((c ^ (r & 7)) << 3), Al + u * 8);
    }
    #pragma unroll
    for(int u = t; u < BN * 8; u += 256){
      int r = u >> 3, c = u & 7;
      int gk = k0 + c * 8;
      const float* src = (gk < Kih) ? (Wih + (size_t)(n0 + r) * Kih + gk)
                                    : (Whh + (size_t)(n0 + r) * Khh + (gk - Kih));
      float4 v0 = *(const float4*)src;
      float4 v1 = *(const float4*)(src + 4);
      short8 ov;
      ov[0] = (short)f2b(v0.x); ov[1] = (short)f2b(v0.y); ov[2] = (short)f2b(v0.z); ov[3] = (short)f2b(v0.w);
      ov[4] = (short)f2b(v1.x); ov[5] = (short)f2b(v1.y); ov[6] = (short)f2b(v1.z); ov[7] = (short)f2b(v1.w);
      ((short8*)Bl)[r * 8 + (c ^ (r & 7))] = ov;
    }
    __syncthreads();
    #pragma unroll
    for(int ks = 0; ks < 2; ks++){
      int kc = ks * 4 + (l >> 4);
      short8 av[4], bv[2];
      #pragma unroll
      for(int mi = 0; mi < 4; mi++){ int r = wm + mi * 16 + (l & 15); av[mi] = Ap[r * 8 + (kc ^ (r & 7))]; }
      #pragma unroll
      for(int ni = 0; ni < 2; ni++){ int r = wn + ni * 16 + (l & 15); bv[ni] = Bp[r * 8 + (kc ^ (r & 7))]; }
      #pragma unroll
      for(int mi = 0; mi < 4; mi++)
        #pragma unroll
        for(int ni = 0; ni < 2; ni++)
          acc[mi][ni] = __builtin_amdgcn_mfma_f32_16x16x32_bf16(av[mi], bv[ni], acc[mi][ni], 0, 0, 0);
    }
    __syncthreads();
  }

  int cr = wm + ((l >> 4) << 2);
  int cc = n0 + wn + (l & 15);
  for(int mi = 0; mi < 4; mi++)
    for(int ni = 0; ni < 2; ni++)
      for(int r = 0; r < 4; r++)
        C[(size_t)(cr + mi * 16 + r) * N + cc + ni * 16] = acc[mi][ni][r];
}

// ---------------- GAT: scores (fused) + softmax + aggregate, per (graph, conv, head) ----------------
__global__ __launch_bounds__(256) void gat_attn2(const u64* __restrict__ adjm,
    const u16* __restrict__ h,
    const float* __restrict__ as1, const float* __restrict__ ad1,
    const float* __restrict__ as2, const float* __restrict__ ad2,
    const float* __restrict__ b1, const float* __restrict__ b2,
    u16* __restrict__ x2b){
  int b = blockIdx.x;
  int cv = blockIdx.y >> 3, hh = blockIdx.y & 7;
  __shared__ float hst[64][64];
  __shared__ float alphaL[64][65];
  __shared__ float esl[64], edl[64];
  __shared__ u64 adjs[64];
  int t = threadIdx.x, w = t >> 6, l = t & 63;
  {
    int j = t >> 2, d0 = (t & 3) * 16;
    const u16* hr = h + (size_t)(b * 64 + j) * 1024 + cv * 512 + hh * 64 + d0;
    #pragma unroll
    for(int k = 0; k < 16; k++) hst[j][d0 + k] = b2f(hr[k]);
  }
  if(t < 64) adjs[t] = adjm[b * 64 + t];
  __syncthreads();
  float aSl = ((cv ? as2 : as1) + hh * 64)[l];
  float aDl = ((cv ? ad2 : ad1) + hh * 64)[l];
  for(int it = 0; it < 16; it++){
    int j = it * 4 + w;
    float v = hst[j][l];
    float ps = v * aSl, pd = v * aDl;
    for(int o = 32; o; o >>= 1){ ps += __shfl_xor(ps, o); pd += __shfl_xor(pd, o); }
    if(l == 0){ esl[j] = ps; edl[j] = pd; }
  }
  __syncthreads();
  for(int it = 0; it < 16; it++){
    int i = it * 4 + w;
    bool on = (adjs[i] >> l) & 1;
    float e = edl[i] + esl[l];
    e = e > 0.f ? e : 0.2f * e;
    float mx = on ? e : -1e30f;
    for(int o = 32; o; o >>= 1) mx = fmaxf(mx, __shfl_xor(mx, o));
    float p = on ? __expf(e - mx) : 0.f;
    float s = p;
    for(int o = 32; o; o >>= 1) s += __shfl_xor(s, o);
    alphaL[i][l] = p / s;
  }
  __syncthreads();
  int i = t >> 2, q = t & 3;
  float acc[16];
  #pragma unroll
  for(int k = 0; k < 16; k++) acc[k] = 0.f;
  for(int j = 0; j < 64; j++){
    float al = alphaL[i][j];
    const float* hr = &hst[j][q * 16];
    #pragma unroll
    for(int k = 0; k < 16; k++) acc[k] += al * hr[k];
  }
  const float* bias = (cv ? b2 : b1) + hh * 64 + q * 16;
  u16* op = x2b + (size_t)(b * 64 + i) * 1024 + cv * 512 + hh * 64 + q * 16;
  #pragma unroll
  for(int k = 0; k < 16; k++) op[k] = f2b(fmaxf(acc[k] + bias[k], 0.f));
}

// ---------------- Set2Set step-0 shortcut ----------------
// z1 = Wih1 @ h0(lb0) + lb1  (f32 GEMV, 4096 rows; one wave per row; h0 recomputed in LDS)
__global__ __launch_bounds__(256) void s2s0_gemv(const float* __restrict__ Wih1,
    const float* __restrict__ lb1, const float* __restrict__ lb0, float* __restrict__ z1u){
  __shared__ float hs[1024];
  int t = threadIdx.x;
  for(int i = t; i < 1024; i += 256){
    float zi = lb0[i], zg = lb0[2048 + i], zo = lb0[3072 + i];
    float cn = (1.f / (1.f + __expf(-zi))) * tanhf(zg);
    hs[i] = (1.f / (1.f + __expf(-zo))) * tanhf(cn);
  }
  __syncthreads();
  int w = t >> 6, l = t & 63;
  int r = blockIdx.x * 4 + w;
  const float* wr = Wih1 + (size_t)r * 1024;
  float s = 0.f;
  #pragma unroll
  for(int k = 0; k < 16; k++) s += wr[l + 64 * k] * hs[l + 64 * k];
  for(int o = 32; o; o >>= 1) s += __shfl_xor(s, o);
  if(l == 0) z1u[r] = s + lb1[r];
}

// ---------------- LSTM gates (sum ns split-K partials) ----------------
__global__ void lstm_gate0(const float* __restrict__ zp, const float* __restrict__ lb,
                           float* __restrict__ c, u16* __restrict__ ac0, u16* __restrict__ ac1,
                           int ns){
  int t = blockIdx.x * 256 + threadIdx.x;  // 128*1024
  int b = t >> 10, j = t & 1023;
  size_t base = (size_t)b * 4096;
  float zi = 0, zf = 0, zg = 0, zo = 0;
  for(int s = 0; s < ns; s++){
    const float* zr = zp + (size_t)s * 524288 + base;
    zi += zr[j]; zf += zr[1024 + j]; zg += zr[2048 + j]; zo += zr[3072 + j];
  }
  zi += lb[j]; zf += lb[1024 + j]; zg += lb[2048 + j]; zo += lb[3072 + j];
  float ci = c[t];
  float si = 1.f / (1.f + __expf(-zi)), sf = 1.f / (1.f + __expf(-zf)), so = 1.f / (1.f + __expf(-zo));
  float cn = sf * ci + si * tanhf(zg);
  c[t] = cn;
  u16 hb = f2b(so * tanhf(cn));
  ac0[(size_t)b * 3072 + 2048 + j] = hb;
  ac1[(size_t)b * 2048 + j] = hb;
}

__global__ void lstm_gate1(const float* __restrict__ zp, const float* __restrict__ lb,
                           float* __restrict__ c, float* __restrict__ h1f,
                           u16* __restrict__ ac1, u16* __restrict__ ac0, int ns){
  int t = blockIdx.x * 256 + threadIdx.x;
  int b = t >> 10, j = t & 1023;
  size_t base = (size_t)b * 4096;
  float zi = 0, zf = 0, zg = 0, zo = 0;
  for(int s = 0; s < ns; s++){
    const float* zr = zp + (size_t)s * 524288 + base;
    zi += zr[j]; zf += zr[1024 + j]; zg += zr[2048 + j]; zo += zr[3072 + j];
  }
  zi += lb[j]; zf += lb[1024 + j]; zg += lb[2048 + j]; zo += lb[3072 + j];
  float ci = c[t];
  float si = 1.f / (1.f + __expf(-zi)), sf = 1.f / (1.f + __expf(-zf)), so = 1.f / (1.f + __expf(-zo));
  float cn = sf * ci + si * tanhf(zg);
  c[t] = cn;
  float hn = so * tanhf(cn);
  h1f[t] = hn;
  u16 hb = f2b(hn);
  ac1[(size_t)b * 2048 + 1024 + j] = hb;
  ac0[(size_t)b * 3072 + j] = hb;
}

// ---------------- Set2Set attention (bf16 x2) ----------------
// STEP 0: h1 rebuilt in-LDS from z1u (graph-uniform).  STEP 1: h1 from h1f.
template<int STEP>
__global__ __launch_bounds__(256) void s2s_e(const u16* __restrict__ x2b,
    const float* __restrict__ h1, const float* __restrict__ z1u, float* __restrict__ e){
  __shared__ float h1s[1024];
  int t = threadIdx.x, w = t >> 6, l = t & 63;
  int node = blockIdx.x * 4 + w;
  int b = node >> 6;
  for(int i = t; i < 1024; i += 256){
    if(STEP == 0){
      float zi = z1u[i], zg = z1u[2048 + i], zo = z1u[3072 + i];
      float cn = (1.f / (1.f + __expf(-zi))) * tanhf(zg);
      h1s[i] = (1.f / (1.f + __expf(-zo))) * tanhf(cn);
    } else {
      h1s[i] = h1[(size_t)b * 1024 + i];
    }
  }
  __syncthreads();
  const u16* xr = x2b + (size_t)node * 1024;
  float s = 0.f;
  #pragma unroll
  for(int k = 0; k < 16; k++){
    int d = k * 64 + l;
    s += b2f(xr[d]) * h1s[d];
  }
  for(int o = 32; o; o >>= 1) s += __shfl_xor(s, o);
  if(l == 0) e[node] = s;
}

// STEP 0 additionally writes the graph-uniform step-0 state (bcast fold).
template<int STEP>
__global__ __launch_bounds__(256) void s2s_r(const u16* __restrict__ x2b,
    const float* __restrict__ e, u16* __restrict__ ac0,
    const float* __restrict__ lb0, const float* __restrict__ z1u,
    u16* __restrict__ ac1, float* __restrict__ c0b, float* __restrict__ c1b){
  int b = blockIdx.x, sl = blockIdx.y;
  __shared__ float al[64];
  int t = threadIdx.x;
  if(t < 64){
    float v = e[b * 64 + t];
    float mx = v;
    for(int o = 32; o; o >>= 1) mx = fmaxf(mx, __shfl_xor(mx, o));
    float p = __expf(v - mx);
    float ss = p;
    for(int o = 32; o; o >>= 1) ss += __shfl_xor(ss, o);
    al[t] = p / ss;
  }
  __syncthreads();
  int d = sl * 256 + t;
  const u16* xp = x2b + (size_t)b * 65536 + d;
  float r = 0.f;
  #pragma unroll 8
  for(int j = 0; j < 64; j++) r += al[j] * b2f(xp[j * 1024]);
  ac0[(size_t)b * 3072 + 1024 + d] = f2b(r);
  if(STEP == 0){
    float zi0 = lb0[d], zg0 = lb0[2048 + d], zo0 = lb0[3072 + d];
    float c0 = (1.f / (1.f + __expf(-zi0))) * tanhf(zg0);
    float h0 = (1.f / (1.f + __expf(-zo0))) * tanhf(c0);
    float zi1 = z1u[d], zg1 = z1u[2048 + d], zo1 = z1u[3072 + d];
    float c1 = (1.f / (1.f + __expf(-zi1))) * tanhf(zg1);
    float h1 = (1.f / (1.f + __expf(-zo1))) * tanhf(c1);
    c0b[(size_t)b * 1024 + d] = c0;
    c1b[(size_t)b * 1024 + d] = c1;
    u16 h0b = f2b(h0), h1b = f2b(h1);
    ac0[(size_t)b * 3072 + d] = h1b;
    ac0[(size_t)b * 3072 + 2048 + d] = h0b;
    ac1[(size_t)b * 2048 + d] = h0b;
    ac1[(size_t)b * 2048 + 1024 + d] = h1b;
  }
}

// ---------------- lin2 combine (8 split partials) + bn + relu + lin3 ----------------
__global__ __launch_bounds__(256) void lin3(const float* __restrict__ zp2,
    const float* __restrict__ sc2, const float* __restrict__ sh2,
    const float* __restrict__ W3, const float* __restrict__ b3, float* __restrict__ out){
  int b = blockIdx.x;
  __shared__ float yl[1024];
  int t = threadIdx.x, w = t >> 6, l = t & 63;
  for(int d = t; d < 1024; d += 256){
    float v = 0.f;
    for(int s = 0; s < 8; s++) v += zp2[(size_t)s * 131072 + b * 1024 + d];
    yl[d] = fmaxf(v, 0.f) * sc2[d] + sh2[d];
  }
  __syncthreads();
  for(int n = w; n < 10; n += 4){
    float s = 0.f;
    for(int d = l; d < 1024; d += 64) s += yl[d] * W3[d * 10 + n];
    for(int o = 32; o; o >>= 1) s += __shfl_xor(s, o);
    if(l == 0) out[b * 10 + n] = s + b3[n];
  }
}

extern "C" void kernel_launch(void* const* d_in, const int* in_sizes, int n_in,
                              void* d_out, int out_size, void* d_ws, size_t ws_size,
                              hipStream_t stream){
  const float* x    = (const float*)d_in[0];
  const float* pos  = (const float*)d_in[1];
  const float* W0   = (const float*)d_in[3];
  const float* bn0g = (const float*)d_in[4];
  const float* bn0b = (const float*)d_in[5];
  const float* bn0m = (const float*)d_in[6];
  const float* bn0v = (const float*)d_in[7];
  const float* Wg1  = (const float*)d_in[8];
  const float* as1  = (const float*)d_in[9];
  const float* ad1  = (const float*)d_in[10];
  const float* b1   = (const float*)d_in[11];
  const float* Wg2  = (const float*)d_in[12];
  const float* as2  = (const float*)d_in[13];
  const float* ad2  = (const float*)d_in[14];
  const float* b2   = (const float*)d_in[15];
  const float* Wih0 = (const float*)d_in[16];
  const float* Whh0 = (const float*)d_in[17];
  const float* bih0 = (const float*)d_in[18];
  const float* bhh0 = (const float*)d_in[19];
  const float* Wih1 = (const float*)d_in[20];
  const float* Whh1 = (const float*)d_in[21];
  const float* bih1 = (const float*)d_in[22];
  const float* bhh1 = (const float*)d_in[23];
  const float* W2   = (const float*)d_in[24];
  const float* bn2g = (const float*)d_in[25];
  const float* bn2b = (const float*)d_in[26];
  const float* bn2m = (const float*)d_in[27];
  const float* bn2v = (const float*)d_in[28];
  const float* W3   = (const float*)d_in[29];
  const float* b3   = (const float*)d_in[30];

  char* ws = (char*)d_ws;
  u16*   xbf  = (u16*)(ws + O_XBF);
  u16*   x2b  = (u16*)(ws + O_XBF);   // alias: x bf16 dead after GEMM1
  u16*   w0t  = (u16*)(ws + O_W0T);
  u16*   wgt  = (u16*)(ws + O_WGT);
  u16*   w2t  = (u16*)(ws + O_W2T);
  u16*   xb   = (u16*)(ws + O_XB);
  u16*   hb   = (u16*)(ws + O_H);      // h bf16 (first 16MB of O_H region)
  u64*   adjm = (u64*)(ws + O_ADJ);
  float* sc0  = (float*)(ws + O_SC0);
  float* sh0  = (float*)(ws + O_SH0);
  float* sc2  = (float*)(ws + O_SC2);
  float* sh2  = (float*)(ws + O_SH2);
  float* lb0  = (float*)(ws + O_LB0);
  float* lb1  = (float*)(ws + O_LB1);
  char*  s2sb = ws + O_H;               // s2s scratch overlays h after GAT
  u16*   ac0  = (u16*)(s2sb + S_AC0);
  u16*   ac1  = (u16*)(s2sb + S_AC1);
  float* c0b  = (float*)(s2sb + S_C0);
  float* c1b  = (float*)(s2sb + S_C1);
  float* h1f  = (float*)(s2sb + S_H1F);
  float* zp   = (float*)(s2sb + S_ZP);
  float* ebuf = (float*)(s2sb + S_E);
  float* z1u  = (float*)(s2sb + S_Z1U);

  // --- setup: x cvt + weight transposes + prep + adjacency (one kernel) ---
  setup_all<<<16432, 256, 0, stream>>>(x, W0, Wg1, Wg2, W2,
                                       bn0g, bn0b, bn0m, bn0v, bn2g, bn2b, bn2m, bn2v,
                                       bih0, bhh0, bih1, bhh1, pos,
                                       xbf, w0t, wgt, w2t, sc0, sh0, sc2, sh2, lb0, lb1, adjm);

  // --- GEMM1: xb = bf16(bn0(relu(x @ W0))) ; GAT h = xb @ [Wg1|Wg2] (bf16 out) ---
  gemm_bf16<1><<<dim3(64, 16), 256, 0, stream>>>(xbf, w0t, nullptr, xb, sc0, sh0, 8192, 2048, 2048);
  gemm_bf16<3><<<dim3(64, 8), 256, 0, stream>>>(xb, wgt, nullptr, hb, nullptr, nullptr, 8192, 1024, 2048);
  // --- GAT attention (scores fused) ---
  gat_attn2<<<dim3(128, 16), 256, 0, stream>>>(adjm, hb, as1, ad1, as2, ad2, b1, b2, x2b);

  // --- Set2Set step 0: LSTM input is 0 -> state is graph-uniform (bias-derived) ---
  s2s0_gemv<<<1024, 256, 0, stream>>>(Wih1, lb1, lb0, z1u);
  s2s_e<0><<<2048, 256, 0, stream>>>(x2b, nullptr, z1u, ebuf);
  s2s_r<0><<<dim3(128, 4), 256, 0, stream>>>(x2b, ebuf, ac0, lb0, z1u, ac1, c0b, c1b);

  // --- Set2Set step 1 (full; LSTM weights read directly as f32) ---
  gemm_skf<<<dim3(64, 8), 256, 0, stream>>>(ac0, Wih0, Whh0, zp, 4096, 3072, 2048, 1024, 384);
  lstm_gate0<<<512, 256, 0, stream>>>(zp, lb0, c0b, ac0, ac1, 8);
  gemm_skf<<<dim3(64, 8), 256, 0, stream>>>(ac1, Wih1, Whh1, zp, 4096, 2048, 1024, 1024, 256);
  lstm_gate1<<<512, 256, 0, stream>>>(zp, lb1, c1b, h1f, ac1, ac0, 8);
  s2s_e<1><<<2048, 256, 0, stream>>>(x2b, h1f, nullptr, ebuf);
  s2s_r<1><<<dim3(128, 4), 256, 0, stream>>>(x2b, ebuf, ac0, nullptr, nullptr, nullptr, nullptr, nullptr);

  // --- lin2 (split-K 8) + lin3 ---
  gemm_sk<<<dim3(16, 8), 256, 0, stream>>>(ac0, w2t, zp, 1024, 3072, 2048, 256);
  lin3<<<128, 256, 0, stream>>>(zp, sc2, sh2, W3, b3, (float*)d_out);
}

// Round 12
// 283.595 us; speedup vs baseline: 5.6194x; 1.0693x over previous
//
#include <hip/hip_runtime.h>
#include <hip/hip_bf16.h>

typedef unsigned short u16;
typedef __attribute__((ext_vector_type(8))) short short8;
typedef __attribute__((ext_vector_type(4))) float f32x4;
typedef unsigned long long u64;

#define DI __device__ __forceinline__

DI u16 f2b(float f){
  unsigned u = __float_as_uint(f);
  unsigned r = 0x7fffu + ((u >> 16) & 1u);
  return (u16)((u + r) >> 16);
}
DI float b2f(u16 u){ return __uint_as_float((unsigned)u << 16); }

DI void gl_lds16(const void* g, void* l){
  __builtin_amdgcn_global_load_lds((const __attribute__((address_space(1))) void*)g,
                                   (__attribute__((address_space(3))) void*)l, 16, 0, 0);
}

// ---------------- workspace layout (bytes) ----------------
constexpr size_t O_XBF = 0;                    // 33554432: x bf16 [8192,2048]; later x2 bf16 [8192,1024] (16MB)
constexpr size_t O_W0T = O_XBF + 33554432;     // 8388608:  W0^T bf16 [2048,2048]
constexpr size_t O_WGT = O_W0T + 8388608;      // 4194304:  [Wg1|Wg2]^T bf16 [1024,2048]
constexpr size_t O_W2T = O_WGT + 4194304;      // 4194304:  W2^T bf16 [1024,2048]
constexpr size_t O_XB  = O_W2T + 4194304;      // 33554432: xb bf16 [8192,2048]
constexpr size_t O_H   = O_XB  + 33554432;     // region: h bf16 [8192,1024] (16MB); Set2Set scratch after GAT
constexpr size_t O_ES  = O_H   + 33554432;     // 524288 (unused)
constexpr size_t O_ED  = O_ES  + 524288;       // 524288 (unused)
constexpr size_t O_ADJ = O_ED  + 524288;       // 65536
constexpr size_t O_SC0 = O_ADJ + 65536;
constexpr size_t O_SH0 = O_SC0 + 8192;
constexpr size_t O_SC2 = O_SH0 + 8192;
constexpr size_t O_SH2 = O_SC2 + 4096;
constexpr size_t O_LB0 = O_SH2 + 4096;
constexpr size_t O_LB1 = O_LB0 + 16384;
// Set2Set scratch inside O_H (h is dead after gat_attn2):
constexpr size_t S_AC0 = 0;                    // 786432: acat0 bf16 [128][3072] = [q_star(2048) | h0(1024)]
constexpr size_t S_AC1 = S_AC0 + 786432;       // 524288: acat1 bf16 [128][2048] = [h0 | h1]
constexpr size_t S_C0  = S_AC1 + 524288;       // 524288
constexpr size_t S_C1  = S_C0  + 524288;       // 524288
constexpr size_t S_H1F = S_C1  + 524288;       // 524288: h1 f32 (step 1 only)
constexpr size_t S_ZP  = S_H1F + 524288;       // 16777216: split-K partials (8 x [128*4096] f32)
constexpr size_t S_E   = S_ZP  + 16777216;     // 32768: s2s scores e[8192]
constexpr size_t S_Z1U = S_E   + 32768;        // 16384: step-0 uniform z1 f32[4096]

// ---------------- one setup kernel: x cvt + 4 transposes + prep + adjacency ----------------
__global__ __launch_bounds__(256) void setup_all(
    const float* __restrict__ x,
    const float* __restrict__ W0, const float* __restrict__ Wg1,
    const float* __restrict__ Wg2, const float* __restrict__ W2,
    const float* __restrict__ g0, const float* __restrict__ b0, const float* __restrict__ m0, const float* __restrict__ v0,
    const float* __restrict__ g2, const float* __restrict__ b2, const float* __restrict__ m2, const float* __restrict__ v2,
    const float* __restrict__ bih0, const float* __restrict__ bhh0,
    const float* __restrict__ bih1, const float* __restrict__ bhh1,
    const float* __restrict__ pos,
    u16* __restrict__ xbf, u16* __restrict__ w0t, u16* __restrict__ wgt, u16* __restrict__ w2t,
    float* __restrict__ sc0, float* __restrict__ sh0, float* __restrict__ sc2, float* __restrict__ sh2,
    float* __restrict__ lb0, float* __restrict__ lb1, u64* __restrict__ adjm)
{
  __shared__ float tile[32][33];
  __shared__ float px[4][64], py[4][64];
  int bx = blockIdx.x, t = threadIdx.x;
  if(bx < 8192){
    int idx = bx * 256 + t;
    int r = idx >> 8, c8 = (idx & 255) << 3;
    const float* src = x + (size_t)r * 2048 + c8;
    float4 v0 = *(const float4*)src;
    float4 v1 = *(const float4*)(src + 4);
    short8 ov;
    ov[0] = (short)f2b(v0.x); ov[1] = (short)f2b(v0.y); ov[2] = (short)f2b(v0.z); ov[3] = (short)f2b(v0.w);
    ov[4] = (short)f2b(v1.x); ov[5] = (short)f2b(v1.y); ov[6] = (short)f2b(v1.z); ov[7] = (short)f2b(v1.w);
    *(short8*)(xbf + (size_t)r * 2048 + c8) = ov;
  } else if(bx < 16384){
    int bx2 = bx - 8192;
    int cx = bx2 & 127, by = bx2 >> 7;
    const float* src; u16* dst; int C, droff;
    if(cx < 64){      src = W0;  dst = w0t; C = 2048; droff = 0; }
    else if(cx < 80){ src = Wg1; dst = wgt; C = 512;  droff = 0;   cx -= 64; }
    else if(cx < 96){ src = Wg2; dst = wgt; C = 512;  droff = 512; cx -= 80; }
    else {            src = W2;  dst = w2t; C = 1024; droff = 0;   cx -= 96; }
    int c0 = cx * 32, r0 = by * 32;
    int tx = t & 31, ty = t >> 5;
    for(int i = 0; i < 4; i++)
      tile[ty + 8*i][tx] = src[(size_t)(r0 + ty + 8*i) * C + c0 + tx];
    __syncthreads();
    for(int i = 0; i < 4; i++)
      dst[(size_t)(droff + c0 + ty + 8*i) * 2048 + r0 + tx] = f2b(tile[tx][ty + 8*i]);
  } else if(bx < 16400){
    int tt = (bx - 16384) * 256 + t;
    if(tt < 2048){ float s = g0[tt] * rsqrtf(v0[tt] + 0.1f); sc0[tt] = s; sh0[tt] = b0[tt] - m0[tt] * s; }
    if(tt < 1024){ float s = g2[tt] * rsqrtf(v2[tt] + 0.1f); sc2[tt] = s; sh2[tt] = b2[tt] - m2[tt] * s; }
    lb0[tt] = bih0[tt] + bhh0[tt];
    lb1[tt] = bih1[tt] + bhh1[tt];
  } else {
    int w = t >> 6, l = t & 63;
    int g = (bx - 16400) * 4 + w;
    float2 p = ((const float2*)pos)[g * 64 + l];
    px[w][l] = p.x; py[w][l] = p.y;
    __syncthreads();
    float xi = p.x, yi = p.y;
    u64 m = 0;
    for(int j = 0; j < 64; j++){
      float dx = xi - px[w][j], dy = yi - py[w][j];
      if(dx * dx + dy * dy <= 16.0f) m |= (1ull << j);
    }
    adjm[g * 64 + l] = m;
  }
}

// ---------------- 256x256 8-phase counted-vmcnt GEMM (GEMM1 only) ----------------
// C[M,N] = bf16(relu(A@Bt^T)*p1 + p2).  M,N multiples of 256; K multiple of 128.
#define STAGE_A(buf, half, kt)                                                        \
  { _Pragma("unroll")                                                                 \
    for(int ld = 0; ld < 2; ld++){                                                    \
      int u = ld * 512 + t;                                                           \
      int r = (u >> 3) + (half) * 128, c = u & 7;                                     \
      gl_lds16(A + (size_t)(m0 + r) * K + (kt) * 64 + ((c ^ (r & 7)) << 3),           \
               LA + (buf) * 16384 + ((half) * 1024 + u) * 8);                         \
    } }
#define STAGE_B(buf, half, kt)                                                        \
  { _Pragma("unroll")                                                                 \
    for(int ld = 0; ld < 2; ld++){                                                    \
      int u = ld * 512 + t;                                                           \
      int r = (u >> 3) + (half) * 128, c = u & 7;                                     \
      gl_lds16(Bt + (size_t)(n0 + r) * K + (kt) * 64 + ((c ^ (r & 7)) << 3),          \
               LB + (buf) * 16384 + ((half) * 1024 + u) * 8);                         \
    } }
#define COMPUTE(buf, q)                                                               \
  { if((q) == 0){                                                                     \
      _Pragma("unroll")                                                               \
      for(int nb = 0; nb < 4; nb++)                                                   \
        _Pragma("unroll")                                                             \
        for(int k2 = 0; k2 < 2; k2++){                                                \
          int col = wn + nb * 16 + (l & 15);                                          \
          int kc = k2 * 4 + (l >> 4);                                                 \
          bfr[nb][k2] = Bp[(buf) * 2048 + col * 8 + (kc ^ (col & 7))];                \
        }                                                                             \
    }                                                                                 \
    short8 af[2][2];                                                                  \
    _Pragma("unroll")                                                                 \
    for(int rb = 0; rb < 2; rb++)                                                     \
      _Pragma("unroll")                                                               \
      for(int k2 = 0; k2 < 2; k2++){                                                  \
        int row = wm + (q) * 32 + rb * 16 + (l & 15);                                 \
        int kc = k2 * 4 + (l >> 4);                                                   \
        af[rb][k2] = Ap[(buf) * 2048 + row * 8 + (kc ^ (row & 7))];                   \
      }                                                                               \
    _Pragma("unroll")                                                                 \
    for(int rb = 0; rb < 2; rb++)                                                     \
      _Pragma("unroll")                                                               \
      for(int nb = 0; nb < 4; nb++)                                                   \
        _Pragma("unroll")                                                             \
        for(int k2 = 0; k2 < 2; k2++)                                                 \
          acc[(q) * 2 + rb][nb] = __builtin_amdgcn_mfma_f32_16x16x32_bf16(            \
              af[rb][k2], bfr[nb][k2], acc[(q) * 2 + rb][nb], 0, 0, 0);               \
  }
#define PHASE_BAR() { __builtin_amdgcn_s_barrier(); __builtin_amdgcn_sched_barrier(0); }
#define VM4() { asm volatile("s_waitcnt vmcnt(4)" ::: "memory"); __builtin_amdgcn_sched_barrier(0); }

__global__ __launch_bounds__(512, 2) void gemm8p(
    const u16* __restrict__ A, const u16* __restrict__ Bt, u16* __restrict__ Cb,
    const float* __restrict__ p1, const float* __restrict__ p2,
    int M, int N, int K)
{
  __shared__ alignas(16) u16 LA[2 * 16384];
  __shared__ alignas(16) u16 LB[2 * 16384];
  int m0 = blockIdx.x * 256, n0 = blockIdx.y * 256;
  int t = threadIdx.x, w = t >> 6, l = t & 63;
  int wm = (w >> 2) * 128, wn = (w & 3) * 64;
  int nt = K >> 6, ni = nt >> 1;
  f32x4 acc[8][4];
  #pragma unroll
  for(int a = 0; a < 8; a++)
    #pragma unroll
    for(int b = 0; b < 4; b++) acc[a][b] = {0.f, 0.f, 0.f, 0.f};
  short8 bfr[4][2];
  const short8* Ap = (const short8*)LA;
  const short8* Bp = (const short8*)LB;

  // prologue: full K-tile 0 into buf0, B-halves of K-tile 1 into buf1
  STAGE_A(0, 0, 0); STAGE_A(0, 1, 0); STAGE_B(0, 0, 0); STAGE_B(0, 1, 0);
  STAGE_B(1, 0, 1); STAGE_B(1, 1, 1);
  VM4();             // 12 loads -> 8 landed (all of K-tile 0); 4 outstanding (buf1 B)
  PHASE_BAR();

  for(int i = 0; i < ni; i++){
    int t1 = 2 * i + 1;
    int t2 = (2 * i + 2 < nt) ? 2 * i + 2 : nt - 1;
    int t3 = (2 * i + 3 < nt) ? 2 * i + 3 : nt - 1;
    // P1: stage Y(t1) A-halves (B staged last iter / prologue); compute X Q0
    STAGE_A(1, 0, t1); STAGE_A(1, 1, t1);
    COMPUTE(0, 0);
    PHASE_BAR();
    // P2: stage X'(t2).B0 (X.B freed after P1)
    STAGE_B(0, 0, t2);
    COMPUTE(0, 1);
    PHASE_BAR();
    // P3: stage X'(t2).B1
    STAGE_B(0, 1, t2);
    COMPUTE(0, 2);
    PHASE_BAR();
    // P4: no stage; ensure Y(t1) fully landed before P5 reads it
    COMPUTE(0, 3);
    VM4();           // 12 outstanding -> 8 landed: prev Y.B + this P1 Y.A
    PHASE_BAR();
    // P5: stage X'(t2).A0 (X.A freed after P4); compute Y Q0
    STAGE_A(0, 0, t2);
    COMPUTE(1, 0);
    PHASE_BAR();
    // P6: stage X'(t2).A1
    STAGE_A(0, 1, t2);
    COMPUTE(1, 1);
    PHASE_BAR();
    // P7: stage Y'(t3).B0 (Y.B freed after P5)
    STAGE_B(1, 0, t3);
    COMPUTE(1, 2);
    PHASE_BAR();
    // P8: stage Y'(t3).B1; ensure X'(t2) fully landed before next P1
    STAGE_B(1, 1, t3);
    COMPUTE(1, 3);
    VM4();           // 12 outstanding -> 8 landed: P2,P3 (X'.B) + P5,P6 (X'.A)
    PHASE_BAR();
  }
  asm volatile("s_waitcnt vmcnt(0)" ::: "memory");

  int cc = n0 + wn + (l & 15);
  int r4 = (l >> 4) << 2;
  #pragma unroll
  for(int ar = 0; ar < 8; ar++)
    #pragma unroll
    for(int nb = 0; nb < 4; nb++)
      #pragma unroll
      for(int r = 0; r < 4; r++){
        int row = m0 + wm + ar * 16 + r4 + r, col = cc + nb * 16;
        float v = acc[ar][nb][r];
        v = fmaxf(v, 0.f) * p1[col] + p2[col];
        Cb[(size_t)row * N + col] = f2b(v);
      }
}

// ---------------- bf16 MFMA GEMM (m97 structure) ----------------
// MODE 1: relu+bn -> bf16 Cb.  MODE 3: plain bf16 Cb.
template<int MODE>
__global__ __launch_bounds__(256) void gemm_bf16(
    const u16* __restrict__ A, const u16* __restrict__ Bt,
    float* __restrict__ Cf, u16* __restrict__ Cb,
    const float* __restrict__ p1, const float* __restrict__ p2,
    int M, int N, int K)
{
  constexpr int BM = 128, BN = 128, BK = 64;
  __shared__ alignas(16) u16 Al[BM * BK];
  __shared__ alignas(16) u16 Bl[BN * BK];
  int m0 = blockIdx.x * BM, n0 = blockIdx.y * BN;
  int t = threadIdx.x, w = t >> 6, l = t & 63;
  int wm = (w >> 1) * 64, wn = (w & 1) * 64;
  f32x4 acc[4][4];
  for(int a = 0; a < 4; a++) for(int b = 0; b < 4; b++) acc[a][b] = {0.f, 0.f, 0.f, 0.f};

  const short8* Ap = (const short8*)Al;
  const short8* Bp = (const short8*)Bl;

  for(int k0 = 0; k0 < K; k0 += BK){
    #pragma unroll
    for(int u = t; u < BM * 8; u += 256){
      int r = u >> 3, c = u & 7;
      gl_lds16(A + (size_t)(m0 + r) * K + k0 + ((c ^ (r & 7)) << 3), Al + u * 8);
    }
    #pragma unroll
    for(int u = t; u < BN * 8; u += 256){
      int r = u >> 3, c = u & 7;
      gl_lds16(Bt + (size_t)(n0 + r) * K + k0 + ((c ^ (r & 7)) << 3), Bl + u * 8);
    }
    __syncthreads();
    #pragma unroll
    for(int ks = 0; ks < 2; ks++){
      int kc = ks * 4 + (l >> 4);
      short8 av[4], bv[4];
      #pragma unroll
      for(int mi = 0; mi < 4; mi++){ int r = wm + mi * 16 + (l & 15); av[mi] = Ap[r * 8 + (kc ^ (r & 7))]; }
      #pragma unroll
      for(int ni = 0; ni < 4; ni++){ int r = wn + ni * 16 + (l & 15); bv[ni] = Bp[r * 8 + (kc ^ (r & 7))]; }
      #pragma unroll
      for(int mi = 0; mi < 4; mi++)
        #pragma unroll
        for(int ni = 0; ni < 4; ni++)
          acc[mi][ni] = __builtin_amdgcn_mfma_f32_16x16x32_bf16(av[mi], bv[ni], acc[mi][ni], 0, 0, 0);
    }
    __syncthreads();
  }

  int cr = m0 + wm + ((l >> 4) << 2);
  int cc = n0 + wn + (l & 15);
  for(int mi = 0; mi < 4; mi++)
    for(int ni = 0; ni < 4; ni++)
      for(int r = 0; r < 4; r++){
        int row = cr + mi * 16 + r, col = cc + ni * 16;
        float v = acc[mi][ni][r];
        if(MODE == 1){ v = fmaxf(v, 0.f) * p1[col] + p2[col]; Cb[(size_t)row * N + col] = f2b(v); }
        else if(MODE == 3){ Cb[(size_t)row * N + col] = f2b(v); }
        else { Cf[(size_t)row * N + col] = v; }
      }
}

// ---------------- split-K skinny GEMM (bf16 B), used for lin2 ----------------
__global__ __launch_bounds__(256) void gemm_sk(
    const u16* __restrict__ A, const u16* __restrict__ Bt, float* __restrict__ Cf,
    int N, int lda, int ldb, int kPer)
{
  constexpr int BM = 128, BN = 64, BK = 64;
  __shared__ alignas(16) u16 Al[BM * BK];
  __shared__ alignas(16) u16 Bl[BN * BK];
  int n0 = blockIdx.x * BN;
  int kb = blockIdx.y * kPer;
  float* C = Cf + (size_t)blockIdx.y * 128 * N;
  int t = threadIdx.x, w = t >> 6, l = t & 63;
  int wm = (w >> 1) * 64, wn = (w & 1) * 32;
  f32x4 acc[4][2];
  for(int a = 0; a < 4; a++) for(int b = 0; b < 2; b++) acc[a][b] = {0.f, 0.f, 0.f, 0.f};

  const short8* Ap = (const short8*)Al;
  const short8* Bp = (const short8*)Bl;

  for(int k0 = kb; k0 < kb + kPer; k0 += BK){
    #pragma unroll
    for(int u = t; u < BM * 8; u += 256){
      int r = u >> 3, c = u & 7;
      gl_lds16(A + (size_t)r * lda + k0 + ((c ^ (r & 7)) << 3), Al + u * 8);
    }
    #pragma unroll
    for(int u = t; u < BN * 8; u += 256){
      int r = u >> 3, c = u & 7;
      gl_lds16(Bt + (size_t)(n0 + r) * ldb + k0 + ((c ^ (r & 7)) << 3), Bl + u * 8);
    }
    __syncthreads();
    #pragma unroll
    for(int ks = 0; ks < 2; ks++){
      int kc = ks * 4 + (l >> 4);
      short8 av[4], bv[2];
      #pragma unroll
      for(int mi = 0; mi < 4; mi++){ int r = wm + mi * 16 + (l & 15); av[mi] = Ap[r * 8 + (kc ^ (r & 7))]; }
      #pragma unroll
      for(int ni = 0; ni < 2; ni++){ int r = wn + ni * 16 + (l & 15); bv[ni] = Bp[r * 8 + (kc ^ (r & 7))]; }
      #pragma unroll
      for(int mi = 0; mi < 4; mi++)
        #pragma unroll
        for(int ni = 0; ni < 2; ni++)
          acc[mi][ni] = __builtin_amdgcn_mfma_f32_16x16x32_bf16(av[mi], bv[ni], acc[mi][ni], 0, 0, 0);
    }
    __syncthreads();
  }

  int cr = wm + ((l >> 4) << 2);
  int cc = n0 + wn + (l & 15);
  for(int mi = 0; mi < 4; mi++)
    for(int ni = 0; ni < 2; ni++)
      for(int r = 0; r < 4; r++)
        C[(size_t)(cr + mi * 16 + r) * N + cc + ni * 16] = acc[mi][ni][r];
}

// ---------------- split-K skinny GEMM with f32 B (in-kernel bf16 conversion) ----------------
__global__ __launch_bounds__(256) void gemm_skf(
    const u16* __restrict__ A, const float* __restrict__ Wih, const float* __restrict__ Whh,
    float* __restrict__ Cf, int N, int lda, int Kih, int Khh, int kPer)
{
  constexpr int BM = 128, BN = 64, BK = 64;
  __shared__ alignas(16) u16 Al[BM * BK];
  __shared__ alignas(16) u16 Bl[BN * BK];
  int n0 = blockIdx.x * BN;
  int kb = blockIdx.y * kPer;
  float* C = Cf + (size_t)blockIdx.y * 128 * N;
  int t = threadIdx.x, w = t >> 6, l = t & 63;
  int wm = (w >> 1) * 64, wn = (w & 1) * 32;
  f32x4 acc[4][2];
  for(int a = 0; a < 4; a++) for(int b = 0; b < 2; b++) acc[a][b] = {0.f, 0.f, 0.f, 0.f};

  const short8* Ap = (const short8*)Al;
  const short8* Bp = (const short8*)Bl;

  for(int k0 = kb; k0 < kb + kPer; k0 += BK){
    #pragma unroll
    for(int u = t; u < BM * 8; u += 256){
      int r = u >> 3, c = u & 7;
      gl_lds16(A + (size_t)r * lda + k0 + ((c ^ (r & 7)) << 3), Al + u * 8);
    }
    #pragma unroll
    for(int u = t; u < BN * 8; u += 256){
      int r = u >> 3, c = u & 7;
      int gk = k0 + c * 8;
      const float* src = (gk < Kih) ? (Wih + (size_t)(n0 + r) * Kih + gk)
                                    : (Whh + (size_t)(n0 + r) * Khh + (gk - Kih));
      float4 v0 = *(const float4*)src;
      float4 v1 = *(const float4*)(src + 4);
      short8 ov;
      ov[0] = (short)f2b(v0.x); ov[1] = (short)f2b(v0.y); ov[2] = (short)f2b(v0.z); ov[3] = (short)f2b(v0.w);
      ov[4] = (short)f2b(v1.x); ov[5] = (short)f2b(v1.y); ov[6] = (short)f2b(v1.z); ov[7] = (short)f2b(v1.w);
      ((short8*)Bl)[r * 8 + (c ^ (r & 7))] = ov;
    }
    __syncthreads();
    #pragma unroll
    for(int ks = 0; ks < 2; ks++){
      int kc = ks * 4 + (l >> 4);
      short8 av[4], bv[2];
      #pragma unroll
      for(int mi = 0; mi < 4; mi++){ int r = wm + mi * 16 + (l & 15); av[mi] = Ap[r * 8 + (kc ^ (r & 7))]; }
      #pragma unroll
      for(int ni = 0; ni < 2; ni++){ int r = wn + ni * 16 + (l & 15); bv[ni] = Bp[r * 8 + (kc ^ (r & 7))]; }
      #pragma unroll
      for(int mi = 0; mi < 4; mi++)
        #pragma unroll
        for(int ni = 0; ni < 2; ni++)
          acc[mi][ni] = __builtin_amdgcn_mfma_f32_16x16x32_bf16(av[mi], bv[ni], acc[mi][ni], 0, 0, 0);
    }
    __syncthreads();
  }

  int cr = wm + ((l >> 4) << 2);
  int cc = n0 + wn + (l & 15);
  for(int mi = 0; mi < 4; mi++)
    for(int ni = 0; ni < 2; ni++)
      for(int r = 0; r < 4; r++)
        C[(size_t)(cr + mi * 16 + r) * N + cc + ni * 16] = acc[mi][ni][r];
}

// ---------------- GAT: scores (fused) + softmax + aggregate, per (graph, conv, head) ----------------
__global__ __launch_bounds__(256) void gat_attn2(const u64* __restrict__ adjm,
    const u16* __restrict__ h,
    const float* __restrict__ as1, const float* __restrict__ ad1,
    const float* __restrict__ as2, const float* __restrict__ ad2,
    const float* __restrict__ b1, const float* __restrict__ b2,
    u16* __restrict__ x2b){
  int b = blockIdx.x;
  int cv = blockIdx.y >> 3, hh = blockIdx.y & 7;
  __shared__ float hst[64][64];
  __shared__ float alphaL[64][65];
  __shared__ float esl[64], edl[64];
  __shared__ u64 adjs[64];
  int t = threadIdx.x, w = t >> 6, l = t & 63;
  {
    int j = t >> 2, d0 = (t & 3) * 16;
    const u16* hr = h + (size_t)(b * 64 + j) * 1024 + cv * 512 + hh * 64 + d0;
    #pragma unroll
    for(int k = 0; k < 16; k++) hst[j][d0 + k] = b2f(hr[k]);
  }
  if(t < 64) adjs[t] = adjm[b * 64 + t];
  __syncthreads();
  float aSl = ((cv ? as2 : as1) + hh * 64)[l];
  float aDl = ((cv ? ad2 : ad1) + hh * 64)[l];
  for(int it = 0; it < 16; it++){
    int j = it * 4 + w;
    float v = hst[j][l];
    float ps = v * aSl, pd = v * aDl;
    for(int o = 32; o; o >>= 1){ ps += __shfl_xor(ps, o); pd += __shfl_xor(pd, o); }
    if(l == 0){ esl[j] = ps; edl[j] = pd; }
  }
  __syncthreads();
  for(int it = 0; it < 16; it++){
    int i = it * 4 + w;
    bool on = (adjs[i] >> l) & 1;
    float e = edl[i] + esl[l];
    e = e > 0.f ? e : 0.2f * e;
    float mx = on ? e : -1e30f;
    for(int o = 32; o; o >>= 1) mx = fmaxf(mx, __shfl_xor(mx, o));
    float p = on ? __expf(e - mx) : 0.f;
    float s = p;
    for(int o = 32; o; o >>= 1) s += __shfl_xor(s, o);
    alphaL[i][l] = p / s;
  }
  __syncthreads();
  int i = t >> 2, q = t & 3;
  float acc[16];
  #pragma unroll
  for(int k = 0; k < 16; k++) acc[k] = 0.f;
  for(int j = 0; j < 64; j++){
    float al = alphaL[i][j];
    const float* hr = &hst[j][q * 16];
    #pragma unroll
    for(int k = 0; k < 16; k++) acc[k] += al * hr[k];
  }
  const float* bias = (cv ? b2 : b1) + hh * 64 + q * 16;
  u16* op = x2b + (size_t)(b * 64 + i) * 1024 + cv * 512 + hh * 64 + q * 16;
  #pragma unroll
  for(int k = 0; k < 16; k++) op[k] = f2b(fmaxf(acc[k] + bias[k], 0.f));
}

// ---------------- Set2Set step-0 shortcut ----------------
__global__ __launch_bounds__(256) void s2s0_gemv(const float* __restrict__ Wih1,
    const float* __restrict__ lb1, const float* __restrict__ lb0, float* __restrict__ z1u){
  __shared__ float hs[1024];
  int t = threadIdx.x;
  for(int i = t; i < 1024; i += 256){
    float zi = lb0[i], zg = lb0[2048 + i], zo = lb0[3072 + i];
    float cn = (1.f / (1.f + __expf(-zi))) * tanhf(zg);
    hs[i] = (1.f / (1.f + __expf(-zo))) * tanhf(cn);
  }
  __syncthreads();
  int w = t >> 6, l = t & 63;
  int r = blockIdx.x * 4 + w;
  const float* wr = Wih1 + (size_t)r * 1024;
  float s = 0.f;
  #pragma unroll
  for(int k = 0; k < 16; k++) s += wr[l + 64 * k] * hs[l + 64 * k];
  for(int o = 32; o; o >>= 1) s += __shfl_xor(s, o);
  if(l == 0) z1u[r] = s + lb1[r];
}

// ---------------- LSTM gates (sum ns split-K partials) ----------------
__global__ void lstm_gate0(const float* __restrict__ zp, const float* __restrict__ lb,
                           float* __restrict__ c, u16* __restrict__ ac0, u16* __restrict__ ac1,
                           int ns){
  int t = blockIdx.x * 256 + threadIdx.x;
  int b = t >> 10, j = t & 1023;
  size_t base = (size_t)b * 4096;
  float zi = 0, zf = 0, zg = 0, zo = 0;
  for(int s = 0; s < ns; s++){
    const float* zr = zp + (size_t)s * 524288 + base;
    zi += zr[j]; zf += zr[1024 + j]; zg += zr[2048 + j]; zo += zr[3072 + j];
  }
  zi += lb[j]; zf += lb[1024 + j]; zg += lb[2048 + j]; zo += lb[3072 + j];
  float ci = c[t];
  float si = 1.f / (1.f + __expf(-zi)), sf = 1.f / (1.f + __expf(-zf)), so = 1.f / (1.f + __expf(-zo));
  float cn = sf * ci + si * tanhf(zg);
  c[t] = cn;
  u16 hb = f2b(so * tanhf(cn));
  ac0[(size_t)b * 3072 + 2048 + j] = hb;
  ac1[(size_t)b * 2048 + j] = hb;
}

__global__ void lstm_gate1(const float* __restrict__ zp, const float* __restrict__ lb,
                           float* __restrict__ c, float* __restrict__ h1f,
                           u16* __restrict__ ac1, u16* __restrict__ ac0, int ns){
  int t = blockIdx.x * 256 + threadIdx.x;
  int b = t >> 10, j = t & 1023;
  size_t base = (size_t)b * 4096;
  float zi = 0, zf = 0, zg = 0, zo = 0;
  for(int s = 0; s < ns; s++){
    const float* zr = zp + (size_t)s * 524288 + base;
    zi += zr[j]; zf += zr[1024 + j]; zg += zr[2048 + j]; zo += zr[3072 + j];
  }
  zi += lb[j]; zf += lb[1024 + j]; zg += lb[2048 + j]; zo += lb[3072 + j];
  float ci = c[t];
  float si = 1.f / (1.f + __expf(-zi)), sf = 1.f / (1.f + __expf(-zf)), so = 1.f / (1.f + __expf(-zo));
  float cn = sf * ci + si * tanhf(zg);
  c[t] = cn;
  float hn = so * tanhf(cn);
  h1f[t] = hn;
  u16 hb = f2b(hn);
  ac1[(size_t)b * 2048 + 1024 + j] = hb;
  ac0[(size_t)b * 3072 + j] = hb;
}

// ---------------- Set2Set attention (bf16 x2) ----------------
template<int STEP>
__global__ __launch_bounds__(256) void s2s_e(const u16* __restrict__ x2b,
    const float* __restrict__ h1, const float* __restrict__ z1u, float* __restrict__ e){
  __shared__ float h1s[1024];
  int t = threadIdx.x, w = t >> 6, l = t & 63;
  int node = blockIdx.x * 4 + w;
  int b = node >> 6;
  for(int i = t; i < 1024; i += 256){
    if(STEP == 0){
      float zi = z1u[i], zg = z1u[2048 + i], zo = z1u[3072 + i];
      float cn = (1.f / (1.f + __expf(-zi))) * tanhf(zg);
      h1s[i] = (1.f / (1.f + __expf(-zo))) * tanhf(cn);
    } else {
      h1s[i] = h1[(size_t)b * 1024 + i];
    }
  }
  __syncthreads();
  const u16* xr = x2b + (size_t)node * 1024;
  float s = 0.f;
  #pragma unroll
  for(int k = 0; k < 16; k++){
    int d = k * 64 + l;
    s += b2f(xr[d]) * h1s[d];
  }
  for(int o = 32; o; o >>= 1) s += __shfl_xor(s, o);
  if(l == 0) e[node] = s;
}

template<int STEP>
__global__ __launch_bounds__(256) void s2s_r(const u16* __restrict__ x2b,
    const float* __restrict__ e, u16* __restrict__ ac0,
    const float* __restrict__ lb0, const float* __restrict__ z1u,
    u16* __restrict__ ac1, float* __restrict__ c0b, float* __restrict__ c1b){
  int b = blockIdx.x, sl = blockIdx.y;
  __shared__ float al[64];
  int t = threadIdx.x;
  if(t < 64){
    float v = e[b * 64 + t];
    float mx = v;
    for(int o = 32; o; o >>= 1) mx = fmaxf(mx, __shfl_xor(mx, o));
    float p = __expf(v - mx);
    float ss = p;
    for(int o = 32; o; o >>= 1) ss += __shfl_xor(ss, o);
    al[t] = p / ss;
  }
  __syncthreads();
  int d = sl * 256 + t;
  const u16* xp = x2b + (size_t)b * 65536 + d;
  float r = 0.f;
  #pragma unroll 8
  for(int j = 0; j < 64; j++) r += al[j] * b2f(xp[j * 1024]);
  ac0[(size_t)b * 3072 + 1024 + d] = f2b(r);
  if(STEP == 0){
    float zi0 = lb0[d], zg0 = lb0[2048 + d], zo0 = lb0[3072 + d];
    float c0 = (1.f / (1.f + __expf(-zi0))) * tanhf(zg0);
    float h0 = (1.f / (1.f + __expf(-zo0))) * tanhf(c0);
    float zi1 = z1u[d], zg1 = z1u[2048 + d], zo1 = z1u[3072 + d];
    float c1 = (1.f / (1.f + __expf(-zi1))) * tanhf(zg1);
    float h1 = (1.f / (1.f + __expf(-zo1))) * tanhf(c1);
    c0b[(size_t)b * 1024 + d] = c0;
    c1b[(size_t)b * 1024 + d] = c1;
    u16 h0b = f2b(h0), h1b = f2b(h1);
    ac0[(size_t)b * 3072 + d] = h1b;
    ac0[(size_t)b * 3072 + 2048 + d] = h0b;
    ac1[(size_t)b * 2048 + d] = h0b;
    ac1[(size_t)b * 2048 + 1024 + d] = h1b;
  }
}

// ---------------- lin2 combine (8 split partials) + bn + relu + lin3 ----------------
__global__ __launch_bounds__(256) void lin3(const float* __restrict__ zp2,
    const float* __restrict__ sc2, const float* __restrict__ sh2,
    const float* __restrict__ W3, const float* __restrict__ b3, float* __restrict__ out){
  int b = blockIdx.x;
  __shared__ float yl[1024];
  int t = threadIdx.x, w = t >> 6, l = t & 63;
  for(int d = t; d < 1024; d += 256){
    float v = 0.f;
    for(int s = 0; s < 8; s++) v += zp2[(size_t)s * 131072 + b * 1024 + d];
    yl[d] = fmaxf(v, 0.f) * sc2[d] + sh2[d];
  }
  __syncthreads();
  for(int n = w; n < 10; n += 4){
    float s = 0.f;
    for(int d = l; d < 1024; d += 64) s += yl[d] * W3[d * 10 + n];
    for(int o = 32; o; o >>= 1) s += __shfl_xor(s, o);
    if(l == 0) out[b * 10 + n] = s + b3[n];
  }
}

extern "C" void kernel_launch(void* const* d_in, const int* in_sizes, int n_in,
                              void* d_out, int out_size, void* d_ws, size_t ws_size,
                              hipStream_t stream){
  const float* x    = (const float*)d_in[0];
  const float* pos  = (const float*)d_in[1];
  const float* W0   = (const float*)d_in[3];
  const float* bn0g = (const float*)d_in[4];
  const float* bn0b = (const float*)d_in[5];
  const float* bn0m = (const float*)d_in[6];
  const float* bn0v = (const float*)d_in[7];
  const float* Wg1  = (const float*)d_in[8];
  const float* as1  = (const float*)d_in[9];
  const float* ad1  = (const float*)d_in[10];
  const float* b1   = (const float*)d_in[11];
  const float* Wg2  = (const float*)d_in[12];
  const float* as2  = (const float*)d_in[13];
  const float* ad2  = (const float*)d_in[14];
  const float* b2   = (const float*)d_in[15];
  const float* Wih0 = (const float*)d_in[16];
  const float* Whh0 = (const float*)d_in[17];
  const float* bih0 = (const float*)d_in[18];
  const float* bhh0 = (const float*)d_in[19];
  const float* Wih1 = (const float*)d_in[20];
  const float* Whh1 = (const float*)d_in[21];
  const float* bih1 = (const float*)d_in[22];
  const float* bhh1 = (const float*)d_in[23];
  const float* W2   = (const float*)d_in[24];
  const float* bn2g = (const float*)d_in[25];
  const float* bn2b = (const float*)d_in[26];
  const float* bn2m = (const float*)d_in[27];
  const float* bn2v = (const float*)d_in[28];
  const float* W3   = (const float*)d_in[29];
  const float* b3   = (const float*)d_in[30];

  char* ws = (char*)d_ws;
  u16*   xbf  = (u16*)(ws + O_XBF);
  u16*   x2b  = (u16*)(ws + O_XBF);
  u16*   w0t  = (u16*)(ws + O_W0T);
  u16*   wgt  = (u16*)(ws + O_WGT);
  u16*   w2t  = (u16*)(ws + O_W2T);
  u16*   xb   = (u16*)(ws + O_XB);
  u16*   hb   = (u16*)(ws + O_H);
  u64*   adjm = (u64*)(ws + O_ADJ);
  float* sc0  = (float*)(ws + O_SC0);
  float* sh0  = (float*)(ws + O_SH0);
  float* sc2  = (float*)(ws + O_SC2);
  float* sh2  = (float*)(ws + O_SH2);
  float* lb0  = (float*)(ws + O_LB0);
  float* lb1  = (float*)(ws + O_LB1);
  char*  s2sb = ws + O_H;
  u16*   ac0  = (u16*)(s2sb + S_AC0);
  u16*   ac1  = (u16*)(s2sb + S_AC1);
  float* c0b  = (float*)(s2sb + S_C0);
  float* c1b  = (float*)(s2sb + S_C1);
  float* h1f  = (float*)(s2sb + S_H1F);
  float* zp   = (float*)(s2sb + S_ZP);
  float* ebuf = (float*)(s2sb + S_E);
  float* z1u  = (float*)(s2sb + S_Z1U);

  // --- setup: x cvt + weight transposes + prep + adjacency (one kernel) ---
  setup_all<<<16432, 256, 0, stream>>>(x, W0, Wg1, Wg2, W2,
                                       bn0g, bn0b, bn0m, bn0v, bn2g, bn2b, bn2m, bn2v,
                                       bih0, bhh0, bih1, bhh1, pos,
                                       xbf, w0t, wgt, w2t, sc0, sh0, sc2, sh2, lb0, lb1, adjm);

  // --- GEMM1 (8-phase 256^2): xb = bf16(bn0(relu(x @ W0))) ---
  gemm8p<<<dim3(32, 8), 512, 0, stream>>>(xbf, w0t, xb, sc0, sh0, 8192, 2048, 2048);
  // --- GAT h = xb @ [Wg1|Wg2] (m97 128^2, bf16 out) ---
  gemm_bf16<3><<<dim3(64, 8), 256, 0, stream>>>(xb, wgt, nullptr, hb, nullptr, nullptr, 8192, 1024, 2048);
  // --- GAT attention (scores fused) ---
  gat_attn2<<<dim3(128, 16), 256, 0, stream>>>(adjm, hb, as1, ad1, as2, ad2, b1, b2, x2b);

  // --- Set2Set step 0: LSTM input is 0 -> state is graph-uniform (bias-derived) ---
  s2s0_gemv<<<1024, 256, 0, stream>>>(Wih1, lb1, lb0, z1u);
  s2s_e<0><<<2048, 256, 0, stream>>>(x2b, nullptr, z1u, ebuf);
  s2s_r<0><<<dim3(128, 4), 256, 0, stream>>>(x2b, ebuf, ac0, lb0, z1u, ac1, c0b, c1b);

  // --- Set2Set step 1 (full; LSTM weights read directly as f32) ---
  gemm_skf<<<dim3(64, 8), 256, 0, stream>>>(ac0, Wih0, Whh0, zp, 4096, 3072, 2048, 1024, 384);
  lstm_gate0<<<512, 256, 0, stream>>>(zp, lb0, c0b, ac0, ac1, 8);
  gemm_skf<<<dim3(64, 8), 256, 0, stream>>>(ac1, Wih1, Whh1, zp, 4096, 2048, 1024, 1024, 256);
  lstm_gate1<<<512, 256, 0, stream>>>(zp, lb1, c1b, h1f, ac1, ac0, 8);
  s2s_e<1><<<2048, 256, 0, stream>>>(x2b, h1f, nullptr, ebuf);
  s2s_r<1><<<dim3(128, 4), 256, 0, stream>>>(x2b, ebuf, ac0, nullptr, nullptr, nullptr, nullptr, nullptr);

  // --- lin2 (split-K 8) + lin3 ---
  gemm_sk<<<dim3(16, 8), 256, 0, stream>>>(ac0, w2t, zp, 1024, 3072, 2048, 256);
  lin3<<<128, 256, 0, stream>>>(zp, sc2, sh2, W3, b3, (float*)d_out);
}

// Round 14
// 278.157 us; speedup vs baseline: 5.7293x; 1.0195x over previous
//
#include <hip/hip_runtime.h>
#include <hip/hip_bf16.h>

typedef unsigned short u16;
typedef __attribute__((ext_vector_type(8))) short short8;
typedef __attribute__((ext_vector_type(4))) float f32x4;
typedef unsigned long long u64;

#define DI __device__ __forceinline__

DI u16 f2b(float f){
  unsigned u = __float_as_uint(f);
  unsigned r = 0x7fffu + ((u >> 16) & 1u);
  return (u16)((u + r) >> 16);
}
DI float b2f(u16 u){ return __uint_as_float((unsigned)u << 16); }

DI void gl_lds16(const void* g, void* l){
  __builtin_amdgcn_global_load_lds((const __attribute__((address_space(1))) void*)g,
                                   (__attribute__((address_space(3))) void*)l, 16, 0, 0);
}

// ---------------- workspace layout (bytes) ----------------
constexpr size_t O_XBF = 0;
constexpr size_t O_W0T = O_XBF + 33554432;
constexpr size_t O_WGT = O_W0T + 8388608;
constexpr size_t O_W2T = O_WGT + 4194304;
constexpr size_t O_XB  = O_W2T + 4194304;
constexpr size_t O_H   = O_XB  + 33554432;
constexpr size_t O_ES  = O_H   + 33554432;
constexpr size_t O_ED  = O_ES  + 524288;
constexpr size_t O_ADJ = O_ED  + 524288;
constexpr size_t O_SC0 = O_ADJ + 65536;
constexpr size_t O_SH0 = O_SC0 + 8192;
constexpr size_t O_SC2 = O_SH0 + 8192;
constexpr size_t O_SH2 = O_SC2 + 4096;
constexpr size_t O_LB0 = O_SH2 + 4096;
constexpr size_t O_LB1 = O_LB0 + 16384;
constexpr size_t S_AC0 = 0;
constexpr size_t S_AC1 = S_AC0 + 786432;
constexpr size_t S_C0  = S_AC1 + 524288;
constexpr size_t S_C1  = S_C0  + 524288;
constexpr size_t S_H1F = S_C1  + 524288;
constexpr size_t S_ZP  = S_H1F + 524288;
constexpr size_t S_E   = S_ZP  + 16777216;
constexpr size_t S_Z1U = S_E   + 32768;

// ---------------- one setup kernel: x cvt + 4 transposes + prep + adjacency ----------------
__global__ __launch_bounds__(256) void setup_all(
    const float* __restrict__ x,
    const float* __restrict__ W0, const float* __restrict__ Wg1,
    const float* __restrict__ Wg2, const float* __restrict__ W2,
    const float* __restrict__ g0, const float* __restrict__ b0, const float* __restrict__ m0, const float* __restrict__ v0,
    const float* __restrict__ g2, const float* __restrict__ b2, const float* __restrict__ m2, const float* __restrict__ v2,
    const float* __restrict__ bih0, const float* __restrict__ bhh0,
    const float* __restrict__ bih1, const float* __restrict__ bhh1,
    const float* __restrict__ pos,
    u16* __restrict__ xbf, u16* __restrict__ w0t, u16* __restrict__ wgt, u16* __restrict__ w2t,
    float* __restrict__ sc0, float* __restrict__ sh0, float* __restrict__ sc2, float* __restrict__ sh2,
    float* __restrict__ lb0, float* __restrict__ lb1, u64* __restrict__ adjm)
{
  __shared__ float tile[32][33];
  __shared__ float px[4][64], py[4][64];
  int bx = blockIdx.x, t = threadIdx.x;
  if(bx < 8192){
    int idx = bx * 256 + t;
    int r = idx >> 8, c8 = (idx & 255) << 3;
    const float* src = x + (size_t)r * 2048 + c8;
    float4 v0 = *(const float4*)src;
    float4 v1 = *(const float4*)(src + 4);
    short8 ov;
    ov[0] = (short)f2b(v0.x); ov[1] = (short)f2b(v0.y); ov[2] = (short)f2b(v0.z); ov[3] = (short)f2b(v0.w);
    ov[4] = (short)f2b(v1.x); ov[5] = (short)f2b(v1.y); ov[6] = (short)f2b(v1.z); ov[7] = (short)f2b(v1.w);
    *(short8*)(xbf + (size_t)r * 2048 + c8) = ov;
  } else if(bx < 16384){
    int bx2 = bx - 8192;
    int cx = bx2 & 127, by = bx2 >> 7;
    const float* src; u16* dst; int C, droff;
    if(cx < 64){      src = W0;  dst = w0t; C = 2048; droff = 0; }
    else if(cx < 80){ src = Wg1; dst = wgt; C = 512;  droff = 0;   cx -= 64; }
    else if(cx < 96){ src = Wg2; dst = wgt; C = 512;  droff = 512; cx -= 80; }
    else {            src = W2;  dst = w2t; C = 1024; droff = 0;   cx -= 96; }
    int c0 = cx * 32, r0 = by * 32;
    int tx = t & 31, ty = t >> 5;
    for(int i = 0; i < 4; i++)
      tile[ty + 8*i][tx] = src[(size_t)(r0 + ty + 8*i) * C + c0 + tx];
    __syncthreads();
    for(int i = 0; i < 4; i++)
      dst[(size_t)(droff + c0 + ty + 8*i) * 2048 + r0 + tx] = f2b(tile[tx][ty + 8*i]);
  } else if(bx < 16400){
    int tt = (bx - 16384) * 256 + t;
    if(tt < 2048){ float s = g0[tt] * rsqrtf(v0[tt] + 0.1f); sc0[tt] = s; sh0[tt] = b0[tt] - m0[tt] * s; }
    if(tt < 1024){ float s = g2[tt] * rsqrtf(v2[tt] + 0.1f); sc2[tt] = s; sh2[tt] = b2[tt] - m2[tt] * s; }
    lb0[tt] = bih0[tt] + bhh0[tt];
    lb1[tt] = bih1[tt] + bhh1[tt];
  } else {
    int w = t >> 6, l = t & 63;
    int g = (bx - 16400) * 4 + w;
    float2 p = ((const float2*)pos)[g * 64 + l];
    px[w][l] = p.x; py[w][l] = p.y;
    __syncthreads();
    float xi = p.x, yi = p.y;
    u64 m = 0;
    for(int j = 0; j < 64; j++){
      float dx = xi - px[w][j], dy = yi - py[w][j];
      if(dx * dx + dy * dy <= 16.0f) m |= (1ull << j);
    }
    adjm[g * 64 + l] = m;
  }
}

// ---------------- 256x256 8-phase counted-vmcnt GEMM (GEMM1) ----------------
#define STAGE_A(buf, half, kt)                                                        \
  { _Pragma("unroll")                                                                 \
    for(int ld = 0; ld < 2; ld++){                                                    \
      int u = ld * 512 + t;                                                           \
      int r = (u >> 3) + (half) * 128, c = u & 7;                                     \
      gl_lds16(A + (size_t)(m0 + r) * K + (kt) * 64 + ((c ^ (r & 7)) << 3),           \
               LA + (buf) * 16384 + ((half) * 1024 + u) * 8);                         \
    } }
#define STAGE_B(buf, half, kt)                                                        \
  { _Pragma("unroll")                                                                 \
    for(int ld = 0; ld < 2; ld++){                                                    \
      int u = ld * 512 + t;                                                           \
      int r = (u >> 3) + (half) * 128, c = u & 7;                                     \
      gl_lds16(Bt + (size_t)(n0 + r) * K + (kt) * 64 + ((c ^ (r & 7)) << 3),          \
               LB + (buf) * 16384 + ((half) * 1024 + u) * 8);                         \
    } }
#define COMPUTE(buf, q)                                                               \
  { if((q) == 0){                                                                     \
      _Pragma("unroll")                                                               \
      for(int nb = 0; nb < 4; nb++)                                                   \
        _Pragma("unroll")                                                             \
        for(int k2 = 0; k2 < 2; k2++){                                                \
          int col = wn + nb * 16 + (l & 15);                                          \
          int kc = k2 * 4 + (l >> 4);                                                 \
          bfr[nb][k2] = Bp[(buf) * 2048 + col * 8 + (kc ^ (col & 7))];                \
        }                                                                             \
    }                                                                                 \
    short8 af[2][2];                                                                  \
    _Pragma("unroll")                                                                 \
    for(int rb = 0; rb < 2; rb++)                                                     \
      _Pragma("unroll")                                                               \
      for(int k2 = 0; k2 < 2; k2++){                                                  \
        int row = wm + (q) * 32 + rb * 16 + (l & 15);                                 \
        int kc = k2 * 4 + (l >> 4);                                                   \
        af[rb][k2] = Ap[(buf) * 2048 + row * 8 + (kc ^ (row & 7))];                   \
      }                                                                               \
    _Pragma("unroll")                                                                 \
    for(int rb = 0; rb < 2; rb++)                                                     \
      _Pragma("unroll")                                                               \
      for(int nb = 0; nb < 4; nb++)                                                   \
        _Pragma("unroll")                                                             \
        for(int k2 = 0; k2 < 2; k2++)                                                 \
          acc[(q) * 2 + rb][nb] = __builtin_amdgcn_mfma_f32_16x16x32_bf16(            \
              af[rb][k2], bfr[nb][k2], acc[(q) * 2 + rb][nb], 0, 0, 0);               \
  }
#define PHASE_BAR() { __builtin_amdgcn_s_barrier(); __builtin_amdgcn_sched_barrier(0); }
#define VM4() { asm volatile("s_waitcnt vmcnt(4)" ::: "memory"); __builtin_amdgcn_sched_barrier(0); }

__global__ __launch_bounds__(512, 2) void gemm8p(
    const u16* __restrict__ A, const u16* __restrict__ Bt, u16* __restrict__ Cb,
    const float* __restrict__ p1, const float* __restrict__ p2,
    int M, int N, int K)
{
  __shared__ alignas(16) u16 LA[2 * 16384];
  __shared__ alignas(16) u16 LB[2 * 16384];
  int m0 = blockIdx.x * 256, n0 = blockIdx.y * 256;
  int t = threadIdx.x, w = t >> 6, l = t & 63;
  int wm = (w >> 2) * 128, wn = (w & 3) * 64;
  int nt = K >> 6, ni = nt >> 1;
  f32x4 acc[8][4];
  #pragma unroll
  for(int a = 0; a < 8; a++)
    #pragma unroll
    for(int b = 0; b < 4; b++) acc[a][b] = {0.f, 0.f, 0.f, 0.f};
  short8 bfr[4][2];
  const short8* Ap = (const short8*)LA;
  const short8* Bp = (const short8*)LB;

  STAGE_A(0, 0, 0); STAGE_A(0, 1, 0); STAGE_B(0, 0, 0); STAGE_B(0, 1, 0);
  STAGE_B(1, 0, 1); STAGE_B(1, 1, 1);
  VM4();
  PHASE_BAR();

  for(int i = 0; i < ni; i++){
    int t1 = 2 * i + 1;
    int t2 = (2 * i + 2 < nt) ? 2 * i + 2 : nt - 1;
    int t3 = (2 * i + 3 < nt) ? 2 * i + 3 : nt - 1;
    STAGE_A(1, 0, t1); STAGE_A(1, 1, t1);
    COMPUTE(0, 0);
    PHASE_BAR();
    STAGE_B(0, 0, t2);
    COMPUTE(0, 1);
    PHASE_BAR();
    STAGE_B(0, 1, t2);
    COMPUTE(0, 2);
    PHASE_BAR();
    COMPUTE(0, 3);
    VM4();
    PHASE_BAR();
    STAGE_A(0, 0, t2);
    COMPUTE(1, 0);
    PHASE_BAR();
    STAGE_A(0, 1, t2);
    COMPUTE(1, 1);
    PHASE_BAR();
    STAGE_B(1, 0, t3);
    COMPUTE(1, 2);
    PHASE_BAR();
    STAGE_B(1, 1, t3);
    COMPUTE(1, 3);
    VM4();
    PHASE_BAR();
  }
  asm volatile("s_waitcnt vmcnt(0)" ::: "memory");

  int cc = n0 + wn + (l & 15);
  int r4 = (l >> 4) << 2;
  #pragma unroll
  for(int ar = 0; ar < 8; ar++)
    #pragma unroll
    for(int nb = 0; nb < 4; nb++)
      #pragma unroll
      for(int r = 0; r < 4; r++){
        int row = m0 + wm + ar * 16 + r4 + r, col = cc + nb * 16;
        float v = acc[ar][nb][r];
        v = fmaxf(v, 0.f) * p1[col] + p2[col];
        Cb[(size_t)row * N + col] = f2b(v);
      }
}

// ---------------- bf16 MFMA GEMM (m97 structure) ----------------
template<int MODE>
__global__ __launch_bounds__(256) void gemm_bf16(
    const u16* __restrict__ A, const u16* __restrict__ Bt,
    float* __restrict__ Cf, u16* __restrict__ Cb,
    const float* __restrict__ p1, const float* __restrict__ p2,
    int M, int N, int K)
{
  constexpr int BM = 128, BN = 128, BK = 64;
  __shared__ alignas(16) u16 Al[BM * BK];
  __shared__ alignas(16) u16 Bl[BN * BK];
  int m0 = blockIdx.x * BM, n0 = blockIdx.y * BN;
  int t = threadIdx.x, w = t >> 6, l = t & 63;
  int wm = (w >> 1) * 64, wn = (w & 1) * 64;
  f32x4 acc[4][4];
  for(int a = 0; a < 4; a++) for(int b = 0; b < 4; b++) acc[a][b] = {0.f, 0.f, 0.f, 0.f};

  const short8* Ap = (const short8*)Al;
  const short8* Bp = (const short8*)Bl;

  for(int k0 = 0; k0 < K; k0 += BK){
    #pragma unroll
    for(int u = t; u < BM * 8; u += 256){
      int r = u >> 3, c = u & 7;
      gl_lds16(A + (size_t)(m0 + r) * K + k0 + ((c ^ (r & 7)) << 3), Al + u * 8);
    }
    #pragma unroll
    for(int u = t; u < BN * 8; u += 256){
      int r = u >> 3, c = u & 7;
      gl_lds16(Bt + (size_t)(n0 + r) * K + k0 + ((c ^ (r & 7)) << 3), Bl + u * 8);
    }
    __syncthreads();
    #pragma unroll
    for(int ks = 0; ks < 2; ks++){
      int kc = ks * 4 + (l >> 4);
      short8 av[4], bv[4];
      #pragma unroll
      for(int mi = 0; mi < 4; mi++){ int r = wm + mi * 16 + (l & 15); av[mi] = Ap[r * 8 + (kc ^ (r & 7))]; }
      #pragma unroll
      for(int ni = 0; ni < 4; ni++){ int r = wn + ni * 16 + (l & 15); bv[ni] = Bp[r * 8 + (kc ^ (r & 7))]; }
      #pragma unroll
      for(int mi = 0; mi < 4; mi++)
        #pragma unroll
        for(int ni = 0; ni < 4; ni++)
          acc[mi][ni] = __builtin_amdgcn_mfma_f32_16x16x32_bf16(av[mi], bv[ni], acc[mi][ni], 0, 0, 0);
    }
    __syncthreads();
  }

  int cr = m0 + wm + ((l >> 4) << 2);
  int cc = n0 + wn + (l & 15);
  for(int mi = 0; mi < 4; mi++)
    for(int ni = 0; ni < 4; ni++)
      for(int r = 0; r < 4; r++){
        int row = cr + mi * 16 + r, col = cc + ni * 16;
        float v = acc[mi][ni][r];
        if(MODE == 1){ v = fmaxf(v, 0.f) * p1[col] + p2[col]; Cb[(size_t)row * N + col] = f2b(v); }
        else if(MODE == 3){ Cb[(size_t)row * N + col] = f2b(v); }
        else { Cf[(size_t)row * N + col] = v; }
      }
}

// ---------------- split-K skinny GEMM (bf16 B), used for lin2 ----------------
__global__ __launch_bounds__(256) void gemm_sk(
    const u16* __restrict__ A, const u16* __restrict__ Bt, float* __restrict__ Cf,
    int N, int lda, int ldb, int kPer)
{
  constexpr int BM = 128, BN = 64, BK = 64;
  __shared__ alignas(16) u16 Al[BM * BK];
  __shared__ alignas(16) u16 Bl[BN * BK];
  int n0 = blockIdx.x * BN;
  int kb = blockIdx.y * kPer;
  float* C = Cf + (size_t)blockIdx.y * 128 * N;
  int t = threadIdx.x, w = t >> 6, l = t & 63;
  int wm = (w >> 1) * 64, wn = (w & 1) * 32;
  f32x4 acc[4][2];
  for(int a = 0; a < 4; a++) for(int b = 0; b < 2; b++) acc[a][b] = {0.f, 0.f, 0.f, 0.f};

  const short8* Ap = (const short8*)Al;
  const short8* Bp = (const short8*)Bl;

  for(int k0 = kb; k0 < kb + kPer; k0 += BK){
    #pragma unroll
    for(int u = t; u < BM * 8; u += 256){
      int r = u >> 3, c = u & 7;
      gl_lds16(A + (size_t)r * lda + k0 + ((c ^ (r & 7)) << 3), Al + u * 8);
    }
    #pragma unroll
    for(int u = t; u < BN * 8; u += 256){
      int r = u >> 3, c = u & 7;
      gl_lds16(Bt + (size_t)(n0 + r) * ldb + k0 + ((c ^ (r & 7)) << 3), Bl + u * 8);
    }
    __syncthreads();
    #pragma unroll
    for(int ks = 0; ks < 2; ks++){
      int kc = ks * 4 + (l >> 4);
      short8 av[4], bv[2];
      #pragma unroll
      for(int mi = 0; mi < 4; mi++){ int r = wm + mi * 16 + (l & 15); av[mi] = Ap[r * 8 + (kc ^ (r & 7))]; }
      #pragma unroll
      for(int ni = 0; ni < 2; ni++){ int r = wn + ni * 16 + (l & 15); bv[ni] = Bp[r * 8 + (kc ^ (r & 7))]; }
      #pragma unroll
      for(int mi = 0; mi < 4; mi++)
        #pragma unroll
        for(int ni = 0; ni < 2; ni++)
          acc[mi][ni] = __builtin_amdgcn_mfma_f32_16x16x32_bf16(av[mi], bv[ni], acc[mi][ni], 0, 0, 0);
    }
    __syncthreads();
  }

  int cr = wm + ((l >> 4) << 2);
  int cc = n0 + wn + (l & 15);
  for(int mi = 0; mi < 4; mi++)
    for(int ni = 0; ni < 2; ni++)
      for(int r = 0; r < 4; r++)
        C[(size_t)(cr + mi * 16 + r) * N + cc + ni * 16] = acc[mi][ni][r];
}

// ---------------- split-K skinny GEMM with f32 B (in-kernel bf16 conversion) ----------------
__global__ __launch_bounds__(256) void gemm_skf(
    const u16* __restrict__ A, const float* __restrict__ Wih, const float* __restrict__ Whh,
    float* __restrict__ Cf, int N, int lda, int Kih, int Khh, int kPer)
{
  constexpr int BM = 128, BN = 64, BK = 64;
  __shared__ alignas(16) u16 Al[BM * BK];
  __shared__ alignas(16) u16 Bl[BN * BK];
  int n0 = blockIdx.x * BN;
  int kb = blockIdx.y * kPer;
  float* C = Cf + (size_t)blockIdx.y * 128 * N;
  int t = threadIdx.x, w = t >> 6, l = t & 63;
  int wm = (w >> 1) * 64, wn = (w & 1) * 32;
  f32x4 acc[4][2];
  for(int a = 0; a < 4; a++) for(int b = 0; b < 2; b++) acc[a][b] = {0.f, 0.f, 0.f, 0.f};

  const short8* Ap = (const short8*)Al;
  const short8* Bp = (const short8*)Bl;

  for(int k0 = kb; k0 < kb + kPer; k0 += BK){
    #pragma unroll
    for(int u = t; u < BM * 8; u += 256){
      int r = u >> 3, c = u & 7;
      gl_lds16(A + (size_t)r * lda + k0 + ((c ^ (r & 7)) << 3), Al + u * 8);
    }
    #pragma unroll
    for(int u = t; u < BN * 8; u += 256){
      int r = u >> 3, c = u & 7;
      int gk = k0 + c * 8;
      const float* src = (gk < Kih) ? (Wih + (size_t)(n0 + r) * Kih + gk)
                                    : (Whh + (size_t)(n0 + r) * Khh + (gk - Kih));
      float4 v0 = *(const float4*)src;
      float4 v1 = *(const float4*)(src + 4);
      short8 ov;
      ov[0] = (short)f2b(v0.x); ov[1] = (short)f2b(v0.y); ov[2] = (short)f2b(v0.z); ov[3] = (short)f2b(v0.w);
      ov[4] = (short)f2b(v1.x); ov[5] = (short)f2b(v1.y); ov[6] = (short)f2b(v1.z); ov[7] = (short)f2b(v1.w);
      ((short8*)Bl)[r * 8 + (c ^ (r & 7))] = ov;
    }
    __syncthreads();
    #pragma unroll
    for(int ks = 0; ks < 2; ks++){
      int kc = ks * 4 + (l >> 4);
      short8 av[4], bv[2];
      #pragma unroll
      for(int mi = 0; mi < 4; mi++){ int r = wm + mi * 16 + (l & 15); av[mi] = Ap[r * 8 + (kc ^ (r & 7))]; }
      #pragma unroll
      for(int ni = 0; ni < 2; ni++){ int r = wn + ni * 16 + (l & 15); bv[ni] = Bp[r * 8 + (kc ^ (r & 7))]; }
      #pragma unroll
      for(int mi = 0; mi < 4; mi++)
        #pragma unroll
        for(int ni = 0; ni < 2; ni++)
          acc[mi][ni] = __builtin_amdgcn_mfma_f32_16x16x32_bf16(av[mi], bv[ni], acc[mi][ni], 0, 0, 0);
    }
    __syncthreads();
  }

  int cr = wm + ((l >> 4) << 2);
  int cc = n0 + wn + (l & 15);
  for(int mi = 0; mi < 4; mi++)
    for(int ni = 0; ni < 2; ni++)
      for(int r = 0; r < 4; r++)
        C[(size_t)(cr + mi * 16 + r) * N + cc + ni * 16] = acc[mi][ni][r];
}

// ---------------- GAT v3: scores + reg-resident softmax + VALU aggregate ----------------
__global__ __launch_bounds__(256) void gat_attn2(const u64* __restrict__ adjm,
    const u16* __restrict__ h,
    const float* __restrict__ as1, const float* __restrict__ ad1,
    const float* __restrict__ as2, const float* __restrict__ ad2,
    const float* __restrict__ b1, const float* __restrict__ b2,
    u16* __restrict__ x2b){
  int b = blockIdx.x;
  int cv = blockIdx.y >> 3, hh = blockIdx.y & 7;
  __shared__ float hst[64][64];
  __shared__ float esl[64], edl[64];
  __shared__ u64 adjs[64];
  int t = threadIdx.x, w = t >> 6, l = t & 63;
  {
    int j = t >> 2, d0 = (t & 3) * 16;
    const u16* hr = h + (size_t)(b * 64 + j) * 1024 + cv * 512 + hh * 64 + d0;
    #pragma unroll
    for(int k = 0; k < 16; k++) hst[j][d0 + k] = b2f(hr[k]);
  }
  if(t < 64) adjs[t] = adjm[b * 64 + t];
  __syncthreads();
  // scores es/ed from staged tile (lane l = dim d)
  float aSl = ((cv ? as2 : as1) + hh * 64)[l];
  float aDl = ((cv ? ad2 : ad1) + hh * 64)[l];
  for(int it = 0; it < 16; it++){
    int j = it * 4 + w;
    float v = hst[j][l];
    float ps = v * aSl, pd = v * aDl;
    for(int o = 32; o; o >>= 1){ ps += __shfl_xor(ps, o); pd += __shfl_xor(pd, o); }
    if(l == 0){ esl[j] = ps; edl[j] = pd; }
  }
  __syncthreads();
  // per-row softmax; alpha kept in registers (lane = neighbor j, row i = it*4+w)
  float alphaR[16];
  #pragma unroll
  for(int it = 0; it < 16; it++){
    int i = it * 4 + w;
    bool on = (adjs[i] >> l) & 1;
    float e = edl[i] + esl[l];
    e = e > 0.f ? e : 0.2f * e;
    float mx = on ? e : -1e30f;
    for(int o = 32; o; o >>= 1) mx = fmaxf(mx, __shfl_xor(mx, o));
    float p = on ? __expf(e - mx) : 0.f;
    float s = p;
    for(int o = 32; o; o >>= 1) s += __shfl_xor(s, o);
    alphaR[it] = p / s;
  }
  // aggregate on VALU: lane = column d; alpha broadcast via readlane (bit-preserving)
  float accv[16];
  #pragma unroll
  for(int k = 0; k < 16; k++) accv[k] = 0.f;
  #pragma unroll
  for(int j = 0; j < 64; j++){
    float hv = hst[j][l];
    #pragma unroll
    for(int it = 0; it < 16; it++){
      float av = __uint_as_float(__builtin_amdgcn_readlane(__float_as_uint(alphaR[it]), j));
      accv[it] += av * hv;
    }
  }
  float bl = ((cv ? b2 : b1) + hh * 64)[l];
  #pragma unroll
  for(int it = 0; it < 16; it++){
    int i = it * 4 + w;
    x2b[(size_t)(b * 64 + i) * 1024 + cv * 512 + hh * 64 + l] = f2b(fmaxf(accv[it] + bl, 0.f));
  }
}

// ---------------- Set2Set step-0 shortcut ----------------
__global__ __launch_bounds__(256) void s2s0_gemv(const float* __restrict__ Wih1,
    const float* __restrict__ lb1, const float* __restrict__ lb0, float* __restrict__ z1u){
  __shared__ float hs[1024];
  int t = threadIdx.x;
  for(int i = t; i < 1024; i += 256){
    float zi = lb0[i], zg = lb0[2048 + i], zo = lb0[3072 + i];
    float cn = (1.f / (1.f + __expf(-zi))) * tanhf(zg);
    hs[i] = (1.f / (1.f + __expf(-zo))) * tanhf(cn);
  }
  __syncthreads();
  int w = t >> 6, l = t & 63;
  int r = blockIdx.x * 4 + w;
  const float* wr = Wih1 + (size_t)r * 1024;
  float s = 0.f;
  #pragma unroll
  for(int k = 0; k < 16; k++) s += wr[l + 64 * k] * hs[l + 64 * k];
  for(int o = 32; o; o >>= 1) s += __shfl_xor(s, o);
  if(l == 0) z1u[r] = s + lb1[r];
}

// ---------------- LSTM gates (sum ns split-K partials) ----------------
__global__ void lstm_gate0(const float* __restrict__ zp, const float* __restrict__ lb,
                           float* __restrict__ c, u16* __restrict__ ac0, u16* __restrict__ ac1,
                           int ns){
  int t = blockIdx.x * 256 + threadIdx.x;
  int b = t >> 10, j = t & 1023;
  size_t base = (size_t)b * 4096;
  float zi = 0, zf = 0, zg = 0, zo = 0;
  for(int s = 0; s < ns; s++){
    const float* zr = zp + (size_t)s * 524288 + base;
    zi += zr[j]; zf += zr[1024 + j]; zg += zr[2048 + j]; zo += zr[3072 + j];
  }
  zi += lb[j]; zf += lb[1024 + j]; zg += lb[2048 + j]; zo += lb[3072 + j];
  float ci = c[t];
  float si = 1.f / (1.f + __expf(-zi)), sf = 1.f / (1.f + __expf(-zf)), so = 1.f / (1.f + __expf(-zo));
  float cn = sf * ci + si * tanhf(zg);
  c[t] = cn;
  u16 hb = f2b(so * tanhf(cn));
  ac0[(size_t)b * 3072 + 2048 + j] = hb;
  ac1[(size_t)b * 2048 + j] = hb;
}

__global__ void lstm_gate1(const float* __restrict__ zp, const float* __restrict__ lb,
                           float* __restrict__ c, float* __restrict__ h1f,
                           u16* __restrict__ ac1, u16* __restrict__ ac0, int ns){
  int t = blockIdx.x * 256 + threadIdx.x;
  int b = t >> 10, j = t & 1023;
  size_t base = (size_t)b * 4096;
  float zi = 0, zf = 0, zg = 0, zo = 0;
  for(int s = 0; s < ns; s++){
    const float* zr = zp + (size_t)s * 524288 + base;
    zi += zr[j]; zf += zr[1024 + j]; zg += zr[2048 + j]; zo += zr[3072 + j];
  }
  zi += lb[j]; zf += lb[1024 + j]; zg += lb[2048 + j]; zo += lb[3072 + j];
  float ci = c[t];
  float si = 1.f / (1.f + __expf(-zi)), sf = 1.f / (1.f + __expf(-zf)), so = 1.f / (1.f + __expf(-zo));
  float cn = sf * ci + si * tanhf(zg);
  c[t] = cn;
  float hn = so * tanhf(cn);
  h1f[t] = hn;
  u16 hb = f2b(hn);
  ac1[(size_t)b * 2048 + 1024 + j] = hb;
  ac0[(size_t)b * 3072 + j] = hb;
}

// ---------------- Set2Set attention (bf16 x2) ----------------
template<int STEP>
__global__ __launch_bounds__(256) void s2s_e(const u16* __restrict__ x2b,
    const float* __restrict__ h1, const float* __restrict__ z1u, float* __restrict__ e){
  __shared__ float h1s[1024];
  int t = threadIdx.x, w = t >> 6, l = t & 63;
  int node = blockIdx.x * 4 + w;
  int b = node >> 6;
  for(int i = t; i < 1024; i += 256){
    if(STEP == 0){
      float zi = z1u[i], zg = z1u[2048 + i], zo = z1u[3072 + i];
      float cn = (1.f / (1.f + __expf(-zi))) * tanhf(zg);
      h1s[i] = (1.f / (1.f + __expf(-zo))) * tanhf(cn);
    } else {
      h1s[i] = h1[(size_t)b * 1024 + i];
    }
  }
  __syncthreads();
  const u16* xr = x2b + (size_t)node * 1024;
  float s = 0.f;
  #pragma unroll
  for(int k = 0; k < 16; k++){
    int d = k * 64 + l;
    s += b2f(xr[d]) * h1s[d];
  }
  for(int o = 32; o; o >>= 1) s += __shfl_xor(s, o);
  if(l == 0) e[node] = s;
}

template<int STEP>
__global__ __launch_bounds__(256) void s2s_r(const u16* __restrict__ x2b,
    const float* __restrict__ e, u16* __restrict__ ac0,
    const float* __restrict__ lb0, const float* __restrict__ z1u,
    u16* __restrict__ ac1, float* __restrict__ c0b, float* __restrict__ c1b){
  int b = blockIdx.x, sl = blockIdx.y;
  __shared__ float al[64];
  int t = threadIdx.x;
  if(t < 64){
    float v = e[b * 64 + t];
    float mx = v;
    for(int o = 32; o; o >>= 1) mx = fmaxf(mx, __shfl_xor(mx, o));
    float p = __expf(v - mx);
    float ss = p;
    for(int o = 32; o; o >>= 1) ss += __shfl_xor(ss, o);
    al[t] = p / ss;
  }
  __syncthreads();
  int d = sl * 256 + t;
  const u16* xp = x2b + (size_t)b * 65536 + d;
  float r = 0.f;
  #pragma unroll 8
  for(int j = 0; j < 64; j++) r += al[j] * b2f(xp[j * 1024]);
  ac0[(size_t)b * 3072 + 1024 + d] = f2b(r);
  if(STEP == 0){
    float zi0 = lb0[d], zg0 = lb0[2048 + d], zo0 = lb0[3072 + d];
    float c0 = (1.f / (1.f + __expf(-zi0))) * tanhf(zg0);
    float h0 = (1.f / (1.f + __expf(-zo0))) * tanhf(c0);
    float zi1 = z1u[d], zg1 = z1u[2048 + d], zo1 = z1u[3072 + d];
    float c1 = (1.f / (1.f + __expf(-zi1))) * tanhf(zg1);
    float h1 = (1.f / (1.f + __expf(-zo1))) * tanhf(c1);
    c0b[(size_t)b * 1024 + d] = c0;
    c1b[(size_t)b * 1024 + d] = c1;
    u16 h0b = f2b(h0), h1b = f2b(h1);
    ac0[(size_t)b * 3072 + d] = h1b;
    ac0[(size_t)b * 3072 + 2048 + d] = h0b;
    ac1[(size_t)b * 2048 + d] = h0b;
    ac1[(size_t)b * 2048 + 1024 + d] = h1b;
  }
}

// ---------------- lin2 combine (8 split partials) + bn + relu + lin3 ----------------
__global__ __launch_bounds__(256) void lin3(const float* __restrict__ zp2,
    const float* __restrict__ sc2, const float* __restrict__ sh2,
    const float* __restrict__ W3, const float* __restrict__ b3, float* __restrict__ out){
  int b = blockIdx.x;
  __shared__ float yl[1024];
  int t = threadIdx.x, w = t >> 6, l = t & 63;
  for(int d = t; d < 1024; d += 256){
    float v = 0.f;
    for(int s = 0; s < 8; s++) v += zp2[(size_t)s * 131072 + b * 1024 + d];
    yl[d] = fmaxf(v, 0.f) * sc2[d] + sh2[d];
  }
  __syncthreads();
  for(int n = w; n < 10; n += 4){
    float s = 0.f;
    for(int d = l; d < 1024; d += 64) s += yl[d] * W3[d * 10 + n];
    for(int o = 32; o; o >>= 1) s += __shfl_xor(s, o);
    if(l == 0) out[b * 10 + n] = s + b3[n];
  }
}

extern "C" void kernel_launch(void* const* d_in, const int* in_sizes, int n_in,
                              void* d_out, int out_size, void* d_ws, size_t ws_size,
                              hipStream_t stream){
  const float* x    = (const float*)d_in[0];
  const float* pos  = (const float*)d_in[1];
  const float* W0   = (const float*)d_in[3];
  const float* bn0g = (const float*)d_in[4];
  const float* bn0b = (const float*)d_in[5];
  const float* bn0m = (const float*)d_in[6];
  const float* bn0v = (const float*)d_in[7];
  const float* Wg1  = (const float*)d_in[8];
  const float* as1  = (const float*)d_in[9];
  const float* ad1  = (const float*)d_in[10];
  const float* b1   = (const float*)d_in[11];
  const float* Wg2  = (const float*)d_in[12];
  const float* as2  = (const float*)d_in[13];
  const float* ad2  = (const float*)d_in[14];
  const float* b2   = (const float*)d_in[15];
  const float* Wih0 = (const float*)d_in[16];
  const float* Whh0 = (const float*)d_in[17];
  const float* bih0 = (const float*)d_in[18];
  const float* bhh0 = (const float*)d_in[19];
  const float* Wih1 = (const float*)d_in[20];
  const float* Whh1 = (const float*)d_in[21];
  const float* bih1 = (const float*)d_in[22];
  const float* bhh1 = (const float*)d_in[23];
  const float* W2   = (const float*)d_in[24];
  const float* bn2g = (const float*)d_in[25];
  const float* bn2b = (const float*)d_in[26];
  const float* bn2m = (const float*)d_in[27];
  const float* bn2v = (const float*)d_in[28];
  const float* W3   = (const float*)d_in[29];
  const float* b3   = (const float*)d_in[30];

  char* ws = (char*)d_ws;
  u16*   xbf  = (u16*)(ws + O_XBF);
  u16*   x2b  = (u16*)(ws + O_XBF);
  u16*   w0t  = (u16*)(ws + O_W0T);
  u16*   wgt  = (u16*)(ws + O_WGT);
  u16*   w2t  = (u16*)(ws + O_W2T);
  u16*   xb   = (u16*)(ws + O_XB);
  u16*   hb   = (u16*)(ws + O_H);
  u64*   adjm = (u64*)(ws + O_ADJ);
  float* sc0  = (float*)(ws + O_SC0);
  float* sh0  = (float*)(ws + O_SH0);
  float* sc2  = (float*)(ws + O_SC2);
  float* sh2  = (float*)(ws + O_SH2);
  float* lb0  = (float*)(ws + O_LB0);
  float* lb1  = (float*)(ws + O_LB1);
  char*  s2sb = ws + O_H;
  u16*   ac0  = (u16*)(s2sb + S_AC0);
  u16*   ac1  = (u16*)(s2sb + S_AC1);
  float* c0b  = (float*)(s2sb + S_C0);
  float* c1b  = (float*)(s2sb + S_C1);
  float* h1f  = (float*)(s2sb + S_H1F);
  float* zp   = (float*)(s2sb + S_ZP);
  float* ebuf = (float*)(s2sb + S_E);
  float* z1u  = (float*)(s2sb + S_Z1U);

  setup_all<<<16432, 256, 0, stream>>>(x, W0, Wg1, Wg2, W2,
                                       bn0g, bn0b, bn0m, bn0v, bn2g, bn2b, bn2m, bn2v,
                                       bih0, bhh0, bih1, bhh1, pos,
                                       xbf, w0t, wgt, w2t, sc0, sh0, sc2, sh2, lb0, lb1, adjm);

  gemm8p<<<dim3(32, 8), 512, 0, stream>>>(xbf, w0t, xb, sc0, sh0, 8192, 2048, 2048);
  gemm_bf16<3><<<dim3(64, 8), 256, 0, stream>>>(xb, wgt, nullptr, hb, nullptr, nullptr, 8192, 1024, 2048);
  gat_attn2<<<dim3(128, 16), 256, 0, stream>>>(adjm, hb, as1, ad1, as2, ad2, b1, b2, x2b);

  s2s0_gemv<<<1024, 256, 0, stream>>>(Wih1, lb1, lb0, z1u);
  s2s_e<0><<<2048, 256, 0, stream>>>(x2b, nullptr, z1u, ebuf);
  s2s_r<0><<<dim3(128, 4), 256, 0, stream>>>(x2b, ebuf, ac0, lb0, z1u, ac1, c0b, c1b);

  gemm_skf<<<dim3(64, 8), 256, 0, stream>>>(ac0, Wih0, Whh0, zp, 4096, 3072, 2048, 1024, 384);
  lstm_gate0<<<512, 256, 0, stream>>>(zp, lb0, c0b, ac0, ac1, 8);
  gemm_skf<<<dim3(64, 8), 256, 0, stream>>>(ac1, Wih1, Whh1, zp, 4096, 2048, 1024, 1024, 256);
  lstm_gate1<<<512, 256, 0, stream>>>(zp, lb1, c1b, h1f, ac1, ac0, 8);
  s2s_e<1><<<2048, 256, 0, stream>>>(x2b, h1f, nullptr, ebuf);
  s2s_r<1><<<dim3(128, 4), 256, 0, stream>>>(x2b, ebuf, ac0, nullptr, nullptr, nullptr, nullptr, nullptr);

  gemm_sk<<<dim3(16, 8), 256, 0, stream>>>(ac0, w2t, zp, 1024, 3072, 2048, 256);
  lin3<<<128, 256, 0, stream>>>(zp, sc2, sh2, W3, b3, (float*)d_out);
}

// Round 15
// 277.067 us; speedup vs baseline: 5.7518x; 1.0039x over previous
//
#include <hip/hip_runtime.h>
#include <hip/hip_bf16.h>

typedef unsigned short u16;
typedef __attribute__((ext_vector_type(8))) short short8;
typedef __attribute__((ext_vector_type(4))) float f32x4;
typedef unsigned long long u64;

#define DI __device__ __forceinline__

DI u16 f2b(float f){
  unsigned u = __float_as_uint(f);
  unsigned r = 0x7fffu + ((u >> 16) & 1u);
  return (u16)((u + r) >> 16);
}
DI float b2f(u16 u){ return __uint_as_float((unsigned)u << 16); }

DI void gl_lds16(const void* g, void* l){
  __builtin_amdgcn_global_load_lds((const __attribute__((address_space(1))) void*)g,
                                   (__attribute__((address_space(3))) void*)l, 16, 0, 0);
}

// ---------------- workspace layout (bytes) ----------------
constexpr size_t O_XBF = 0;
constexpr size_t O_W0T = O_XBF + 33554432;
constexpr size_t O_WGT = O_W0T + 8388608;
constexpr size_t O_W2T = O_WGT + 4194304;
constexpr size_t O_XB  = O_W2T + 4194304;
constexpr size_t O_H   = O_XB  + 33554432;
constexpr size_t O_ES  = O_H   + 33554432;
constexpr size_t O_ED  = O_ES  + 524288;
constexpr size_t O_ADJ = O_ED  + 524288;
constexpr size_t O_SC0 = O_ADJ + 65536;
constexpr size_t O_SH0 = O_SC0 + 8192;
constexpr size_t O_SC2 = O_SH0 + 8192;
constexpr size_t O_SH2 = O_SC2 + 4096;
constexpr size_t O_LB0 = O_SH2 + 4096;
constexpr size_t O_LB1 = O_LB0 + 16384;
constexpr size_t S_AC0 = 0;
constexpr size_t S_AC1 = S_AC0 + 786432;
constexpr size_t S_C0  = S_AC1 + 524288;
constexpr size_t S_C1  = S_C0  + 524288;
constexpr size_t S_H1F = S_C1  + 524288;
constexpr size_t S_ZP  = S_H1F + 524288;
constexpr size_t S_E   = S_ZP  + 16777216;
constexpr size_t S_Z1U = S_E   + 32768;

// ---------------- one setup kernel: x cvt + 4 transposes + prep + adjacency ----------------
__global__ __launch_bounds__(256) void setup_all(
    const float* __restrict__ x,
    const float* __restrict__ W0, const float* __restrict__ Wg1,
    const float* __restrict__ Wg2, const float* __restrict__ W2,
    const float* __restrict__ g0, const float* __restrict__ b0, const float* __restrict__ m0, const float* __restrict__ v0,
    const float* __restrict__ g2, const float* __restrict__ b2, const float* __restrict__ m2, const float* __restrict__ v2,
    const float* __restrict__ bih0, const float* __restrict__ bhh0,
    const float* __restrict__ bih1, const float* __restrict__ bhh1,
    const float* __restrict__ pos,
    u16* __restrict__ xbf, u16* __restrict__ w0t, u16* __restrict__ wgt, u16* __restrict__ w2t,
    float* __restrict__ sc0, float* __restrict__ sh0, float* __restrict__ sc2, float* __restrict__ sh2,
    float* __restrict__ lb0, float* __restrict__ lb1, u64* __restrict__ adjm)
{
  __shared__ float tile[32][33];
  __shared__ float px[4][64], py[4][64];
  int bx = blockIdx.x, t = threadIdx.x;
  if(bx < 8192){
    int idx = bx * 256 + t;
    int r = idx >> 8, c8 = (idx & 255) << 3;
    const float* src = x + (size_t)r * 2048 + c8;
    float4 v0 = *(const float4*)src;
    float4 v1 = *(const float4*)(src + 4);
    short8 ov;
    ov[0] = (short)f2b(v0.x); ov[1] = (short)f2b(v0.y); ov[2] = (short)f2b(v0.z); ov[3] = (short)f2b(v0.w);
    ov[4] = (short)f2b(v1.x); ov[5] = (short)f2b(v1.y); ov[6] = (short)f2b(v1.z); ov[7] = (short)f2b(v1.w);
    *(short8*)(xbf + (size_t)r * 2048 + c8) = ov;
  } else if(bx < 16384){
    int bx2 = bx - 8192;
    int cx = bx2 & 127, by = bx2 >> 7;
    const float* src; u16* dst; int C, droff;
    if(cx < 64){      src = W0;  dst = w0t; C = 2048; droff = 0; }
    else if(cx < 80){ src = Wg1; dst = wgt; C = 512;  droff = 0;   cx -= 64; }
    else if(cx < 96){ src = Wg2; dst = wgt; C = 512;  droff = 512; cx -= 80; }
    else {            src = W2;  dst = w2t; C = 1024; droff = 0;   cx -= 96; }
    int c0 = cx * 32, r0 = by * 32;
    int tx = t & 31, ty = t >> 5;
    for(int i = 0; i < 4; i++)
      tile[ty + 8*i][tx] = src[(size_t)(r0 + ty + 8*i) * C + c0 + tx];
    __syncthreads();
    for(int i = 0; i < 4; i++)
      dst[(size_t)(droff + c0 + ty + 8*i) * 2048 + r0 + tx] = f2b(tile[tx][ty + 8*i]);
  } else if(bx < 16400){
    int tt = (bx - 16384) * 256 + t;
    if(tt < 2048){ float s = g0[tt] * rsqrtf(v0[tt] + 0.1f); sc0[tt] = s; sh0[tt] = b0[tt] - m0[tt] * s; }
    if(tt < 1024){ float s = g2[tt] * rsqrtf(v2[tt] + 0.1f); sc2[tt] = s; sh2[tt] = b2[tt] - m2[tt] * s; }
    lb0[tt] = bih0[tt] + bhh0[tt];
    lb1[tt] = bih1[tt] + bhh1[tt];
  } else {
    int w = t >> 6, l = t & 63;
    int g = (bx - 16400) * 4 + w;
    float2 p = ((const float2*)pos)[g * 64 + l];
    px[w][l] = p.x; py[w][l] = p.y;
    __syncthreads();
    float xi = p.x, yi = p.y;
    u64 m = 0;
    for(int j = 0; j < 64; j++){
      float dx = xi - px[w][j], dy = yi - py[w][j];
      if(dx * dx + dy * dy <= 16.0f) m |= (1ull << j);
    }
    adjm[g * 64 + l] = m;
  }
}

// ---------------- 256x256 8-phase counted-vmcnt GEMM (GEMM1) ----------------
#define STAGE_A(buf, half, kt)                                                        \
  { _Pragma("unroll")                                                                 \
    for(int ld = 0; ld < 2; ld++){                                                    \
      int u = ld * 512 + t;                                                           \
      int r = (u >> 3) + (half) * 128, c = u & 7;                                     \
      gl_lds16(A + (size_t)(m0 + r) * K + (kt) * 64 + ((c ^ (r & 7)) << 3),           \
               LA + (buf) * 16384 + ((half) * 1024 + u) * 8);                         \
    } }
#define STAGE_B(buf, half, kt)                                                        \
  { _Pragma("unroll")                                                                 \
    for(int ld = 0; ld < 2; ld++){                                                    \
      int u = ld * 512 + t;                                                           \
      int r = (u >> 3) + (half) * 128, c = u & 7;                                     \
      gl_lds16(Bt + (size_t)(n0 + r) * K + (kt) * 64 + ((c ^ (r & 7)) << 3),          \
               LB + (buf) * 16384 + ((half) * 1024 + u) * 8);                         \
    } }
#define COMPUTE(buf, q)                                                               \
  { if((q) == 0){                                                                     \
      _Pragma("unroll")                                                               \
      for(int nb = 0; nb < 4; nb++)                                                   \
        _Pragma("unroll")                                                             \
        for(int k2 = 0; k2 < 2; k2++){                                                \
          int col = wn + nb * 16 + (l & 15);                                          \
          int kc = k2 * 4 + (l >> 4);                                                 \
          bfr[nb][k2] = Bp[(buf) * 2048 + col * 8 + (kc ^ (col & 7))];                \
        }                                                                             \
    }                                                                                 \
    short8 af[2][2];                                                                  \
    _Pragma("unroll")                                                                 \
    for(int rb = 0; rb < 2; rb++)                                                     \
      _Pragma("unroll")                                                               \
      for(int k2 = 0; k2 < 2; k2++){                                                  \
        int row = wm + (q) * 32 + rb * 16 + (l & 15);                                 \
        int kc = k2 * 4 + (l >> 4);                                                   \
        af[rb][k2] = Ap[(buf) * 2048 + row * 8 + (kc ^ (row & 7))];                   \
      }                                                                               \
    __builtin_amdgcn_s_setprio(1);                                                    \
    _Pragma("unroll")                                                                 \
    for(int rb = 0; rb < 2; rb++)                                                     \
      _Pragma("unroll")                                                               \
      for(int nb = 0; nb < 4; nb++)                                                   \
        _Pragma("unroll")                                                             \
        for(int k2 = 0; k2 < 2; k2++)                                                 \
          acc[(q) * 2 + rb][nb] = __builtin_amdgcn_mfma_f32_16x16x32_bf16(            \
              af[rb][k2], bfr[nb][k2], acc[(q) * 2 + rb][nb], 0, 0, 0);               \
    __builtin_amdgcn_s_setprio(0);                                                    \
  }
#define PHASE_BAR() { __builtin_amdgcn_s_barrier(); __builtin_amdgcn_sched_barrier(0); }
#define VM4() { asm volatile("s_waitcnt vmcnt(4)" ::: "memory"); __builtin_amdgcn_sched_barrier(0); }

__global__ __launch_bounds__(512, 2) void gemm8p(
    const u16* __restrict__ A, const u16* __restrict__ Bt, u16* __restrict__ Cb,
    const float* __restrict__ p1, const float* __restrict__ p2,
    int M, int N, int K)
{
  __shared__ alignas(16) u16 LA[2 * 16384];
  __shared__ alignas(16) u16 LB[2 * 16384];
  int m0 = blockIdx.x * 256, n0 = blockIdx.y * 256;
  int t = threadIdx.x, w = t >> 6, l = t & 63;
  int wm = (w >> 2) * 128, wn = (w & 3) * 64;
  int nt = K >> 6, ni = nt >> 1;
  f32x4 acc[8][4];
  #pragma unroll
  for(int a = 0; a < 8; a++)
    #pragma unroll
    for(int b = 0; b < 4; b++) acc[a][b] = {0.f, 0.f, 0.f, 0.f};
  short8 bfr[4][2];
  const short8* Ap = (const short8*)LA;
  const short8* Bp = (const short8*)LB;

  STAGE_A(0, 0, 0); STAGE_A(0, 1, 0); STAGE_B(0, 0, 0); STAGE_B(0, 1, 0);
  STAGE_B(1, 0, 1); STAGE_B(1, 1, 1);
  VM4();
  PHASE_BAR();

  for(int i = 0; i < ni; i++){
    int t1 = 2 * i + 1;
    int t2 = (2 * i + 2 < nt) ? 2 * i + 2 : nt - 1;
    int t3 = (2 * i + 3 < nt) ? 2 * i + 3 : nt - 1;
    STAGE_A(1, 0, t1); STAGE_A(1, 1, t1);
    COMPUTE(0, 0);
    PHASE_BAR();
    STAGE_B(0, 0, t2);
    COMPUTE(0, 1);
    PHASE_BAR();
    STAGE_B(0, 1, t2);
    COMPUTE(0, 2);
    PHASE_BAR();
    COMPUTE(0, 3);
    VM4();
    PHASE_BAR();
    STAGE_A(0, 0, t2);
    COMPUTE(1, 0);
    PHASE_BAR();
    STAGE_A(0, 1, t2);
    COMPUTE(1, 1);
    PHASE_BAR();
    STAGE_B(1, 0, t3);
    COMPUTE(1, 2);
    PHASE_BAR();
    STAGE_B(1, 1, t3);
    COMPUTE(1, 3);
    VM4();
    PHASE_BAR();
  }
  asm volatile("s_waitcnt vmcnt(0)" ::: "memory");

  int cc = n0 + wn + (l & 15);
  int r4 = (l >> 4) << 2;
  #pragma unroll
  for(int ar = 0; ar < 8; ar++)
    #pragma unroll
    for(int nb = 0; nb < 4; nb++)
      #pragma unroll
      for(int r = 0; r < 4; r++){
        int row = m0 + wm + ar * 16 + r4 + r, col = cc + nb * 16;
        float v = acc[ar][nb][r];
        v = fmaxf(v, 0.f) * p1[col] + p2[col];
        Cb[(size_t)row * N + col] = f2b(v);
      }
}

// ---------------- bf16 MFMA GEMM (m97 structure) ----------------
template<int MODE>
__global__ __launch_bounds__(256) void gemm_bf16(
    const u16* __restrict__ A, const u16* __restrict__ Bt,
    float* __restrict__ Cf, u16* __restrict__ Cb,
    const float* __restrict__ p1, const float* __restrict__ p2,
    int M, int N, int K)
{
  constexpr int BM = 128, BN = 128, BK = 64;
  __shared__ alignas(16) u16 Al[BM * BK];
  __shared__ alignas(16) u16 Bl[BN * BK];
  int m0 = blockIdx.x * BM, n0 = blockIdx.y * BN;
  int t = threadIdx.x, w = t >> 6, l = t & 63;
  int wm = (w >> 1) * 64, wn = (w & 1) * 64;
  f32x4 acc[4][4];
  for(int a = 0; a < 4; a++) for(int b = 0; b < 4; b++) acc[a][b] = {0.f, 0.f, 0.f, 0.f};

  const short8* Ap = (const short8*)Al;
  const short8* Bp = (const short8*)Bl;

  for(int k0 = 0; k0 < K; k0 += BK){
    #pragma unroll
    for(int u = t; u < BM * 8; u += 256){
      int r = u >> 3, c = u & 7;
      gl_lds16(A + (size_t)(m0 + r) * K + k0 + ((c ^ (r & 7)) << 3), Al + u * 8);
    }
    #pragma unroll
    for(int u = t; u < BN * 8; u += 256){
      int r = u >> 3, c = u & 7;
      gl_lds16(Bt + (size_t)(n0 + r) * K + k0 + ((c ^ (r & 7)) << 3), Bl + u * 8);
    }
    __syncthreads();
    #pragma unroll
    for(int ks = 0; ks < 2; ks++){
      int kc = ks * 4 + (l >> 4);
      short8 av[4], bv[4];
      #pragma unroll
      for(int mi = 0; mi < 4; mi++){ int r = wm + mi * 16 + (l & 15); av[mi] = Ap[r * 8 + (kc ^ (r & 7))]; }
      #pragma unroll
      for(int ni = 0; ni < 4; ni++){ int r = wn + ni * 16 + (l & 15); bv[ni] = Bp[r * 8 + (kc ^ (r & 7))]; }
      #pragma unroll
      for(int mi = 0; mi < 4; mi++)
        #pragma unroll
        for(int ni = 0; ni < 4; ni++)
          acc[mi][ni] = __builtin_amdgcn_mfma_f32_16x16x32_bf16(av[mi], bv[ni], acc[mi][ni], 0, 0, 0);
    }
    __syncthreads();
  }

  int cr = m0 + wm + ((l >> 4) << 2);
  int cc = n0 + wn + (l & 15);
  for(int mi = 0; mi < 4; mi++)
    for(int ni = 0; ni < 4; ni++)
      for(int r = 0; r < 4; r++){
        int row = cr + mi * 16 + r, col = cc + ni * 16;
        float v = acc[mi][ni][r];
        if(MODE == 1){ v = fmaxf(v, 0.f) * p1[col] + p2[col]; Cb[(size_t)row * N + col] = f2b(v); }
        else if(MODE == 3){ Cb[(size_t)row * N + col] = f2b(v); }
        else { Cf[(size_t)row * N + col] = v; }
      }
}

// ---------------- split-K skinny GEMM (bf16 B), used for lin2 ----------------
__global__ __launch_bounds__(256) void gemm_sk(
    const u16* __restrict__ A, const u16* __restrict__ Bt, float* __restrict__ Cf,
    int N, int lda, int ldb, int kPer)
{
  constexpr int BM = 128, BN = 64, BK = 64;
  __shared__ alignas(16) u16 Al[BM * BK];
  __shared__ alignas(16) u16 Bl[BN * BK];
  int n0 = blockIdx.x * BN;
  int kb = blockIdx.y * kPer;
  float* C = Cf + (size_t)blockIdx.y * 128 * N;
  int t = threadIdx.x, w = t >> 6, l = t & 63;
  int wm = (w >> 1) * 64, wn = (w & 1) * 32;
  f32x4 acc[4][2];
  for(int a = 0; a < 4; a++) for(int b = 0; b < 2; b++) acc[a][b] = {0.f, 0.f, 0.f, 0.f};

  const short8* Ap = (const short8*)Al;
  const short8* Bp = (const short8*)Bl;

  for(int k0 = kb; k0 < kb + kPer; k0 += BK){
    #pragma unroll
    for(int u = t; u < BM * 8; u += 256){
      int r = u >> 3, c = u & 7;
      gl_lds16(A + (size_t)r * lda + k0 + ((c ^ (r & 7)) << 3), Al + u * 8);
    }
    #pragma unroll
    for(int u = t; u < BN * 8; u += 256){
      int r = u >> 3, c = u & 7;
      gl_lds16(Bt + (size_t)(n0 + r) * ldb + k0 + ((c ^ (r & 7)) << 3), Bl + u * 8);
    }
    __syncthreads();
    #pragma unroll
    for(int ks = 0; ks < 2; ks++){
      int kc = ks * 4 + (l >> 4);
      short8 av[4], bv[2];
      #pragma unroll
      for(int mi = 0; mi < 4; mi++){ int r = wm + mi * 16 + (l & 15); av[mi] = Ap[r * 8 + (kc ^ (r & 7))]; }
      #pragma unroll
      for(int ni = 0; ni < 2; ni++){ int r = wn + ni * 16 + (l & 15); bv[ni] = Bp[r * 8 + (kc ^ (r & 7))]; }
      #pragma unroll
      for(int mi = 0; mi < 4; mi++)
        #pragma unroll
        for(int ni = 0; ni < 2; ni++)
          acc[mi][ni] = __builtin_amdgcn_mfma_f32_16x16x32_bf16(av[mi], bv[ni], acc[mi][ni], 0, 0, 0);
    }
    __syncthreads();
  }

  int cr = wm + ((l >> 4) << 2);
  int cc = n0 + wn + (l & 15);
  for(int mi = 0; mi < 4; mi++)
    for(int ni = 0; ni < 2; ni++)
      for(int r = 0; r < 4; r++)
        C[(size_t)(cr + mi * 16 + r) * N + cc + ni * 16] = acc[mi][ni][r];
}

// ---------------- split-K skinny GEMM with f32 B (in-kernel bf16 conversion) ----------------
__global__ __launch_bounds__(256) void gemm_skf(
    const u16* __restrict__ A, const float* __restrict__ Wih, const float* __restrict__ Whh,
    float* __restrict__ Cf, int N, int lda, int Kih, int Khh, int kPer)
{
  constexpr int BM = 128, BN = 64, BK = 64;
  __shared__ alignas(16) u16 Al[BM * BK];
  __shared__ alignas(16) u16 Bl[BN * BK];
  int n0 = blockIdx.x * BN;
  int kb = blockIdx.y * kPer;
  float* C = Cf + (size_t)blockIdx.y * 128 * N;
  int t = threadIdx.x, w = t >> 6, l = t & 63;
  int wm = (w >> 1) * 64, wn = (w & 1) * 32;
  f32x4 acc[4][2];
  for(int a = 0; a < 4; a++) for(int b = 0; b < 2; b++) acc[a][b] = {0.f, 0.f, 0.f, 0.f};

  const short8* Ap = (const short8*)Al;
  const short8* Bp = (const short8*)Bl;

  for(int k0 = kb; k0 < kb + kPer; k0 += BK){
    #pragma unroll
    for(int u = t; u < BM * 8; u += 256){
      int r = u >> 3, c = u & 7;
      gl_lds16(A + (size_t)r * lda + k0 + ((c ^ (r & 7)) << 3), Al + u * 8);
    }
    #pragma unroll
    for(int u = t; u < BN * 8; u += 256){
      int r = u >> 3, c = u & 7;
      int gk = k0 + c * 8;
      const float* src = (gk < Kih) ? (Wih + (size_t)(n0 + r) * Kih + gk)
                                    : (Whh + (size_t)(n0 + r) * Khh + (gk - Kih));
      float4 v0 = *(const float4*)src;
      float4 v1 = *(const float4*)(src + 4);
      short8 ov;
      ov[0] = (short)f2b(v0.x); ov[1] = (short)f2b(v0.y); ov[2] = (short)f2b(v0.z); ov[3] = (short)f2b(v0.w);
      ov[4] = (short)f2b(v1.x); ov[5] = (short)f2b(v1.y); ov[6] = (short)f2b(v1.z); ov[7] = (short)f2b(v1.w);
      ((short8*)Bl)[r * 8 + (c ^ (r & 7))] = ov;
    }
    __syncthreads();
    #pragma unroll
    for(int ks = 0; ks < 2; ks++){
      int kc = ks * 4 + (l >> 4);
      short8 av[4], bv[2];
      #pragma unroll
      for(int mi = 0; mi < 4; mi++){ int r = wm + mi * 16 + (l & 15); av[mi] = Ap[r * 8 + (kc ^ (r & 7))]; }
      #pragma unroll
      for(int ni = 0; ni < 2; ni++){ int r = wn + ni * 16 + (l & 15); bv[ni] = Bp[r * 8 + (kc ^ (r & 7))]; }
      #pragma unroll
      for(int mi = 0; mi < 4; mi++)
        #pragma unroll
        for(int ni = 0; ni < 2; ni++)
          acc[mi][ni] = __builtin_amdgcn_mfma_f32_16x16x32_bf16(av[mi], bv[ni], acc[mi][ni], 0, 0, 0);
    }
    __syncthreads();
  }

  int cr = wm + ((l >> 4) << 2);
  int cc = n0 + wn + (l & 15);
  for(int mi = 0; mi < 4; mi++)
    for(int ni = 0; ni < 2; ni++)
      for(int r = 0; r < 4; r++)
        C[(size_t)(cr + mi * 16 + r) * N + cc + ni * 16] = acc[mi][ni][r];
}

// ---------------- GAT v3: scores + reg-resident softmax + VALU aggregate ----------------
__global__ __launch_bounds__(256) void gat_attn2(const u64* __restrict__ adjm,
    const u16* __restrict__ h,
    const float* __restrict__ as1, const float* __restrict__ ad1,
    const float* __restrict__ as2, const float* __restrict__ ad2,
    const float* __restrict__ b1, const float* __restrict__ b2,
    u16* __restrict__ x2b){
  int b = blockIdx.x;
  int cv = blockIdx.y >> 3, hh = blockIdx.y & 7;
  __shared__ float hst[64][64];
  __shared__ float esl[64], edl[64];
  __shared__ u64 adjs[64];
  int t = threadIdx.x, w = t >> 6, l = t & 63;
  {
    int j = t >> 2, d0 = (t & 3) * 16;
    const u16* hr = h + (size_t)(b * 64 + j) * 1024 + cv * 512 + hh * 64 + d0;
    #pragma unroll
    for(int k = 0; k < 16; k++) hst[j][d0 + k] = b2f(hr[k]);
  }
  if(t < 64) adjs[t] = adjm[b * 64 + t];
  __syncthreads();
  float aSl = ((cv ? as2 : as1) + hh * 64)[l];
  float aDl = ((cv ? ad2 : ad1) + hh * 64)[l];
  for(int it = 0; it < 16; it++){
    int j = it * 4 + w;
    float v = hst[j][l];
    float ps = v * aSl, pd = v * aDl;
    for(int o = 32; o; o >>= 1){ ps += __shfl_xor(ps, o); pd += __shfl_xor(pd, o); }
    if(l == 0){ esl[j] = ps; edl[j] = pd; }
  }
  __syncthreads();
  float alphaR[16];
  #pragma unroll
  for(int it = 0; it < 16; it++){
    int i = it * 4 + w;
    bool on = (adjs[i] >> l) & 1;
    float e = edl[i] + esl[l];
    e = e > 0.f ? e : 0.2f * e;
    float mx = on ? e : -1e30f;
    for(int o = 32; o; o >>= 1) mx = fmaxf(mx, __shfl_xor(mx, o));
    float p = on ? __expf(e - mx) : 0.f;
    float s = p;
    for(int o = 32; o; o >>= 1) s += __shfl_xor(s, o);
    alphaR[it] = p / s;
  }
  float accv[16];
  #pragma unroll
  for(int k = 0; k < 16; k++) accv[k] = 0.f;
  #pragma unroll
  for(int j = 0; j < 64; j++){
    float hv = hst[j][l];
    #pragma unroll
    for(int it = 0; it < 16; it++){
      float av = __uint_as_float(__builtin_amdgcn_readlane(__float_as_uint(alphaR[it]), j));
      accv[it] += av * hv;
    }
  }
  float bl = ((cv ? b2 : b1) + hh * 64)[l];
  #pragma unroll
  for(int it = 0; it < 16; it++){
    int i = it * 4 + w;
    x2b[(size_t)(b * 64 + i) * 1024 + cv * 512 + hh * 64 + l] = f2b(fmaxf(accv[it] + bl, 0.f));
  }
}

// ---------------- Set2Set step-0 shortcut ----------------
__global__ __launch_bounds__(256) void s2s0_gemv(const float* __restrict__ Wih1,
    const float* __restrict__ lb1, const float* __restrict__ lb0, float* __restrict__ z1u){
  __shared__ float hs[1024];
  int t = threadIdx.x;
  for(int i = t; i < 1024; i += 256){
    float zi = lb0[i], zg = lb0[2048 + i], zo = lb0[3072 + i];
    float cn = (1.f / (1.f + __expf(-zi))) * tanhf(zg);
    hs[i] = (1.f / (1.f + __expf(-zo))) * tanhf(cn);
  }
  __syncthreads();
  int w = t >> 6, l = t & 63;
  int r = blockIdx.x * 4 + w;
  const float* wr = Wih1 + (size_t)r * 1024;
  float s = 0.f;
  #pragma unroll
  for(int k = 0; k < 16; k++) s += wr[l + 64 * k] * hs[l + 64 * k];
  for(int o = 32; o; o >>= 1) s += __shfl_xor(s, o);
  if(l == 0) z1u[r] = s + lb1[r];
}

// ---------------- LSTM gates (sum ns split-K partials) ----------------
__global__ void lstm_gate0(const float* __restrict__ zp, const float* __restrict__ lb,
                           float* __restrict__ c, u16* __restrict__ ac0, u16* __restrict__ ac1,
                           int ns){
  int t = blockIdx.x * 256 + threadIdx.x;
  int b = t >> 10, j = t & 1023;
  size_t base = (size_t)b * 4096;
  float zi = 0, zf = 0, zg = 0, zo = 0;
  for(int s = 0; s < ns; s++){
    const float* zr = zp + (size_t)s * 524288 + base;
    zi += zr[j]; zf += zr[1024 + j]; zg += zr[2048 + j]; zo += zr[3072 + j];
  }
  zi += lb[j]; zf += lb[1024 + j]; zg += lb[2048 + j]; zo += lb[3072 + j];
  float ci = c[t];
  float si = 1.f / (1.f + __expf(-zi)), sf = 1.f / (1.f + __expf(-zf)), so = 1.f / (1.f + __expf(-zo));
  float cn = sf * ci + si * tanhf(zg);
  c[t] = cn;
  u16 hb = f2b(so * tanhf(cn));
  ac0[(size_t)b * 3072 + 2048 + j] = hb;
  ac1[(size_t)b * 2048 + j] = hb;
}

__global__ void lstm_gate1(const float* __restrict__ zp, const float* __restrict__ lb,
                           float* __restrict__ c, float* __restrict__ h1f,
                           u16* __restrict__ ac1, u16* __restrict__ ac0, int ns){
  int t = blockIdx.x * 256 + threadIdx.x;
  int b = t >> 10, j = t & 1023;
  size_t base = (size_t)b * 4096;
  float zi = 0, zf = 0, zg = 0, zo = 0;
  for(int s = 0; s < ns; s++){
    const float* zr = zp + (size_t)s * 524288 + base;
    zi += zr[j]; zf += zr[1024 + j]; zg += zr[2048 + j]; zo += zr[3072 + j];
  }
  zi += lb[j]; zf += lb[1024 + j]; zg += lb[2048 + j]; zo += lb[3072 + j];
  float ci = c[t];
  float si = 1.f / (1.f + __expf(-zi)), sf = 1.f / (1.f + __expf(-zf)), so = 1.f / (1.f + __expf(-zo));
  float cn = sf * ci + si * tanhf(zg);
  c[t] = cn;
  float hn = so * tanhf(cn);
  h1f[t] = hn;
  u16 hb = f2b(hn);
  ac1[(size_t)b * 2048 + 1024 + j] = hb;
  ac0[(size_t)b * 3072 + j] = hb;
}

// ---------------- Set2Set attention (bf16 x2) ----------------
template<int STEP>
__global__ __launch_bounds__(256) void s2s_e(const u16* __restrict__ x2b,
    const float* __restrict__ h1, const float* __restrict__ z1u, float* __restrict__ e){
  __shared__ float h1s[1024];
  int t = threadIdx.x, w = t >> 6, l = t & 63;
  int node = blockIdx.x * 4 + w;
  int b = node >> 6;
  for(int i = t; i < 1024; i += 256){
    if(STEP == 0){
      float zi = z1u[i], zg = z1u[2048 + i], zo = z1u[3072 + i];
      float cn = (1.f / (1.f + __expf(-zi))) * tanhf(zg);
      h1s[i] = (1.f / (1.f + __expf(-zo))) * tanhf(cn);
    } else {
      h1s[i] = h1[(size_t)b * 1024 + i];
    }
  }
  __syncthreads();
  const u16* xr = x2b + (size_t)node * 1024;
  float s = 0.f;
  #pragma unroll
  for(int k = 0; k < 16; k++){
    int d = k * 64 + l;
    s += b2f(xr[d]) * h1s[d];
  }
  for(int o = 32; o; o >>= 1) s += __shfl_xor(s, o);
  if(l == 0) e[node] = s;
}

template<int STEP>
__global__ __launch_bounds__(256) void s2s_r(const u16* __restrict__ x2b,
    const float* __restrict__ e, u16* __restrict__ ac0,
    const float* __restrict__ lb0, const float* __restrict__ z1u,
    u16* __restrict__ ac1, float* __restrict__ c0b, float* __restrict__ c1b){
  int b = blockIdx.x, sl = blockIdx.y;
  __shared__ float al[64];
  int t = threadIdx.x;
  if(t < 64){
    float v = e[b * 64 + t];
    float mx = v;
    for(int o = 32; o; o >>= 1) mx = fmaxf(mx, __shfl_xor(mx, o));
    float p = __expf(v - mx);
    float ss = p;
    for(int o = 32; o; o >>= 1) ss += __shfl_xor(ss, o);
    al[t] = p / ss;
  }
  __syncthreads();
  int d = sl * 256 + t;
  const u16* xp = x2b + (size_t)b * 65536 + d;
  float r = 0.f;
  #pragma unroll 8
  for(int j = 0; j < 64; j++) r += al[j] * b2f(xp[j * 1024]);
  ac0[(size_t)b * 3072 + 1024 + d] = f2b(r);
  if(STEP == 0){
    float zi0 = lb0[d], zg0 = lb0[2048 + d], zo0 = lb0[3072 + d];
    float c0 = (1.f / (1.f + __expf(-zi0))) * tanhf(zg0);
    float h0 = (1.f / (1.f + __expf(-zo0))) * tanhf(c0);
    float zi1 = z1u[d], zg1 = z1u[2048 + d], zo1 = z1u[3072 + d];
    float c1 = (1.f / (1.f + __expf(-zi1))) * tanhf(zg1);
    float h1 = (1.f / (1.f + __expf(-zo1))) * tanhf(c1);
    c0b[(size_t)b * 1024 + d] = c0;
    c1b[(size_t)b * 1024 + d] = c1;
    u16 h0b = f2b(h0), h1b = f2b(h1);
    ac0[(size_t)b * 3072 + d] = h1b;
    ac0[(size_t)b * 3072 + 2048 + d] = h0b;
    ac1[(size_t)b * 2048 + d] = h0b;
    ac1[(size_t)b * 2048 + 1024 + d] = h1b;
  }
}

// ---------------- lin2 combine (8 split partials) + bn + relu + lin3 ----------------
__global__ __launch_bounds__(256) void lin3(const float* __restrict__ zp2,
    const float* __restrict__ sc2, const float* __restrict__ sh2,
    const float* __restrict__ W3, const float* __restrict__ b3, float* __restrict__ out){
  int b = blockIdx.x;
  __shared__ float yl[1024];
  int t = threadIdx.x, w = t >> 6, l = t & 63;
  for(int d = t; d < 1024; d += 256){
    float v = 0.f;
    for(int s = 0; s < 8; s++) v += zp2[(size_t)s * 131072 + b * 1024 + d];
    yl[d] = fmaxf(v, 0.f) * sc2[d] + sh2[d];
  }
  __syncthreads();
  for(int n = w; n < 10; n += 4){
    float s = 0.f;
    for(int d = l; d < 1024; d += 64) s += yl[d] * W3[d * 10 + n];
    for(int o = 32; o; o >>= 1) s += __shfl_xor(s, o);
    if(l == 0) out[b * 10 + n] = s + b3[n];
  }
}

extern "C" void kernel_launch(void* const* d_in, const int* in_sizes, int n_in,
                              void* d_out, int out_size, void* d_ws, size_t ws_size,
                              hipStream_t stream){
  const float* x    = (const float*)d_in[0];
  const float* pos  = (const float*)d_in[1];
  const float* W0   = (const float*)d_in[3];
  const float* bn0g = (const float*)d_in[4];
  const float* bn0b = (const float*)d_in[5];
  const float* bn0m = (const float*)d_in[6];
  const float* bn0v = (const float*)d_in[7];
  const float* Wg1  = (const float*)d_in[8];
  const float* as1  = (const float*)d_in[9];
  const float* ad1  = (const float*)d_in[10];
  const float* b1   = (const float*)d_in[11];
  const float* Wg2  = (const float*)d_in[12];
  const float* as2  = (const float*)d_in[13];
  const float* ad2  = (const float*)d_in[14];
  const float* b2   = (const float*)d_in[15];
  const float* Wih0 = (const float*)d_in[16];
  const float* Whh0 = (const float*)d_in[17];
  const float* bih0 = (const float*)d_in[18];
  const float* bhh0 = (const float*)d_in[19];
  const float* Wih1 = (const float*)d_in[20];
  const float* Whh1 = (const float*)d_in[21];
  const float* bih1 = (const float*)d_in[22];
  const float* bhh1 = (const float*)d_in[23];
  const float* W2   = (const float*)d_in[24];
  const float* bn2g = (const float*)d_in[25];
  const float* bn2b = (const float*)d_in[26];
  const float* bn2m = (const float*)d_in[27];
  const float* bn2v = (const float*)d_in[28];
  const float* W3   = (const float*)d_in[29];
  const float* b3   = (const float*)d_in[30];

  char* ws = (char*)d_ws;
  u16*   xbf  = (u16*)(ws + O_XBF);
  u16*   x2b  = (u16*)(ws + O_XBF);
  u16*   w0t  = (u16*)(ws + O_W0T);
  u16*   wgt  = (u16*)(ws + O_WGT);
  u16*   w2t  = (u16*)(ws + O_W2T);
  u16*   xb   = (u16*)(ws + O_XB);
  u16*   hb   = (u16*)(ws + O_H);
  u64*   adjm = (u64*)(ws + O_ADJ);
  float* sc0  = (float*)(ws + O_SC0);
  float* sh0  = (float*)(ws + O_SH0);
  float* sc2  = (float*)(ws + O_SC2);
  float* sh2  = (float*)(ws + O_SH2);
  float* lb0  = (float*)(ws + O_LB0);
  float* lb1  = (float*)(ws + O_LB1);
  char*  s2sb = ws + O_H;
  u16*   ac0  = (u16*)(s2sb + S_AC0);
  u16*   ac1  = (u16*)(s2sb + S_AC1);
  float* c0b  = (float*)(s2sb + S_C0);
  float* c1b  = (float*)(s2sb + S_C1);
  float* h1f  = (float*)(s2sb + S_H1F);
  float* zp   = (float*)(s2sb + S_ZP);
  float* ebuf = (float*)(s2sb + S_E);
  float* z1u  = (float*)(s2sb + S_Z1U);

  setup_all<<<16432, 256, 0, stream>>>(x, W0, Wg1, Wg2, W2,
                                       bn0g, bn0b, bn0m, bn0v, bn2g, bn2b, bn2m, bn2v,
                                       bih0, bhh0, bih1, bhh1, pos,
                                       xbf, w0t, wgt, w2t, sc0, sh0, sc2, sh2, lb0, lb1, adjm);

  gemm8p<<<dim3(32, 8), 512, 0, stream>>>(xbf, w0t, xb, sc0, sh0, 8192, 2048, 2048);
  gemm_bf16<3><<<dim3(64, 8), 256, 0, stream>>>(xb, wgt, nullptr, hb, nullptr, nullptr, 8192, 1024, 2048);
  gat_attn2<<<dim3(128, 16), 256, 0, stream>>>(adjm, hb, as1, ad1, as2, ad2, b1, b2, x2b);

  s2s0_gemv<<<1024, 256, 0, stream>>>(Wih1, lb1, lb0, z1u);
  s2s_e<0><<<2048, 256, 0, stream>>>(x2b, nullptr, z1u, ebuf);
  s2s_r<0><<<dim3(128, 4), 256, 0, stream>>>(x2b, ebuf, ac0, lb0, z1u, ac1, c0b, c1b);

  gemm_skf<<<dim3(64, 8), 256, 0, stream>>>(ac0, Wih0, Whh0, zp, 4096, 3072, 2048, 1024, 384);
  lstm_gate0<<<512, 256, 0, stream>>>(zp, lb0, c0b, ac0, ac1, 8);
  gemm_skf<<<dim3(64, 8), 256, 0, stream>>>(ac1, Wih1, Whh1, zp, 4096, 2048, 1024, 1024, 256);
  lstm_gate1<<<512, 256, 0, stream>>>(zp, lb1, c1b, h1f, ac1, ac0, 8);
  s2s_e<1><<<2048, 256, 0, stream>>>(x2b, h1f, nullptr, ebuf);
  s2s_r<1><<<dim3(128, 4), 256, 0, stream>>>(x2b, ebuf, ac0, nullptr, nullptr, nullptr, nullptr, nullptr);

  gemm_sk<<<dim3(16, 8), 256, 0, stream>>>(ac0, w2t, zp, 1024, 3072, 2048, 256);
  lin3<<<128, 256, 0, stream>>>(zp, sc2, sh2, W3, b3, (float*)d_out);
}